// Round 2
// baseline (1973.664 us; speedup 1.0000x reference)
//
#include <hip/hip_runtime.h>
#include <hip/hip_bf16.h>

// Problem constants (fixed by the harness)
#define NN  50000      // nodes
#define EE  800000     // edges before self-loops
#define NE2 850000     // edges + self-loops
#define NB  512        // graphs
// GAT1: F=128 -> 4 heads x 64 (256). GAT2: 256 -> 1 head x 128. GCN: 128 -> 64.

#define BN_RS 0.9999950000374997f   // 1/sqrt(1+1e-5)

__device__ __forceinline__ float bf2f(__hip_bfloat16 v) { return __bfloat162float(v); }
__device__ __forceinline__ float lrelu01(float v) { return v > 0.f ? v : 0.01f * v; }
__device__ __forceinline__ float lrelu02(float v) { return v > 0.f ? v : 0.2f * v; }

__device__ __forceinline__ void edge_sd(const int* __restrict__ ei, int e, int& s, int& d) {
    if (e < EE) { s = ei[e]; d = ei[EE + e]; }
    else        { s = e - EE; d = e - EE; }      // self-loop
}

// ---------------- dtype detector: bf16 halfwords have structured exponent bits ----------
// For bf16 x~N(0,1): low 16 bits of each 32-bit word are a bf16 value; bits 14:7 (exponent)
// land in ~[113,129]. For fp32 x: low 16 bits are low mantissa bits (uniform) -> in-range
// with p~0.16. 1024 samples separate the two decisively.
__global__ __launch_bounds__(256) void det_k(const unsigned* __restrict__ xw, int* __restrict__ flag) {
    __shared__ int cnt;
    if (threadIdx.x == 0) cnt = 0;
    __syncthreads();
    int c = 0;
#pragma unroll
    for (int k = 0; k < 4; ++k) {
        unsigned w = xw[threadIdx.x * 4 + k];
        unsigned ef = (w >> 7) & 0xFFu;
        if (ef >= 100u && ef <= 140u) c++;
    }
    atomicAdd(&cnt, c);
    __syncthreads();
    if (threadIdx.x == 0) *flag = (cnt > 512) ? 1 : 0;   // 1 = bf16 inputs
}

__global__ __launch_bounds__(256) void conv_x_k(const void* __restrict__ x, float* __restrict__ xf,
                                                const int* __restrict__ flag) {
    bool bf = (*flag != 0);
    size_t i = (size_t)blockIdx.x * 256 + threadIdx.x;
    if (i >= (size_t)NN * 128) return;
    xf[i] = bf ? bf2f(((const __hip_bfloat16*)x)[i]) : ((const float*)x)[i];
}

#define NSEG 20
struct SegArgs { const void* src[NSEG]; int n[NSEG]; int off[NSEG]; };

__global__ __launch_bounds__(256) void conv_w_k(SegArgs a, float* __restrict__ wf,
                                                const int* __restrict__ flag) {
    bool bf = (*flag != 0);
    for (int s = 0; s < NSEG; ++s) {
        const void* sp = a.src[s];
        int n = a.n[s];
        float* dp = wf + a.off[s];
        for (int i = threadIdx.x; i < n; i += 256)
            dp[i] = bf ? bf2f(((const __hip_bfloat16*)sp)[i]) : ((const float*)sp)[i];
    }
}

// ---------------- Tiled fp32 GEMM: C[M x NCOLS] = A[M x K] @ W[K x NCOLS] ----------------
template <int K, int NCOLS>
__global__ __launch_bounds__(256) void gemm_k(const float* __restrict__ A,
                                              const float* __restrict__ W,
                                              float* __restrict__ C, int M) {
    __shared__ float As[16][64];   // [k][m]
    __shared__ float Ws[16][64];   // [k][n]
    const int tid = threadIdx.x;
    const int bm = blockIdx.x * 64;
    const int bn = blockIdx.y * 64;
    const int tx = tid & 15, ty = tid >> 4;
    const int lm = tid >> 2, lk = (tid & 3) << 2;
    const int wk = tid >> 4, wc = (tid & 15) << 2;
    float acc[4][4] = {};
    for (int k0 = 0; k0 < K; k0 += 16) {
        float a0 = 0.f, a1 = 0.f, a2 = 0.f, a3 = 0.f, w0, w1, w2, w3;
        int gm = bm + lm;
        if (gm < M) {
            const float* p = A + (size_t)gm * K + k0 + lk;
            a0 = p[0]; a1 = p[1]; a2 = p[2]; a3 = p[3];
        }
        {
            const float* p = W + (size_t)(k0 + wk) * NCOLS + bn + wc;
            w0 = p[0]; w1 = p[1]; w2 = p[2]; w3 = p[3];
        }
        __syncthreads();
        As[lk + 0][lm] = a0; As[lk + 1][lm] = a1; As[lk + 2][lm] = a2; As[lk + 3][lm] = a3;
        Ws[wk][wc + 0] = w0; Ws[wk][wc + 1] = w1; Ws[wk][wc + 2] = w2; Ws[wk][wc + 3] = w3;
        __syncthreads();
#pragma unroll
        for (int kk = 0; kk < 16; ++kk) {
            float av[4], wv[4];
#pragma unroll
            for (int i = 0; i < 4; ++i) av[i] = As[kk][ty * 4 + i];
#pragma unroll
            for (int j = 0; j < 4; ++j) wv[j] = Ws[kk][tx * 4 + j];
#pragma unroll
            for (int i = 0; i < 4; ++i)
#pragma unroll
                for (int j = 0; j < 4; ++j) acc[i][j] = fmaf(av[i], wv[j], acc[i][j]);
        }
    }
#pragma unroll
    for (int i = 0; i < 4; ++i) {
        int gm = bm + ty * 4 + i;
        if (gm < M) {
            float* cp = C + (size_t)gm * NCOLS + bn + tx * 4;
            cp[0] = acc[i][0]; cp[1] = acc[i][1]; cp[2] = acc[i][2]; cp[3] = acc[i][3];
        }
    }
}

// ---------------- GAT1 attention scores: wave per node, 4 heads x 64 ch ----------------
__global__ __launch_bounds__(256) void scores1_k(const float* __restrict__ h1,
                                                 const float* __restrict__ a_src,
                                                 const float* __restrict__ a_dst,
                                                 float* __restrict__ sc_s, float* __restrict__ sc_d) {
    int n = (blockIdx.x * 256 + threadIdx.x) >> 6;
    int lane = threadIdx.x & 63;
    if (n >= NN) return;
#pragma unroll
    for (int h = 0; h < 4; ++h) {
        float v = h1[(size_t)n * 256 + h * 64 + lane];
        float ps = v * a_src[h * 64 + lane];
        float pd = v * a_dst[h * 64 + lane];
#pragma unroll
        for (int off = 32; off; off >>= 1) { ps += __shfl_down(ps, off); pd += __shfl_down(pd, off); }
        if (lane == 0) { sc_s[n * 4 + h] = ps; sc_d[n * 4 + h] = pd; }
    }
}

__global__ __launch_bounds__(256) void scores2_k(const float* __restrict__ h2,
                                                 const float* __restrict__ a_src,
                                                 const float* __restrict__ a_dst,
                                                 float* __restrict__ sc_s, float* __restrict__ sc_d) {
    int n = (blockIdx.x * 256 + threadIdx.x) >> 6;
    int lane = threadIdx.x & 63;
    if (n >= NN) return;
    float v0 = h2[(size_t)n * 128 + lane];
    float v1 = h2[(size_t)n * 128 + 64 + lane];
    float ps = v0 * a_src[lane] + v1 * a_src[64 + lane];
    float pd = v0 * a_dst[lane] + v1 * a_dst[64 + lane];
#pragma unroll
    for (int off = 32; off; off >>= 1) { ps += __shfl_down(ps, off); pd += __shfl_down(pd, off); }
    if (lane == 0) { sc_s[n] = ps; sc_d[n] = pd; }
}

// ---------------- edge pass: softmax denominators (no max-subtraction; |e| small) ----------
__global__ __launch_bounds__(256) void att_sum1_k(const int* __restrict__ ei,
                                                  const float* __restrict__ sc_s,
                                                  const float* __restrict__ sc_d,
                                                  float* __restrict__ s1, float* __restrict__ deg) {
    int e = blockIdx.x * 256 + threadIdx.x;
    if (e >= NE2) return;
    int s, d; edge_sd(ei, e, s, d);
    float4 ss = ((const float4*)sc_s)[s];
    float4 sd = ((const float4*)sc_d)[d];
    atomicAdd(&s1[d * 4 + 0], __expf(lrelu02(ss.x + sd.x)));
    atomicAdd(&s1[d * 4 + 1], __expf(lrelu02(ss.y + sd.y)));
    atomicAdd(&s1[d * 4 + 2], __expf(lrelu02(ss.z + sd.z)));
    atomicAdd(&s1[d * 4 + 3], __expf(lrelu02(ss.w + sd.w)));
    atomicAdd(&deg[d], 1.0f);   // degree for GCN (A + I), fused here
}

__global__ __launch_bounds__(256) void att_sum2_k(const int* __restrict__ ei,
                                                  const float* __restrict__ sc_s,
                                                  const float* __restrict__ sc_d,
                                                  float* __restrict__ s2) {
    int e = blockIdx.x * 256 + threadIdx.x;
    if (e >= NE2) return;
    int s, d; edge_sd(ei, e, s, d);
    atomicAdd(&s2[d], __expf(lrelu02(sc_s[s] + sc_d[d])));
}

// ---------------- edge pass: weighted aggregate (wave per edge, lane = channel) -----------
__global__ __launch_bounds__(256) void att_agg1_k(const int* __restrict__ ei,
                                                  const float* __restrict__ h1,
                                                  const float* __restrict__ sc_s,
                                                  const float* __restrict__ sc_d,
                                                  const float* __restrict__ s1,
                                                  float* __restrict__ acc) {
    int e = (blockIdx.x * 256 + threadIdx.x) >> 6;
    int lane = threadIdx.x & 63;
    if (e >= NE2) return;
    int s, d; edge_sd(ei, e, s, d);
#pragma unroll
    for (int h = 0; h < 4; ++h) {
        float al = __expf(lrelu02(sc_s[s * 4 + h] + sc_d[d * 4 + h])) / (s1[d * 4 + h] + 1e-16f);
        float hv = h1[(size_t)s * 256 + h * 64 + lane];
        atomicAdd(&acc[(size_t)d * 256 + h * 64 + lane], hv * al);
    }
}

__global__ __launch_bounds__(256) void att_agg2_k(const int* __restrict__ ei,
                                                  const float* __restrict__ h2,
                                                  const float* __restrict__ sc_s,
                                                  const float* __restrict__ sc_d,
                                                  const float* __restrict__ s2,
                                                  float* __restrict__ acc) {
    int e = (blockIdx.x * 256 + threadIdx.x) >> 6;
    int lane = threadIdx.x & 63;
    if (e >= NE2) return;
    int s, d; edge_sd(ei, e, s, d);
    float al = __expf(lrelu02(sc_s[s] + sc_d[d])) / (s2[d] + 1e-16f);
    atomicAdd(&acc[(size_t)d * 128 + lane],      h2[(size_t)s * 128 + lane] * al);
    atomicAdd(&acc[(size_t)d * 128 + 64 + lane], h2[(size_t)s * 128 + 64 + lane] * al);
}

__global__ __launch_bounds__(256) void gcn_agg_k(const int* __restrict__ ei,
                                                 const float* __restrict__ hg,
                                                 const float* __restrict__ dis,
                                                 float* __restrict__ acc) {
    int e = (blockIdx.x * 256 + threadIdx.x) >> 6;
    int lane = threadIdx.x & 63;
    if (e >= NE2) return;
    int s, d; edge_sd(ei, e, s, d);
    float w = dis[s] * dis[d];
    atomicAdd(&acc[(size_t)d * 64 + lane], hg[(size_t)s * 64 + lane] * w);
}

// ---------------- x = bn(lrelu(acc + bias)) in place ----------------
template <int CH>
__global__ __launch_bounds__(256) void act_bn_k(float* __restrict__ x,
                                                const float* __restrict__ bias,
                                                const float* __restrict__ g,
                                                const float* __restrict__ b) {
    size_t i = (size_t)blockIdx.x * 256 + threadIdx.x;
    if (i >= (size_t)NN * CH) return;
    int c = (int)(i & (CH - 1));
    float v = lrelu01(x[i] + bias[c]);
    x[i] = v * (g[c] * BN_RS) + b[c];
}

__global__ __launch_bounds__(256) void dis_k(const float* __restrict__ deg, float* __restrict__ dis) {
    int n = blockIdx.x * 256 + threadIdx.x;
    if (n >= NN) return;
    float dg = deg[n];
    dis[n] = dg > 0.f ? rsqrtf(dg) : 0.f;
}

// ---------------- x3 = lrelu(accg + bg); pooled sums via atomics -----------
__global__ __launch_bounds__(256) void pool_k(const float* __restrict__ accg,
                                              const float* __restrict__ bg,
                                              const int* __restrict__ batch,
                                              float* __restrict__ pool, float* __restrict__ cnt) {
    int n = (blockIdx.x * 256 + threadIdx.x) >> 6;
    int lane = threadIdx.x & 63;
    if (n >= NN) return;
    float v = lrelu01(accg[(size_t)n * 64 + lane] + bg[lane]);
    int b = batch[n];
    atomicAdd(&pool[b * 64 + lane], v);
    if (lane == 0) atomicAdd(&cnt[b], 1.0f);
}

// ---------------- per-graph MLP head; output dtype per flag ----------------
__global__ __launch_bounds__(128) void mlp_k(const float* __restrict__ pool,
                                             const float* __restrict__ cnt,
                                             const float* __restrict__ l1W,
                                             const float* __restrict__ l1b,
                                             const float* __restrict__ g3,
                                             const float* __restrict__ b3,
                                             const float* __restrict__ l2W,
                                             const float* __restrict__ l2b,
                                             void* __restrict__ outp,
                                             const int* __restrict__ flag) {
    __shared__ float pl[64];
    __shared__ float y1s[128];
    int g = blockIdx.x, t = threadIdx.x;
    if (t < 64) {
        float c = cnt[g];
        c = c < 1.f ? 1.f : c;
        pl[t] = pool[g * 64 + t] / c;
    }
    __syncthreads();
    float acc = l1b[t];
#pragma unroll 8
    for (int j = 0; j < 64; ++j) acc = fmaf(pl[j], l1W[j * 128 + t], acc);
    acc = acc * (g3[t] * BN_RS) + b3[t];
    y1s[t] = lrelu01(acc);
    __syncthreads();
    if (t < 10) {
        float o = l2b[t];
#pragma unroll 8
        for (int j = 0; j < 128; ++j) o = fmaf(y1s[j], l2W[j * 10 + t], o);
        if (*flag) ((__hip_bfloat16*)outp)[g * 10 + t] = __float2bfloat16(o);
        else       ((float*)outp)[g * 10 + t] = o;
    }
}

// weight segment sizes and offsets in canonical fp32 buffer
static const int kSegN[NSEG]   = {32768, 256, 256, 256, 32768, 128, 128, 128, 8192, 64,
                                  256, 256, 128, 128, 128, 128, 8192, 128, 1280, 10};
// d_in indices for each segment (W1,as1,ad1,b1,W2,as2,ad2,b2,Wg,bg,bn1g,bn1b,bn2g,bn2b,bn3g,bn3b,l1W,l1b,l2W,l2b)
static const int kSegIn[NSEG]  = {3, 4, 5, 6, 7, 8, 9, 10, 11, 12, 13, 14, 15, 16, 17, 18, 19, 20, 21, 22};

extern "C" void kernel_launch(void* const* d_in, const int* in_sizes, int n_in,
                              void* d_out, int out_size, void* d_ws, size_t ws_size,
                              hipStream_t stream) {
    const void* x_raw = d_in[0];
    const int*  ei    = (const int*)d_in[1];
    const int*  batch = (const int*)d_in[2];

    // ---- workspace layout (fp32 canonical everything) ----
    int*   flag = (int*)d_ws;
    float* ws   = (float*)d_ws;
    float* xf   = ws + 16;                         // N*128
    float* wf   = xf + (size_t)NN * 128;           // 85584
    float* bufA = wf + 85584;                      // N*256
    float* bufB = bufA + (size_t)NN * 256;         // N*256
    float* sc_s1 = bufB + (size_t)NN * 256;        // N*4
    float* sc_d1 = sc_s1 + (size_t)NN * 4;
    float* s1    = sc_d1 + (size_t)NN * 4;
    float* sc_s2 = s1    + (size_t)NN * 4;         // N
    float* sc_d2 = sc_s2 + NN;
    float* s2    = sc_d2 + NN;
    float* degb  = s2    + NN;
    float* disb  = degb  + NN;
    float* poolb = disb  + NN;                     // B*64
    float* cntb  = poolb + NB * 64;                // B

    // canonical weight pointers
    int off[NSEG]; int o = 0;
    for (int s = 0; s < NSEG; ++s) { off[s] = o; o += kSegN[s]; }
    float* W1f  = wf + off[0];  float* as1f = wf + off[1];  float* ad1f = wf + off[2];
    float* b1f  = wf + off[3];  float* W2f  = wf + off[4];  float* as2f = wf + off[5];
    float* ad2f = wf + off[6];  float* b2f  = wf + off[7];  float* Wgf  = wf + off[8];
    float* bgf  = wf + off[9];  float* bn1g = wf + off[10]; float* bn1b = wf + off[11];
    float* bn2g = wf + off[12]; float* bn2b = wf + off[13]; float* bn3g = wf + off[14];
    float* bn3b = wf + off[15]; float* l1Wf = wf + off[16]; float* l1bf = wf + off[17];
    float* l2Wf = wf + off[18]; float* l2bf = wf + off[19];

    float* h1   = bufA;
    float* acc1 = bufB;                         // -> x1 in place
    float* h2   = bufA;                         // h1 dead after att_agg1
    float* acc2 = bufA + (size_t)NN * 128;      // -> x2 in place
    float* hg   = bufB;                         // x1 dead after gemm2
    float* accg = bufB + (size_t)NN * 64;

    // ---- dtype detect + canonicalize ----
    det_k<<<1, 256, 0, stream>>>((const unsigned*)x_raw, flag);
    conv_x_k<<<(NN * 128 + 255) / 256, 256, 0, stream>>>(x_raw, xf, flag);
    SegArgs sa;
    for (int s = 0; s < NSEG; ++s) { sa.src[s] = d_in[kSegIn[s]]; sa.n[s] = kSegN[s]; sa.off[s] = off[s]; }
    conv_w_k<<<1, 256, 0, stream>>>(sa, wf, flag);

    // zero accumulators
    hipMemsetAsync(acc1, 0, (size_t)NN * 256 * sizeof(float), stream);
    hipMemsetAsync(s1,   0, (size_t)NN * 4 * sizeof(float), stream);
    hipMemsetAsync(s2,   0, (size_t)NN * sizeof(float), stream);
    hipMemsetAsync(degb, 0, (size_t)NN * sizeof(float), stream);
    hipMemsetAsync(poolb,0, (size_t)(NB * 64 + NB) * sizeof(float), stream);

    // ---- GAT layer 1 ----
    gemm_k<128, 256><<<dim3(782, 4), 256, 0, stream>>>(xf, W1f, h1, NN);
    scores1_k<<<12500, 256, 0, stream>>>(h1, as1f, ad1f, sc_s1, sc_d1);
    att_sum1_k<<<(NE2 + 255) / 256, 256, 0, stream>>>(ei, sc_s1, sc_d1, s1, degb);
    att_agg1_k<<<NE2 / 4, 256, 0, stream>>>(ei, h1, sc_s1, sc_d1, s1, acc1);
    act_bn_k<256><<<(NN * 256) / 256, 256, 0, stream>>>(acc1, b1f, bn1g, bn1b);  // -> x1
    dis_k<<<(NN + 255) / 256, 256, 0, stream>>>(degb, disb);

    // ---- GAT layer 2 ----
    gemm_k<256, 128><<<dim3(782, 2), 256, 0, stream>>>(acc1 /*x1*/, W2f, h2, NN);
    scores2_k<<<12500, 256, 0, stream>>>(h2, as2f, ad2f, sc_s2, sc_d2);
    hipMemsetAsync(acc2, 0, (size_t)NN * 128 * sizeof(float), stream);
    att_sum2_k<<<(NE2 + 255) / 256, 256, 0, stream>>>(ei, sc_s2, sc_d2, s2);
    att_agg2_k<<<NE2 / 4, 256, 0, stream>>>(ei, h2, sc_s2, sc_d2, s2, acc2);
    act_bn_k<128><<<(NN * 128) / 256, 256, 0, stream>>>(acc2, b2f, bn2g, bn2b);  // -> x2

    // ---- GCN ----
    gemm_k<128, 64><<<dim3(782, 1), 256, 0, stream>>>(acc2 /*x2*/, Wgf, hg, NN);
    hipMemsetAsync(accg, 0, (size_t)NN * 64 * sizeof(float), stream);
    gcn_agg_k<<<NE2 / 4, 256, 0, stream>>>(ei, hg, disb, accg);

    // ---- pool + MLP head ----
    pool_k<<<12500, 256, 0, stream>>>(accg, bgf, batch, poolb, cntb);
    mlp_k<<<NB, 128, 0, stream>>>(poolb, cntb, l1Wf, l1bf, bn3g, bn3b, l2Wf, l2bf, d_out, flag);
}

// Round 3
// 919.764 us; speedup vs baseline: 2.1458x; 2.1458x over previous
//
#include <hip/hip_runtime.h>
#include <hip/hip_bf16.h>

// Problem constants (fixed by the harness)
#define NN  50000      // nodes
#define EE  800000     // edges before self-loops
#define NE2 850000     // edges + self-loops
#define NB  512        // graphs
// GAT1: F=128 -> 4 heads x 64 (256). GAT2: 256 -> 1 head x 128. GCN: 128 -> 64.

#define BN_RS 0.9999950000374997f   // 1/sqrt(1+1e-5)

__device__ __forceinline__ float bf2f(__hip_bfloat16 v) { return __bfloat162float(v); }
__device__ __forceinline__ float lrelu01(float v) { return v > 0.f ? v : 0.01f * v; }
__device__ __forceinline__ float lrelu02(float v) { return v > 0.f ? v : 0.2f * v; }

__device__ __forceinline__ void edge_sd(const int* __restrict__ ei, int e, int& s, int& d) {
    if (e < EE) { s = ei[e]; d = ei[EE + e]; }
    else        { s = e - EE; d = e - EE; }      // self-loop
}

// ---------------- dtype detector (bf16 vs fp32 inputs) ----------------
__global__ __launch_bounds__(256) void det_k(const unsigned* __restrict__ xw, int* __restrict__ flag) {
    __shared__ int cnt;
    if (threadIdx.x == 0) cnt = 0;
    __syncthreads();
    int c = 0;
#pragma unroll
    for (int k = 0; k < 4; ++k) {
        unsigned w = xw[threadIdx.x * 4 + k];
        unsigned ef = (w >> 7) & 0xFFu;
        if (ef >= 100u && ef <= 140u) c++;
    }
    atomicAdd(&cnt, c);
    __syncthreads();
    if (threadIdx.x == 0) *flag = (cnt > 512) ? 1 : 0;   // 1 = bf16 inputs
}

__global__ __launch_bounds__(256) void conv_x_k(const void* __restrict__ x, float* __restrict__ xf,
                                                const int* __restrict__ flag) {
    bool bf = (*flag != 0);
    size_t i = (size_t)blockIdx.x * 256 + threadIdx.x;
    if (i >= (size_t)NN * 128) return;
    xf[i] = bf ? bf2f(((const __hip_bfloat16*)x)[i]) : ((const float*)x)[i];
}

#define NSEG 20
struct SegArgs { const void* src[NSEG]; int n[NSEG]; int off[NSEG]; };

__global__ __launch_bounds__(256) void conv_w_k(SegArgs a, float* __restrict__ wf,
                                                const int* __restrict__ flag) {
    bool bf = (*flag != 0);
    for (int s = 0; s < NSEG; ++s) {
        const void* sp = a.src[s];
        int n = a.n[s];
        float* dp = wf + a.off[s];
        for (int i = threadIdx.x; i < n; i += 256)
            dp[i] = bf ? bf2f(((const __hip_bfloat16*)sp)[i]) : ((const float*)sp)[i];
    }
}

// ---------------- CSR build: deg -> scan -> scatter ----------------
__global__ __launch_bounds__(256) void deg_k(const int* __restrict__ ei, int* __restrict__ degi) {
    int e = blockIdx.x * 256 + threadIdx.x;
    if (e >= NE2) return;
    int s, d; edge_sd(ei, e, s, d);
    atomicAdd(&degi[d], 1);
}

__global__ __launch_bounds__(1024) void scan_k(const int* __restrict__ degi,
                                               int* __restrict__ row_ptr,
                                               int* __restrict__ cursor) {
    __shared__ int ps[1024];
    int t = threadIdx.x;
    int start = t * 49;
    int stop = start + 49 < NN ? start + 49 : NN;
    if (start > NN) start = NN;
    int s = 0;
    for (int i = start; i < stop; ++i) s += degi[i];
    ps[t] = s;
    __syncthreads();
    for (int off = 1; off < 1024; off <<= 1) {
        int v = (t >= off) ? ps[t - off] : 0;
        __syncthreads();
        ps[t] += v;
        __syncthreads();
    }
    int base = (t == 0) ? 0 : ps[t - 1];
    for (int i = start; i < stop; ++i) {
        row_ptr[i] = base; cursor[i] = base;
        base += degi[i];
    }
    if (t == 1023) row_ptr[NN] = ps[1023];
}

__global__ __launch_bounds__(256) void scatter_k(const int* __restrict__ ei,
                                                 int* __restrict__ cursor,
                                                 int* __restrict__ csr_src) {
    int e = blockIdx.x * 256 + threadIdx.x;
    if (e >= NE2) return;
    int s, d; edge_sd(ei, e, s, d);
    int pos = atomicAdd(&cursor[d], 1);
    csr_src[pos] = s;
}

__global__ __launch_bounds__(256) void dis_k(const int* __restrict__ row_ptr, float* __restrict__ dis) {
    int n = blockIdx.x * 256 + threadIdx.x;
    if (n >= NN) return;
    int dg = row_ptr[n + 1] - row_ptr[n];
    dis[n] = dg > 0 ? rsqrtf((float)dg) : 0.f;
}

// ---------------- Tiled fp32 GEMM: C[M x NCOLS] = A[M x K] @ W[K x NCOLS] ----------------
template <int K, int NCOLS>
__global__ __launch_bounds__(256) void gemm_k(const float* __restrict__ A,
                                              const float* __restrict__ W,
                                              float* __restrict__ C, int M) {
    __shared__ float As[16][64];   // [k][m]
    __shared__ float Ws[16][64];   // [k][n]
    const int tid = threadIdx.x;
    const int bm = blockIdx.x * 64;
    const int bn = blockIdx.y * 64;
    const int tx = tid & 15, ty = tid >> 4;
    const int lm = tid >> 2, lk = (tid & 3) << 2;
    const int wk = tid >> 4, wc = (tid & 15) << 2;
    float acc[4][4] = {};
    for (int k0 = 0; k0 < K; k0 += 16) {
        float a0 = 0.f, a1 = 0.f, a2 = 0.f, a3 = 0.f, w0, w1, w2, w3;
        int gm = bm + lm;
        if (gm < M) {
            const float* p = A + (size_t)gm * K + k0 + lk;
            a0 = p[0]; a1 = p[1]; a2 = p[2]; a3 = p[3];
        }
        {
            const float* p = W + (size_t)(k0 + wk) * NCOLS + bn + wc;
            w0 = p[0]; w1 = p[1]; w2 = p[2]; w3 = p[3];
        }
        __syncthreads();
        As[lk + 0][lm] = a0; As[lk + 1][lm] = a1; As[lk + 2][lm] = a2; As[lk + 3][lm] = a3;
        Ws[wk][wc + 0] = w0; Ws[wk][wc + 1] = w1; Ws[wk][wc + 2] = w2; Ws[wk][wc + 3] = w3;
        __syncthreads();
#pragma unroll
        for (int kk = 0; kk < 16; ++kk) {
            float av[4], wv[4];
#pragma unroll
            for (int i = 0; i < 4; ++i) av[i] = As[kk][ty * 4 + i];
#pragma unroll
            for (int j = 0; j < 4; ++j) wv[j] = Ws[kk][tx * 4 + j];
#pragma unroll
            for (int i = 0; i < 4; ++i)
#pragma unroll
                for (int j = 0; j < 4; ++j) acc[i][j] = fmaf(av[i], wv[j], acc[i][j]);
        }
    }
#pragma unroll
    for (int i = 0; i < 4; ++i) {
        int gm = bm + ty * 4 + i;
        if (gm < M) {
            float* cp = C + (size_t)gm * NCOLS + bn + tx * 4;
            cp[0] = acc[i][0]; cp[1] = acc[i][1]; cp[2] = acc[i][2]; cp[3] = acc[i][3];
        }
    }
}

// ---------------- attention scores ----------------
__global__ __launch_bounds__(256) void scores1_k(const float* __restrict__ h1,
                                                 const float* __restrict__ a_src,
                                                 const float* __restrict__ a_dst,
                                                 float* __restrict__ sc_s, float* __restrict__ sc_d) {
    int n = (blockIdx.x * 256 + threadIdx.x) >> 6;
    int lane = threadIdx.x & 63;
    if (n >= NN) return;
#pragma unroll
    for (int h = 0; h < 4; ++h) {
        float v = h1[(size_t)n * 256 + h * 64 + lane];
        float ps = v * a_src[h * 64 + lane];
        float pd = v * a_dst[h * 64 + lane];
#pragma unroll
        for (int off = 32; off; off >>= 1) { ps += __shfl_down(ps, off); pd += __shfl_down(pd, off); }
        if (lane == 0) { sc_s[n * 4 + h] = ps; sc_d[n * 4 + h] = pd; }
    }
}

__global__ __launch_bounds__(256) void scores2_k(const float* __restrict__ h2,
                                                 const float* __restrict__ a_src,
                                                 const float* __restrict__ a_dst,
                                                 float* __restrict__ sc_s, float* __restrict__ sc_d) {
    int n = (blockIdx.x * 256 + threadIdx.x) >> 6;
    int lane = threadIdx.x & 63;
    if (n >= NN) return;
    float v0 = h2[(size_t)n * 128 + lane];
    float v1 = h2[(size_t)n * 128 + 64 + lane];
    float ps = v0 * a_src[lane] + v1 * a_src[64 + lane];
    float pd = v0 * a_dst[lane] + v1 * a_dst[64 + lane];
#pragma unroll
    for (int off = 32; off; off >>= 1) { ps += __shfl_down(ps, off); pd += __shfl_down(pd, off); }
    if (lane == 0) { sc_s[n] = ps; sc_d[n] = pd; }
}

// ---------------- GAT1 aggregate: wave per dst node, CSR gather, fused softmax+bias+BN ------
// Softmax normalization is linear: out = (sum_e exp(e)*h[src]) / (sum_e exp(e)).
__global__ __launch_bounds__(256) void agg1_k(const int* __restrict__ row_ptr,
                                              const int* __restrict__ csr_src,
                                              const float4* __restrict__ h1,    // [N*64]
                                              const float4* __restrict__ sc_s4, // [N]
                                              const float4* __restrict__ sc_d4, // [N]
                                              const float4* __restrict__ b1,    // [64]
                                              const float4* __restrict__ g1,
                                              const float4* __restrict__ bb1,
                                              float4* __restrict__ x1) {
    int n = (blockIdx.x * 256 + threadIdx.x) >> 6;
    int lane = threadIdx.x & 63;
    if (n >= NN) return;
    int row = row_ptr[n], end = row_ptr[n + 1];
    float4 scd = sc_d4[n];
    float4 acc = {0.f, 0.f, 0.f, 0.f};
    float4 den = {0.f, 0.f, 0.f, 0.f};
    for (int c = row; c < end; c += 64) {
        int myE = c + lane;
        int msrc = 0; float4 me = {0.f, 0.f, 0.f, 0.f};
        if (myE < end) {
            msrc = csr_src[myE];
            float4 scs = sc_s4[msrc];
            me.x = __expf(lrelu02(scs.x + scd.x));
            me.y = __expf(lrelu02(scs.y + scd.y));
            me.z = __expf(lrelu02(scs.z + scd.z));
            me.w = __expf(lrelu02(scs.w + scd.w));
            den.x += me.x; den.y += me.y; den.z += me.z; den.w += me.w;
        }
        int m = end - c; if (m > 64) m = 64;
        for (int j = 0; j < m; ++j) {
            int s = __shfl(msrc, j);
            float e0 = __shfl(me.x, j), e1 = __shfl(me.y, j);
            float e2 = __shfl(me.z, j), e3 = __shfl(me.w, j);
            // channel block 4*lane..4*lane+3 -> head = lane>>4
            float eh = lane < 32 ? (lane < 16 ? e0 : e1) : (lane < 48 ? e2 : e3);
            float4 hv = h1[(size_t)s * 64 + lane];
            acc.x = fmaf(hv.x, eh, acc.x);
            acc.y = fmaf(hv.y, eh, acc.y);
            acc.z = fmaf(hv.z, eh, acc.z);
            acc.w = fmaf(hv.w, eh, acc.w);
        }
    }
#pragma unroll
    for (int off = 32; off; off >>= 1) {
        den.x += __shfl_xor(den.x, off);
        den.y += __shfl_xor(den.y, off);
        den.z += __shfl_xor(den.z, off);
        den.w += __shfl_xor(den.w, off);
    }
    float dh = lane < 32 ? (lane < 16 ? den.x : den.y) : (lane < 48 ? den.z : den.w);
    float inv = 1.f / (dh + 1e-16f);
    float4 bb = b1[lane], gg = g1[lane], be = bb1[lane];
    float4 o;
    o.x = lrelu01(acc.x * inv + bb.x) * (gg.x * BN_RS) + be.x;
    o.y = lrelu01(acc.y * inv + bb.y) * (gg.y * BN_RS) + be.y;
    o.z = lrelu01(acc.z * inv + bb.z) * (gg.z * BN_RS) + be.z;
    o.w = lrelu01(acc.w * inv + bb.w) * (gg.w * BN_RS) + be.w;
    x1[(size_t)n * 64 + lane] = o;
}

// ---------------- GAT2 aggregate: 1 head x 128 ch, float2 per lane ----------------
__global__ __launch_bounds__(256) void agg2_k(const int* __restrict__ row_ptr,
                                              const int* __restrict__ csr_src,
                                              const float2* __restrict__ h2,   // [N*64]
                                              const float* __restrict__ sc_s,  // [N]
                                              const float* __restrict__ sc_d,
                                              const float2* __restrict__ b2,   // [64]
                                              const float2* __restrict__ g2,
                                              const float2* __restrict__ bb2,
                                              float2* __restrict__ x2) {
    int n = (blockIdx.x * 256 + threadIdx.x) >> 6;
    int lane = threadIdx.x & 63;
    if (n >= NN) return;
    int row = row_ptr[n], end = row_ptr[n + 1];
    float scd = sc_d[n];
    float ax = 0.f, ay = 0.f, den = 0.f;
    for (int c = row; c < end; c += 64) {
        int myE = c + lane;
        int msrc = 0; float me = 0.f;
        if (myE < end) {
            msrc = csr_src[myE];
            me = __expf(lrelu02(sc_s[msrc] + scd));
            den += me;
        }
        int m = end - c; if (m > 64) m = 64;
        for (int j = 0; j < m; ++j) {
            int s = __shfl(msrc, j);
            float e = __shfl(me, j);
            float2 hv = h2[(size_t)s * 64 + lane];
            ax = fmaf(hv.x, e, ax);
            ay = fmaf(hv.y, e, ay);
        }
    }
#pragma unroll
    for (int off = 32; off; off >>= 1) den += __shfl_xor(den, off);
    float inv = 1.f / (den + 1e-16f);
    float2 bb = b2[lane], gg = g2[lane], be = bb2[lane];
    float2 o;
    o.x = lrelu01(ax * inv + bb.x) * (gg.x * BN_RS) + be.x;
    o.y = lrelu01(ay * inv + bb.y) * (gg.y * BN_RS) + be.y;
    x2[(size_t)n * 64 + lane] = o;
}

// ---------------- GCN aggregate + lrelu + pool (x3 never materialized) ----------------
__global__ __launch_bounds__(256) void gcn_k(const int* __restrict__ row_ptr,
                                             const int* __restrict__ csr_src,
                                             const float* __restrict__ hg,   // [N*64]
                                             const float* __restrict__ dis,
                                             const float* __restrict__ bg,   // [64]
                                             const int* __restrict__ batch,
                                             float* __restrict__ pool, float* __restrict__ cnt) {
    int n = (blockIdx.x * 256 + threadIdx.x) >> 6;
    int lane = threadIdx.x & 63;
    if (n >= NN) return;
    int row = row_ptr[n], end = row_ptr[n + 1];
    float dn = dis[n];
    float acc = 0.f;
    for (int c = row; c < end; c += 64) {
        int myE = c + lane;
        int msrc = 0; float mw = 0.f;
        if (myE < end) {
            msrc = csr_src[myE];
            mw = dis[msrc];
        }
        int m = end - c; if (m > 64) m = 64;
        for (int j = 0; j < m; ++j) {
            int s = __shfl(msrc, j);
            float w = __shfl(mw, j);
            acc = fmaf(hg[(size_t)s * 64 + lane], w, acc);
        }
    }
    float v = lrelu01(acc * dn + bg[lane]);
    int b = batch[n];
    atomicAdd(&pool[b * 64 + lane], v);
    if (lane == 0) atomicAdd(&cnt[b], 1.0f);
}

// ---------------- per-graph MLP head; output dtype per flag ----------------
__global__ __launch_bounds__(128) void mlp_k(const float* __restrict__ pool,
                                             const float* __restrict__ cnt,
                                             const float* __restrict__ l1W,
                                             const float* __restrict__ l1b,
                                             const float* __restrict__ g3,
                                             const float* __restrict__ b3,
                                             const float* __restrict__ l2W,
                                             const float* __restrict__ l2b,
                                             void* __restrict__ outp,
                                             const int* __restrict__ flag) {
    __shared__ float pl[64];
    __shared__ float y1s[128];
    int g = blockIdx.x, t = threadIdx.x;
    if (t < 64) {
        float c = cnt[g];
        c = c < 1.f ? 1.f : c;
        pl[t] = pool[g * 64 + t] / c;
    }
    __syncthreads();
    float acc = l1b[t];
#pragma unroll 8
    for (int j = 0; j < 64; ++j) acc = fmaf(pl[j], l1W[j * 128 + t], acc);
    acc = acc * (g3[t] * BN_RS) + b3[t];
    y1s[t] = lrelu01(acc);
    __syncthreads();
    if (t < 10) {
        float o = l2b[t];
#pragma unroll 8
        for (int j = 0; j < 128; ++j) o = fmaf(y1s[j], l2W[j * 10 + t], o);
        if (*flag) ((__hip_bfloat16*)outp)[g * 10 + t] = __float2bfloat16(o);
        else       ((float*)outp)[g * 10 + t] = o;
    }
}

// weight segment sizes (W1,as1,ad1,b1,W2,as2,ad2,b2,Wg,bg,bn1g,bn1b,bn2g,bn2b,bn3g,bn3b,l1W,l1b,l2W,l2b)
static const int kSegN[NSEG]  = {32768, 256, 256, 256, 32768, 128, 128, 128, 8192, 64,
                                 256, 256, 128, 128, 128, 128, 8192, 128, 1280, 10};
static const int kSegIn[NSEG] = {3, 4, 5, 6, 7, 8, 9, 10, 11, 12, 13, 14, 15, 16, 17, 18, 19, 20, 21, 22};

extern "C" void kernel_launch(void* const* d_in, const int* in_sizes, int n_in,
                              void* d_out, int out_size, void* d_ws, size_t ws_size,
                              hipStream_t stream) {
    const void* x_raw = d_in[0];
    const int*  ei    = (const int*)d_in[1];
    const int*  batch = (const int*)d_in[2];

    // ---- workspace layout ----
    int*   flag = (int*)d_ws;
    float* ws   = (float*)d_ws;
    float* xf   = ws + 16;                         // N*128
    float* wf   = xf + (size_t)NN * 128;           // 85584
    float* bufA = wf + 85584;                      // N*256
    float* bufB = bufA + (size_t)NN * 256;         // N*256
    float* sc_s1 = bufB + (size_t)NN * 256;        // N*4
    float* sc_d1 = sc_s1 + (size_t)NN * 4;         // N*4
    float* sc_s2 = sc_d1 + (size_t)NN * 4;         // N
    float* sc_d2 = sc_s2 + NN;                     // N
    float* disb  = sc_d2 + NN;                     // N
    float* poolb = disb + NN;                      // B*64
    float* cntb  = poolb + NB * 64;                // B
    int*   degi  = (int*)(cntb + NB);              // N
    int*   row_ptr = degi + NN;                    // N+1
    int*   cursor  = row_ptr + NN + 1;             // N
    int*   csr_src = cursor + NN;                  // NE2

    int off[NSEG]; int o = 0;
    for (int s = 0; s < NSEG; ++s) { off[s] = o; o += kSegN[s]; }
    float* W1f  = wf + off[0];  float* as1f = wf + off[1];  float* ad1f = wf + off[2];
    float* b1f  = wf + off[3];  float* W2f  = wf + off[4];  float* as2f = wf + off[5];
    float* ad2f = wf + off[6];  float* b2f  = wf + off[7];  float* Wgf  = wf + off[8];
    float* bgf  = wf + off[9];  float* bn1g = wf + off[10]; float* bn1b = wf + off[11];
    float* bn2g = wf + off[12]; float* bn2b = wf + off[13]; float* bn3g = wf + off[14];
    float* bn3b = wf + off[15]; float* l1Wf = wf + off[16]; float* l1bf = wf + off[17];
    float* l2Wf = wf + off[18]; float* l2bf = wf + off[19];

    float* h1 = bufA;                          // [N,256]
    float* x1 = bufB;                          // [N,256]
    float* h2 = bufA;                          // [N,128] (h1 dead after agg1)  -- NOTE: overlaps h1
    float* x2 = bufA + (size_t)NN * 128;       // [N,128]
    float* hg = bufB;                          // [N,64]  (x1 dead after gemm2)

    // ---- dtype detect + canonicalize ----
    det_k<<<1, 256, 0, stream>>>((const unsigned*)x_raw, flag);
    conv_x_k<<<(NN * 128 + 255) / 256, 256, 0, stream>>>(x_raw, xf, flag);
    SegArgs sa;
    for (int s = 0; s < NSEG; ++s) { sa.src[s] = d_in[kSegIn[s]]; sa.n[s] = kSegN[s]; sa.off[s] = off[s]; }
    conv_w_k<<<1, 256, 0, stream>>>(sa, wf, flag);

    // ---- CSR build (by destination) ----
    hipMemsetAsync(degi, 0, NN * sizeof(int), stream);
    hipMemsetAsync(poolb, 0, (size_t)(NB * 64 + NB) * sizeof(float), stream);
    deg_k<<<(NE2 + 255) / 256, 256, 0, stream>>>(ei, degi);
    scan_k<<<1, 1024, 0, stream>>>(degi, row_ptr, cursor);
    scatter_k<<<(NE2 + 255) / 256, 256, 0, stream>>>(ei, cursor, csr_src);
    dis_k<<<(NN + 255) / 256, 256, 0, stream>>>(row_ptr, disb);

    // ---- GAT layer 1 ----
    gemm_k<128, 256><<<dim3(782, 4), 256, 0, stream>>>(xf, W1f, h1, NN);
    scores1_k<<<12500, 256, 0, stream>>>(h1, as1f, ad1f, sc_s1, sc_d1);
    agg1_k<<<12500, 256, 0, stream>>>(row_ptr, csr_src, (const float4*)h1,
                                      (const float4*)sc_s1, (const float4*)sc_d1,
                                      (const float4*)b1f, (const float4*)bn1g,
                                      (const float4*)bn1b, (float4*)x1);

    // ---- GAT layer 2 ----
    gemm_k<256, 128><<<dim3(782, 2), 256, 0, stream>>>(x1, W2f, h2, NN);
    scores2_k<<<12500, 256, 0, stream>>>(h2, as2f, ad2f, sc_s2, sc_d2);
    agg2_k<<<12500, 256, 0, stream>>>(row_ptr, csr_src, (const float2*)h2,
                                      sc_s2, sc_d2,
                                      (const float2*)b2f, (const float2*)bn2g,
                                      (const float2*)bn2b, (float2*)x2);

    // ---- GCN + pool ----
    gemm_k<128, 64><<<dim3(782, 1), 256, 0, stream>>>(x2, Wgf, hg, NN);
    gcn_k<<<12500, 256, 0, stream>>>(row_ptr, csr_src, hg, disb, bgf, batch, poolb, cntb);

    // ---- MLP head ----
    mlp_k<<<NB, 128, 0, stream>>>(poolb, cntb, l1Wf, l1bf, bn3g, bn3b, l2Wf, l2bf, d_out, flag);
}

// Round 4
// 827.302 us; speedup vs baseline: 2.3857x; 1.1118x over previous
//
#include <hip/hip_runtime.h>
#include <hip/hip_bf16.h>

// Problem constants (fixed by the harness)
#define NN  50000      // nodes
#define EE  800000     // edges before self-loops
#define NE2 850000     // edges + self-loops
#define NB  512        // graphs
// GAT1: F=128 -> 4 heads x 64 (256). GAT2: 256 -> 1 head x 128. GCN: 128 -> 64.

#define BN_RS 0.9999950000374997f   // 1/sqrt(1+1e-5)

__device__ __forceinline__ float bf2f(__hip_bfloat16 v) { return __bfloat162float(v); }
__device__ __forceinline__ float lrelu01(float v) { return v > 0.f ? v : 0.01f * v; }
__device__ __forceinline__ float lrelu02(float v) { return v > 0.f ? v : 0.2f * v; }

__device__ __forceinline__ void edge_sd(const int* __restrict__ ei, int e, int& s, int& d) {
    if (e < EE) { s = ei[e]; d = ei[EE + e]; }
    else        { s = e - EE; d = e - EE; }      // self-loop
}

// ---------------- dtype detector (bf16 vs fp32 inputs) ----------------
__global__ __launch_bounds__(256) void det_k(const unsigned* __restrict__ xw, int* __restrict__ flag) {
    __shared__ int cnt;
    if (threadIdx.x == 0) cnt = 0;
    __syncthreads();
    int c = 0;
#pragma unroll
    for (int k = 0; k < 4; ++k) {
        unsigned w = xw[threadIdx.x * 4 + k];
        unsigned ef = (w >> 7) & 0xFFu;
        if (ef >= 100u && ef <= 140u) c++;
    }
    atomicAdd(&cnt, c);
    __syncthreads();
    if (threadIdx.x == 0) *flag = (cnt > 512) ? 1 : 0;   // 1 = bf16 inputs
}

__global__ __launch_bounds__(256) void conv_x_k(const void* __restrict__ x, float* __restrict__ xf,
                                                const int* __restrict__ flag) {
    bool bf = (*flag != 0);
    size_t i = (size_t)blockIdx.x * 256 + threadIdx.x;
    if (i >= (size_t)NN * 128) return;
    xf[i] = bf ? bf2f(((const __hip_bfloat16*)x)[i]) : ((const float*)x)[i];
}

#define NSEG 20
#define WTOT 85578
struct SegArgs { const void* src[NSEG]; int off[NSEG]; };

// grid-parallel weight conversion: each thread finds its segment by offset compare
__global__ __launch_bounds__(256) void conv_w_k(SegArgs a, float* __restrict__ wf,
                                                const int* __restrict__ flag) {
    bool bf = (*flag != 0);
    int i = blockIdx.x * 256 + threadIdx.x;
    if (i >= WTOT) return;
    int s = 0;
#pragma unroll
    for (int k = 1; k < NSEG; ++k) if (i >= a.off[k]) s = k;
    int local = i - a.off[s];
    wf[i] = bf ? bf2f(((const __hip_bfloat16*)a.src[s])[local]) : ((const float*)a.src[s])[local];
}

// ---------------- CSR build: deg -> scan -> scatter ----------------
__global__ __launch_bounds__(256) void deg_k(const int* __restrict__ ei, int* __restrict__ degi) {
    int e = blockIdx.x * 256 + threadIdx.x;
    if (e >= NE2) return;
    int s, d; edge_sd(ei, e, s, d);
    atomicAdd(&degi[d], 1);
}

__global__ __launch_bounds__(1024) void scan_k(const int* __restrict__ degi,
                                               int* __restrict__ row_ptr,
                                               int* __restrict__ cursor) {
    __shared__ int ps[1024];
    int t = threadIdx.x;
    int start = t * 49;
    int stop = start + 49 < NN ? start + 49 : NN;
    if (start > NN) start = NN;
    int s = 0;
    for (int i = start; i < stop; ++i) s += degi[i];
    ps[t] = s;
    __syncthreads();
    for (int off = 1; off < 1024; off <<= 1) {
        int v = (t >= off) ? ps[t - off] : 0;
        __syncthreads();
        ps[t] += v;
        __syncthreads();
    }
    int base = (t == 0) ? 0 : ps[t - 1];
    for (int i = start; i < stop; ++i) {
        row_ptr[i] = base; cursor[i] = base;
        base += degi[i];
    }
    if (t == 1023) row_ptr[NN] = ps[1023];
}

__global__ __launch_bounds__(256) void scatter_k(const int* __restrict__ ei,
                                                 int* __restrict__ cursor,
                                                 int* __restrict__ csr_src) {
    int e = blockIdx.x * 256 + threadIdx.x;
    if (e >= NE2) return;
    int s, d; edge_sd(ei, e, s, d);
    int pos = atomicAdd(&cursor[d], 1);
    csr_src[pos] = s;
}

__global__ __launch_bounds__(256) void dis_k(const int* __restrict__ row_ptr, float* __restrict__ dis) {
    int n = blockIdx.x * 256 + threadIdx.x;
    if (n >= NN) return;
    int dg = row_ptr[n + 1] - row_ptr[n];
    dis[n] = dg > 0 ? rsqrtf((float)dg) : 0.f;
}

// ---------------- Tiled fp32 GEMM: C[M x NCOLS] = A[M x K] @ W[K x NCOLS] ----------------
template <int K, int NCOLS>
__global__ __launch_bounds__(256) void gemm_k(const float* __restrict__ A,
                                              const float* __restrict__ W,
                                              float* __restrict__ C, int M) {
    __shared__ float As[16][64];   // [k][m]
    __shared__ float Ws[16][64];   // [k][n]
    const int tid = threadIdx.x;
    const int bm = blockIdx.x * 64;
    const int bn = blockIdx.y * 64;
    const int tx = tid & 15, ty = tid >> 4;
    const int lm = tid >> 2, lk = (tid & 3) << 2;
    const int wk = tid >> 4, wc = (tid & 15) << 2;
    float acc[4][4] = {};
    for (int k0 = 0; k0 < K; k0 += 16) {
        float a0 = 0.f, a1 = 0.f, a2 = 0.f, a3 = 0.f, w0, w1, w2, w3;
        int gm = bm + lm;
        if (gm < M) {
            const float* p = A + (size_t)gm * K + k0 + lk;
            a0 = p[0]; a1 = p[1]; a2 = p[2]; a3 = p[3];
        }
        {
            const float* p = W + (size_t)(k0 + wk) * NCOLS + bn + wc;
            w0 = p[0]; w1 = p[1]; w2 = p[2]; w3 = p[3];
        }
        __syncthreads();
        As[lk + 0][lm] = a0; As[lk + 1][lm] = a1; As[lk + 2][lm] = a2; As[lk + 3][lm] = a3;
        Ws[wk][wc + 0] = w0; Ws[wk][wc + 1] = w1; Ws[wk][wc + 2] = w2; Ws[wk][wc + 3] = w3;
        __syncthreads();
#pragma unroll
        for (int kk = 0; kk < 16; ++kk) {
            float av[4], wv[4];
#pragma unroll
            for (int i = 0; i < 4; ++i) av[i] = As[kk][ty * 4 + i];
#pragma unroll
            for (int j = 0; j < 4; ++j) wv[j] = Ws[kk][tx * 4 + j];
#pragma unroll
            for (int i = 0; i < 4; ++i)
#pragma unroll
                for (int j = 0; j < 4; ++j) acc[i][j] = fmaf(av[i], wv[j], acc[i][j]);
        }
    }
#pragma unroll
    for (int i = 0; i < 4; ++i) {
        int gm = bm + ty * 4 + i;
        if (gm < M) {
            float* cp = C + (size_t)gm * NCOLS + bn + tx * 4;
            cp[0] = acc[i][0]; cp[1] = acc[i][1]; cp[2] = acc[i][2]; cp[3] = acc[i][3];
        }
    }
}

// ---------------- attention scores ----------------
__global__ __launch_bounds__(256) void scores1_k(const float* __restrict__ h1,
                                                 const float* __restrict__ a_src,
                                                 const float* __restrict__ a_dst,
                                                 float* __restrict__ sc_s, float* __restrict__ sc_d) {
    int n = (blockIdx.x * 256 + threadIdx.x) >> 6;
    int lane = threadIdx.x & 63;
    if (n >= NN) return;
#pragma unroll
    for (int h = 0; h < 4; ++h) {
        float v = h1[(size_t)n * 256 + h * 64 + lane];
        float ps = v * a_src[h * 64 + lane];
        float pd = v * a_dst[h * 64 + lane];
#pragma unroll
        for (int off = 32; off; off >>= 1) { ps += __shfl_down(ps, off); pd += __shfl_down(pd, off); }
        if (lane == 0) { sc_s[n * 4 + h] = ps; sc_d[n * 4 + h] = pd; }
    }
}

__global__ __launch_bounds__(256) void scores2_k(const float* __restrict__ h2,
                                                 const float* __restrict__ a_src,
                                                 const float* __restrict__ a_dst,
                                                 float* __restrict__ sc_s, float* __restrict__ sc_d) {
    int n = (blockIdx.x * 256 + threadIdx.x) >> 6;
    int lane = threadIdx.x & 63;
    if (n >= NN) return;
    float v0 = h2[(size_t)n * 128 + lane];
    float v1 = h2[(size_t)n * 128 + 64 + lane];
    float ps = v0 * a_src[lane] + v1 * a_src[64 + lane];
    float pd = v0 * a_dst[lane] + v1 * a_dst[64 + lane];
#pragma unroll
    for (int off = 32; off; off >>= 1) { ps += __shfl_down(ps, off); pd += __shfl_down(pd, off); }
    if (lane == 0) { sc_s[n] = ps; sc_d[n] = pd; }
}

__device__ __forceinline__ float sel4(float4 v, int head) {
    float ab = (head & 1) ? v.y : v.x;
    float cd = (head & 1) ? v.w : v.z;
    return (head & 2) ? cd : ab;
}

// ---------------- GAT1 aggregate: wave per dst node, scalar broadcast loads, unroll x2 ------
// Softmax normalization is linear: out = (sum_e exp(e)*h[src]) / (sum_e exp(e)).
__global__ __launch_bounds__(256) void agg1_k(const int* __restrict__ row_ptr,
                                              const int* __restrict__ csr_src,
                                              const float4* __restrict__ h1,    // [N*64]
                                              const float4* __restrict__ sc_s4, // [N]
                                              const float4* __restrict__ sc_d4, // [N]
                                              const float4* __restrict__ b1,    // [64]
                                              const float4* __restrict__ g1,
                                              const float4* __restrict__ bb1,
                                              float4* __restrict__ x1) {
    int n = (blockIdx.x * 256 + threadIdx.x) >> 6;
    int lane = threadIdx.x & 63;
    if (n >= NN) return;
    int row = row_ptr[n], end = row_ptr[n + 1];
    int head = lane >> 4;
    float scd_h = sel4(sc_d4[n], head);
    float4 acc = {0.f, 0.f, 0.f, 0.f};
    float den = 0.f;
    int c = row;
    for (; c + 1 < end; c += 2) {
        int s0 = csr_src[c], s1 = csr_src[c + 1];
        float4 scs0 = sc_s4[s0], scs1 = sc_s4[s1];
        float4 hv0 = h1[(size_t)s0 * 64 + lane];
        float4 hv1 = h1[(size_t)s1 * 64 + lane];
        float e0 = __expf(lrelu02(sel4(scs0, head) + scd_h));
        float e1 = __expf(lrelu02(sel4(scs1, head) + scd_h));
        den += e0 + e1;
        acc.x = fmaf(hv0.x, e0, fmaf(hv1.x, e1, acc.x));
        acc.y = fmaf(hv0.y, e0, fmaf(hv1.y, e1, acc.y));
        acc.z = fmaf(hv0.z, e0, fmaf(hv1.z, e1, acc.z));
        acc.w = fmaf(hv0.w, e0, fmaf(hv1.w, e1, acc.w));
    }
    if (c < end) {
        int s0 = csr_src[c];
        float4 scs0 = sc_s4[s0];
        float4 hv0 = h1[(size_t)s0 * 64 + lane];
        float e0 = __expf(lrelu02(sel4(scs0, head) + scd_h));
        den += e0;
        acc.x = fmaf(hv0.x, e0, acc.x);
        acc.y = fmaf(hv0.y, e0, acc.y);
        acc.z = fmaf(hv0.z, e0, acc.z);
        acc.w = fmaf(hv0.w, e0, acc.w);
    }
    float inv = 1.f / (den + 1e-16f);
    float4 bb = b1[lane], gg = g1[lane], be = bb1[lane];
    float4 o;
    o.x = lrelu01(acc.x * inv + bb.x) * (gg.x * BN_RS) + be.x;
    o.y = lrelu01(acc.y * inv + bb.y) * (gg.y * BN_RS) + be.y;
    o.z = lrelu01(acc.z * inv + bb.z) * (gg.z * BN_RS) + be.z;
    o.w = lrelu01(acc.w * inv + bb.w) * (gg.w * BN_RS) + be.w;
    x1[(size_t)n * 64 + lane] = o;
}

// ---------------- GAT2 aggregate: 2 half-wave groups, 2 edges in flight ----------------
__global__ __launch_bounds__(256) void agg2_k(const int* __restrict__ row_ptr,
                                              const int* __restrict__ csr_src,
                                              const float4* __restrict__ h2,   // [N*32]
                                              const float* __restrict__ sc_s,  // [N]
                                              const float* __restrict__ sc_d,
                                              const float4* __restrict__ b2,   // [32]
                                              const float4* __restrict__ g2,
                                              const float4* __restrict__ bb2,
                                              float4* __restrict__ x2) {
    int n = (blockIdx.x * 256 + threadIdx.x) >> 6;
    int lane = threadIdx.x & 63;
    if (n >= NN) return;
    int g = lane >> 5, sl = lane & 31;
    int row = row_ptr[n], end = row_ptr[n + 1];
    float scd = sc_d[n];
    float4 acc = {0.f, 0.f, 0.f, 0.f};
    float den = 0.f;
    for (int c = row + g; c < end; c += 2) {
        int s = csr_src[c];
        float e = __expf(lrelu02(sc_s[s] + scd));
        den += e;
        float4 hv = h2[(size_t)s * 32 + sl];
        acc.x = fmaf(hv.x, e, acc.x);
        acc.y = fmaf(hv.y, e, acc.y);
        acc.z = fmaf(hv.z, e, acc.z);
        acc.w = fmaf(hv.w, e, acc.w);
    }
    den += __shfl_xor(den, 32);
    acc.x += __shfl_xor(acc.x, 32);
    acc.y += __shfl_xor(acc.y, 32);
    acc.z += __shfl_xor(acc.z, 32);
    acc.w += __shfl_xor(acc.w, 32);
    if (g == 0) {
        float inv = 1.f / (den + 1e-16f);
        float4 bb = b2[sl], gg = g2[sl], be = bb2[sl];
        float4 o;
        o.x = lrelu01(acc.x * inv + bb.x) * (gg.x * BN_RS) + be.x;
        o.y = lrelu01(acc.y * inv + bb.y) * (gg.y * BN_RS) + be.y;
        o.z = lrelu01(acc.z * inv + bb.z) * (gg.z * BN_RS) + be.z;
        o.w = lrelu01(acc.w * inv + bb.w) * (gg.w * BN_RS) + be.w;
        x2[(size_t)n * 32 + sl] = o;
    }
}

// ---------------- GCN aggregate + lrelu + pool: 4 groups x 16 lanes, 4 edges in flight -----
__global__ __launch_bounds__(256) void gcn_k(const int* __restrict__ row_ptr,
                                             const int* __restrict__ csr_src,
                                             const float4* __restrict__ hg,   // [N*16]
                                             const float* __restrict__ dis,
                                             const float4* __restrict__ bg,   // [16]
                                             const int* __restrict__ batch,
                                             float* __restrict__ pool, float* __restrict__ cnt) {
    int n = (blockIdx.x * 256 + threadIdx.x) >> 6;
    int lane = threadIdx.x & 63;
    if (n >= NN) return;
    int g = lane >> 4, sl = lane & 15;
    int row = row_ptr[n], end = row_ptr[n + 1];
    float dn = dis[n];
    float4 acc = {0.f, 0.f, 0.f, 0.f};
    for (int c = row + g; c < end; c += 4) {
        int s = csr_src[c];
        float w = dis[s];
        float4 hv = hg[(size_t)s * 16 + sl];
        acc.x = fmaf(hv.x, w, acc.x);
        acc.y = fmaf(hv.y, w, acc.y);
        acc.z = fmaf(hv.z, w, acc.z);
        acc.w = fmaf(hv.w, w, acc.w);
    }
#pragma unroll
    for (int off = 16; off <= 32; off <<= 1) {
        acc.x += __shfl_xor(acc.x, off);
        acc.y += __shfl_xor(acc.y, off);
        acc.z += __shfl_xor(acc.z, off);
        acc.w += __shfl_xor(acc.w, off);
    }
    if (g == 0) {
        float4 bb = bg[sl];
        int b = batch[n];
        atomicAdd(&pool[b * 64 + sl * 4 + 0], lrelu01(acc.x * dn + bb.x));
        atomicAdd(&pool[b * 64 + sl * 4 + 1], lrelu01(acc.y * dn + bb.y));
        atomicAdd(&pool[b * 64 + sl * 4 + 2], lrelu01(acc.z * dn + bb.z));
        atomicAdd(&pool[b * 64 + sl * 4 + 3], lrelu01(acc.w * dn + bb.w));
        if (sl == 0) atomicAdd(&cnt[b], 1.0f);
    }
}

// ---------------- per-graph MLP head; output dtype per flag ----------------
__global__ __launch_bounds__(128) void mlp_k(const float* __restrict__ pool,
                                             const float* __restrict__ cnt,
                                             const float* __restrict__ l1W,
                                             const float* __restrict__ l1b,
                                             const float* __restrict__ g3,
                                             const float* __restrict__ b3,
                                             const float* __restrict__ l2W,
                                             const float* __restrict__ l2b,
                                             void* __restrict__ outp,
                                             const int* __restrict__ flag) {
    __shared__ float pl[64];
    __shared__ float y1s[128];
    int g = blockIdx.x, t = threadIdx.x;
    if (t < 64) {
        float c = cnt[g];
        c = c < 1.f ? 1.f : c;
        pl[t] = pool[g * 64 + t] / c;
    }
    __syncthreads();
    float acc = l1b[t];
#pragma unroll 8
    for (int j = 0; j < 64; ++j) acc = fmaf(pl[j], l1W[j * 128 + t], acc);
    acc = acc * (g3[t] * BN_RS) + b3[t];
    y1s[t] = lrelu01(acc);
    __syncthreads();
    if (t < 10) {
        float o = l2b[t];
#pragma unroll 8
        for (int j = 0; j < 128; ++j) o = fmaf(y1s[j], l2W[j * 10 + t], o);
        if (*flag) ((__hip_bfloat16*)outp)[g * 10 + t] = __float2bfloat16(o);
        else       ((float*)outp)[g * 10 + t] = o;
    }
}

// weight segment sizes (W1,as1,ad1,b1,W2,as2,ad2,b2,Wg,bg,bn1g,bn1b,bn2g,bn2b,bn3g,bn3b,l1W,l1b,l2W,l2b)
static const int kSegN[NSEG]  = {32768, 256, 256, 256, 32768, 128, 128, 128, 8192, 64,
                                 256, 256, 128, 128, 128, 128, 8192, 128, 1280, 10};
static const int kSegIn[NSEG] = {3, 4, 5, 6, 7, 8, 9, 10, 11, 12, 13, 14, 15, 16, 17, 18, 19, 20, 21, 22};

extern "C" void kernel_launch(void* const* d_in, const int* in_sizes, int n_in,
                              void* d_out, int out_size, void* d_ws, size_t ws_size,
                              hipStream_t stream) {
    const void* x_raw = d_in[0];
    const int*  ei    = (const int*)d_in[1];
    const int*  batch = (const int*)d_in[2];

    // ---- workspace layout ----
    int*   flag = (int*)d_ws;
    float* ws   = (float*)d_ws;
    float* xf   = ws + 16;                         // N*128
    float* wf   = xf + (size_t)NN * 128;           // 85584 (85578 used)
    float* bufA = wf + 85584;                      // N*256
    float* bufB = bufA + (size_t)NN * 256;         // N*256
    float* sc_s1 = bufB + (size_t)NN * 256;        // N*4
    float* sc_d1 = sc_s1 + (size_t)NN * 4;         // N*4
    float* sc_s2 = sc_d1 + (size_t)NN * 4;         // N
    float* sc_d2 = sc_s2 + NN;                     // N
    float* disb  = sc_d2 + NN;                     // N
    float* poolb = disb + NN;                      // B*64
    float* cntb  = poolb + NB * 64;                // B
    int*   degi  = (int*)(cntb + NB);              // N
    int*   row_ptr = degi + NN;                    // N+1
    int*   cursor  = row_ptr + NN + 1;             // N
    int*   csr_src = cursor + NN;                  // NE2

    int off[NSEG]; int o = 0;
    for (int s = 0; s < NSEG; ++s) { off[s] = o; o += kSegN[s]; }
    float* W1f  = wf + off[0];  float* as1f = wf + off[1];  float* ad1f = wf + off[2];
    float* b1f  = wf + off[3];  float* W2f  = wf + off[4];  float* as2f = wf + off[5];
    float* ad2f = wf + off[6];  float* b2f  = wf + off[7];  float* Wgf  = wf + off[8];
    float* bgf  = wf + off[9];  float* bn1g = wf + off[10]; float* bn1b = wf + off[11];
    float* bn2g = wf + off[12]; float* bn2b = wf + off[13]; float* bn3g = wf + off[14];
    float* bn3b = wf + off[15]; float* l1Wf = wf + off[16]; float* l1bf = wf + off[17];
    float* l2Wf = wf + off[18]; float* l2bf = wf + off[19];

    float* h1 = bufA;                          // [N,256]
    float* x1 = bufB;                          // [N,256]
    float* h2 = bufA;                          // [N,128] (h1 dead after agg1)
    float* x2 = bufA + (size_t)NN * 128;       // [N,128]
    float* hg = bufB;                          // [N,64]  (x1 dead after gemm2)

    // ---- dtype detect + canonicalize ----
    det_k<<<1, 256, 0, stream>>>((const unsigned*)x_raw, flag);
    conv_x_k<<<(NN * 128 + 255) / 256, 256, 0, stream>>>(x_raw, xf, flag);
    SegArgs sa;
    for (int s = 0; s < NSEG; ++s) { sa.src[s] = d_in[kSegIn[s]]; sa.off[s] = off[s]; }
    conv_w_k<<<(WTOT + 255) / 256, 256, 0, stream>>>(sa, wf, flag);

    // ---- CSR build (by destination) ----
    hipMemsetAsync(degi, 0, NN * sizeof(int), stream);
    hipMemsetAsync(poolb, 0, (size_t)(NB * 64 + NB) * sizeof(float), stream);
    deg_k<<<(NE2 + 255) / 256, 256, 0, stream>>>(ei, degi);
    scan_k<<<1, 1024, 0, stream>>>(degi, row_ptr, cursor);
    scatter_k<<<(NE2 + 255) / 256, 256, 0, stream>>>(ei, cursor, csr_src);
    dis_k<<<(NN + 255) / 256, 256, 0, stream>>>(row_ptr, disb);

    // ---- GAT layer 1 ----
    gemm_k<128, 256><<<dim3(782, 4), 256, 0, stream>>>(xf, W1f, h1, NN);
    scores1_k<<<12500, 256, 0, stream>>>(h1, as1f, ad1f, sc_s1, sc_d1);
    agg1_k<<<12500, 256, 0, stream>>>(row_ptr, csr_src, (const float4*)h1,
                                      (const float4*)sc_s1, (const float4*)sc_d1,
                                      (const float4*)b1f, (const float4*)bn1g,
                                      (const float4*)bn1b, (float4*)x1);

    // ---- GAT layer 2 ----
    gemm_k<256, 128><<<dim3(782, 2), 256, 0, stream>>>(x1, W2f, h2, NN);
    scores2_k<<<12500, 256, 0, stream>>>(h2, as2f, ad2f, sc_s2, sc_d2);
    agg2_k<<<12500, 256, 0, stream>>>(row_ptr, csr_src, (const float4*)h2,
                                      sc_s2, sc_d2,
                                      (const float4*)b2f, (const float4*)bn2g,
                                      (const float4*)bn2b, (float4*)x2);

    // ---- GCN + pool ----
    gemm_k<128, 64><<<dim3(782, 1), 256, 0, stream>>>(x2, Wgf, hg, NN);
    gcn_k<<<12500, 256, 0, stream>>>(row_ptr, csr_src, (const float4*)hg, disb,
                                     (const float4*)bgf, batch, poolb, cntb);

    // ---- MLP head ----
    mlp_k<<<NB, 128, 0, stream>>>(poolb, cntb, l1Wf, l1bf, bn3g, bn3b, l2Wf, l2bf, d_out, flag);
}

// Round 5
// 695.901 us; speedup vs baseline: 2.8361x; 1.1888x over previous
//
#include <hip/hip_runtime.h>
#include <hip/hip_bf16.h>

// Problem constants (fixed by the harness)
#define NN  50000      // nodes
#define EE  800000     // edges before self-loops
#define NE2 850000     // edges + self-loops
#define NB  512        // graphs
#define NRT 3125       // row tiles of 16 (NN = 3125*16 exactly)
// GAT1: F=128 -> 4 heads x 64 (256). GAT2: 256 -> 1 head x 128. GCN: 128 -> 64.

#define BN_RS 0.9999950000374997f   // 1/sqrt(1+1e-5)

typedef __attribute__((ext_vector_type(8))) short short8;
typedef __attribute__((ext_vector_type(4))) float f32x4;

__device__ __forceinline__ float bf2f(__hip_bfloat16 v) { return __bfloat162float(v); }
__device__ __forceinline__ unsigned short f2b(float v) {
    __hip_bfloat16 b = __float2bfloat16(v);
    return *reinterpret_cast<unsigned short*>(&b);
}
__device__ __forceinline__ float lrelu01(float v) { return v > 0.f ? v : 0.01f * v; }
__device__ __forceinline__ float lrelu02(float v) { return v > 0.f ? v : 0.2f * v; }

__device__ __forceinline__ void edge_sd(const int* __restrict__ ei, int e, int& s, int& d) {
    if (e < EE) { s = ei[e]; d = ei[EE + e]; }
    else        { s = e - EE; d = e - EE; }      // self-loop
}

// ---------------- dtype detector (bf16 vs fp32 inputs) ----------------
__global__ __launch_bounds__(256) void det_k(const unsigned* __restrict__ xw, int* __restrict__ flag) {
    __shared__ int cnt;
    if (threadIdx.x == 0) cnt = 0;
    __syncthreads();
    int c = 0;
#pragma unroll
    for (int k = 0; k < 4; ++k) {
        unsigned w = xw[threadIdx.x * 4 + k];
        unsigned ef = (w >> 7) & 0xFFu;
        if (ef >= 100u && ef <= 140u) c++;
    }
    atomicAdd(&cnt, c);
    __syncthreads();
    if (threadIdx.x == 0) *flag = (cnt > 512) ? 1 : 0;   // 1 = bf16 inputs
}

// canonicalize x to bf16 (straight copy if already bf16)
__global__ __launch_bounds__(256) void conv_x_k(const void* __restrict__ x,
                                                unsigned short* __restrict__ xb,
                                                const int* __restrict__ flag) {
    bool bf = (*flag != 0);
    size_t i = (size_t)blockIdx.x * 256 + threadIdx.x;
    if (i >= (size_t)NN * 128) return;
    xb[i] = bf ? ((const unsigned short*)x)[i] : f2b(((const float*)x)[i]);
}

#define NSEG 20
#define WTOT 85578
struct SegArgs { const void* src[NSEG]; int off[NSEG]; };

// grid-parallel weight conversion to canonical fp32
__global__ __launch_bounds__(256) void conv_w_k(SegArgs a, float* __restrict__ wf,
                                                const int* __restrict__ flag) {
    bool bf = (*flag != 0);
    int i = blockIdx.x * 256 + threadIdx.x;
    if (i >= WTOT) return;
    int s = 0;
#pragma unroll
    for (int k = 1; k < NSEG; ++k) if (i >= a.off[k]) s = k;
    int local = i - a.off[s];
    wf[i] = bf ? bf2f(((const __hip_bfloat16*)a.src[s])[local]) : ((const float*)a.src[s])[local];
}

// transpose W[K][N] fp32 -> Wt[N][K] bf16 (B^T layout for MFMA b-frags)
template <int K, int N>
__global__ __launch_bounds__(256) void tr_k(const float* __restrict__ W, unsigned short* __restrict__ Wt) {
    int i = blockIdx.x * 256 + threadIdx.x;
    if (i >= K * N) return;
    int k = i / N, n = i - k * N;
    Wt[n * K + k] = f2b(W[i]);
}

// ---------------- CSR build: deg -> scan -> scatter ----------------
__global__ __launch_bounds__(256) void deg_k(const int* __restrict__ ei, int* __restrict__ degi) {
    int e = blockIdx.x * 256 + threadIdx.x;
    if (e >= NE2) return;
    int s, d; edge_sd(ei, e, s, d);
    atomicAdd(&degi[d], 1);
}

__global__ __launch_bounds__(1024) void scan_k(const int* __restrict__ degi,
                                               int* __restrict__ row_ptr,
                                               int* __restrict__ cursor) {
    __shared__ int ps[1024];
    int t = threadIdx.x;
    int start = t * 49;
    int stop = start + 49 < NN ? start + 49 : NN;
    if (start > NN) start = NN;
    int s = 0;
    for (int i = start; i < stop; ++i) s += degi[i];
    ps[t] = s;
    __syncthreads();
    for (int off = 1; off < 1024; off <<= 1) {
        int v = (t >= off) ? ps[t - off] : 0;
        __syncthreads();
        ps[t] += v;
        __syncthreads();
    }
    int base = (t == 0) ? 0 : ps[t - 1];
    for (int i = start; i < stop; ++i) {
        row_ptr[i] = base; cursor[i] = base;
        base += degi[i];
    }
    if (t == 1023) row_ptr[NN] = ps[1023];
}

__global__ __launch_bounds__(256) void scatter_k(const int* __restrict__ ei,
                                                 int* __restrict__ cursor,
                                                 int* __restrict__ csr_src) {
    int e = blockIdx.x * 256 + threadIdx.x;
    if (e >= NE2) return;
    int s, d; edge_sd(ei, e, s, d);
    int pos = atomicAdd(&cursor[d], 1);
    csr_src[pos] = s;
}

__global__ __launch_bounds__(256) void dis_k(const int* __restrict__ row_ptr, float* __restrict__ dis) {
    int n = blockIdx.x * 256 + threadIdx.x;
    if (n >= NN) return;
    int dg = row_ptr[n + 1] - row_ptr[n];
    dis[n] = dg > 0 ? rsqrtf((float)dg) : 0.f;
}

// ---------------- MFMA bf16 GEMM: C[M x NCOLS] f32 = A[M x K] bf16 @ Bt[NCOLS x K] bf16 ----
// One wave computes a 16x64 tile: 1 a-frag + 4 b-frags per k-step, 4 MFMAs.
// A-frag: lane holds A[m=lane&15][k0 + (lane>>4)*8 + 0..7]; b-frag same with n=lane&15.
// C/D: col=lane&15, row=(lane>>4)*4+reg  [guide §3, m89/m91-verified]
template <int K, int NCOLS>
__global__ __launch_bounds__(256) void mgemm_k(const short* __restrict__ A,
                                               const short* __restrict__ Bt,
                                               float* __restrict__ C) {
    constexpr int CG = NCOLS / 64;
    int wave = threadIdx.x >> 6, lane = threadIdx.x & 63;
    int gidx = blockIdx.x * 4 + wave;
    if (gidx >= NRT * CG) return;
    int rt = gidx / CG, cg = gidx - rt * CG;
    int l15 = lane & 15, quad = lane >> 4;
    const short* ap = A + (size_t)(rt * 16 + l15) * K + quad * 8;
    const short* bp = Bt + (size_t)(cg * 64 + l15) * K + quad * 8;
    f32x4 acc[4] = {};
    for (int k0 = 0; k0 < K; k0 += 32) {
        short8 a = *(const short8*)(ap + k0);
#pragma unroll
        for (int j = 0; j < 4; ++j) {
            short8 b = *(const short8*)(bp + (size_t)j * 16 * K + k0);
            acc[j] = __builtin_amdgcn_mfma_f32_16x16x32_bf16(a, b, acc[j], 0, 0, 0);
        }
    }
#pragma unroll
    for (int j = 0; j < 4; ++j) {
        int n = cg * 64 + j * 16 + l15;
#pragma unroll
        for (int r = 0; r < 4; ++r) {
            int row = rt * 16 + quad * 4 + r;
            C[(size_t)row * NCOLS + n] = acc[j][r];
        }
    }
}

// ---------------- attention scores ----------------
__global__ __launch_bounds__(256) void scores1_k(const float* __restrict__ h1,
                                                 const float* __restrict__ a_src,
                                                 const float* __restrict__ a_dst,
                                                 float* __restrict__ sc_s, float* __restrict__ sc_d) {
    int n = (blockIdx.x * 256 + threadIdx.x) >> 6;
    int lane = threadIdx.x & 63;
    if (n >= NN) return;
#pragma unroll
    for (int h = 0; h < 4; ++h) {
        float v = h1[(size_t)n * 256 + h * 64 + lane];
        float ps = v * a_src[h * 64 + lane];
        float pd = v * a_dst[h * 64 + lane];
#pragma unroll
        for (int off = 32; off; off >>= 1) { ps += __shfl_down(ps, off); pd += __shfl_down(pd, off); }
        if (lane == 0) { sc_s[n * 4 + h] = ps; sc_d[n * 4 + h] = pd; }
    }
}

__global__ __launch_bounds__(256) void scores2_k(const float* __restrict__ h2,
                                                 const float* __restrict__ a_src,
                                                 const float* __restrict__ a_dst,
                                                 float* __restrict__ sc_s, float* __restrict__ sc_d) {
    int n = (blockIdx.x * 256 + threadIdx.x) >> 6;
    int lane = threadIdx.x & 63;
    if (n >= NN) return;
    float v0 = h2[(size_t)n * 128 + lane];
    float v1 = h2[(size_t)n * 128 + 64 + lane];
    float ps = v0 * a_src[lane] + v1 * a_src[64 + lane];
    float pd = v0 * a_dst[lane] + v1 * a_dst[64 + lane];
#pragma unroll
    for (int off = 32; off; off >>= 1) { ps += __shfl_down(ps, off); pd += __shfl_down(pd, off); }
    if (lane == 0) { sc_s[n] = ps; sc_d[n] = pd; }
}

__device__ __forceinline__ float sel4(float4 v, int head) {
    float ab = (head & 1) ? v.y : v.x;
    float cd = (head & 1) ? v.w : v.z;
    return (head & 2) ? cd : ab;
}

// ---------------- GAT1 aggregate: wave per dst node; writes x1 as bf16 ----------------
__global__ __launch_bounds__(256) void agg1_k(const int* __restrict__ row_ptr,
                                              const int* __restrict__ csr_src,
                                              const float4* __restrict__ h1,    // [N*64]
                                              const float4* __restrict__ sc_s4, // [N]
                                              const float4* __restrict__ sc_d4, // [N]
                                              const float4* __restrict__ b1,    // [64]
                                              const float4* __restrict__ g1,
                                              const float4* __restrict__ bb1,
                                              ushort4* __restrict__ x1b) {
    int n = (blockIdx.x * 256 + threadIdx.x) >> 6;
    int lane = threadIdx.x & 63;
    if (n >= NN) return;
    int row = row_ptr[n], end = row_ptr[n + 1];
    int head = lane >> 4;
    float scd_h = sel4(sc_d4[n], head);
    float4 acc = {0.f, 0.f, 0.f, 0.f};
    float den = 0.f;
    int c = row;
    for (; c + 1 < end; c += 2) {
        int s0 = csr_src[c], s1 = csr_src[c + 1];
        float4 scs0 = sc_s4[s0], scs1 = sc_s4[s1];
        float4 hv0 = h1[(size_t)s0 * 64 + lane];
        float4 hv1 = h1[(size_t)s1 * 64 + lane];
        float e0 = __expf(lrelu02(sel4(scs0, head) + scd_h));
        float e1 = __expf(lrelu02(sel4(scs1, head) + scd_h));
        den += e0 + e1;
        acc.x = fmaf(hv0.x, e0, fmaf(hv1.x, e1, acc.x));
        acc.y = fmaf(hv0.y, e0, fmaf(hv1.y, e1, acc.y));
        acc.z = fmaf(hv0.z, e0, fmaf(hv1.z, e1, acc.z));
        acc.w = fmaf(hv0.w, e0, fmaf(hv1.w, e1, acc.w));
    }
    if (c < end) {
        int s0 = csr_src[c];
        float4 scs0 = sc_s4[s0];
        float4 hv0 = h1[(size_t)s0 * 64 + lane];
        float e0 = __expf(lrelu02(sel4(scs0, head) + scd_h));
        den += e0;
        acc.x = fmaf(hv0.x, e0, acc.x);
        acc.y = fmaf(hv0.y, e0, acc.y);
        acc.z = fmaf(hv0.z, e0, acc.z);
        acc.w = fmaf(hv0.w, e0, acc.w);
    }
    float inv = 1.f / (den + 1e-16f);
    float4 bb = b1[lane], gg = g1[lane], be = bb1[lane];
    ushort4 o;
    o.x = f2b(lrelu01(acc.x * inv + bb.x) * (gg.x * BN_RS) + be.x);
    o.y = f2b(lrelu01(acc.y * inv + bb.y) * (gg.y * BN_RS) + be.y);
    o.z = f2b(lrelu01(acc.z * inv + bb.z) * (gg.z * BN_RS) + be.z);
    o.w = f2b(lrelu01(acc.w * inv + bb.w) * (gg.w * BN_RS) + be.w);
    x1b[(size_t)n * 64 + lane] = o;
}

// ---------------- GAT2 aggregate: 2 half-wave groups; writes x2 as bf16 ----------------
__global__ __launch_bounds__(256) void agg2_k(const int* __restrict__ row_ptr,
                                              const int* __restrict__ csr_src,
                                              const float4* __restrict__ h2,   // [N*32]
                                              const float* __restrict__ sc_s,  // [N]
                                              const float* __restrict__ sc_d,
                                              const float4* __restrict__ b2,   // [32]
                                              const float4* __restrict__ g2,
                                              const float4* __restrict__ bb2,
                                              ushort4* __restrict__ x2b) {
    int n = (blockIdx.x * 256 + threadIdx.x) >> 6;
    int lane = threadIdx.x & 63;
    if (n >= NN) return;
    int g = lane >> 5, sl = lane & 31;
    int row = row_ptr[n], end = row_ptr[n + 1];
    float scd = sc_d[n];
    float4 acc = {0.f, 0.f, 0.f, 0.f};
    float den = 0.f;
    for (int c = row + g; c < end; c += 2) {
        int s = csr_src[c];
        float e = __expf(lrelu02(sc_s[s] + scd));
        den += e;
        float4 hv = h2[(size_t)s * 32 + sl];
        acc.x = fmaf(hv.x, e, acc.x);
        acc.y = fmaf(hv.y, e, acc.y);
        acc.z = fmaf(hv.z, e, acc.z);
        acc.w = fmaf(hv.w, e, acc.w);
    }
    den += __shfl_xor(den, 32);
    acc.x += __shfl_xor(acc.x, 32);
    acc.y += __shfl_xor(acc.y, 32);
    acc.z += __shfl_xor(acc.z, 32);
    acc.w += __shfl_xor(acc.w, 32);
    if (g == 0) {
        float inv = 1.f / (den + 1e-16f);
        float4 bb = b2[sl], gg = g2[sl], be = bb2[sl];
        ushort4 o;
        o.x = f2b(lrelu01(acc.x * inv + bb.x) * (gg.x * BN_RS) + be.x);
        o.y = f2b(lrelu01(acc.y * inv + bb.y) * (gg.y * BN_RS) + be.y);
        o.z = f2b(lrelu01(acc.z * inv + bb.z) * (gg.z * BN_RS) + be.z);
        o.w = f2b(lrelu01(acc.w * inv + bb.w) * (gg.w * BN_RS) + be.w);
        x2b[(size_t)n * 32 + sl] = o;
    }
}

// ---------------- GCN aggregate + lrelu -> x3 (coalesced store, NO atomics) ----------------
__global__ __launch_bounds__(256) void gcn_k(const int* __restrict__ row_ptr,
                                             const int* __restrict__ csr_src,
                                             const float4* __restrict__ hg,   // [N*16]
                                             const float* __restrict__ dis,
                                             const float4* __restrict__ bg,   // [16]
                                             float4* __restrict__ x3) {       // [N*16]
    int n = (blockIdx.x * 256 + threadIdx.x) >> 6;
    int lane = threadIdx.x & 63;
    if (n >= NN) return;
    int g = lane >> 4, sl = lane & 15;
    int row = row_ptr[n], end = row_ptr[n + 1];
    float dn = dis[n];
    float4 acc = {0.f, 0.f, 0.f, 0.f};
    for (int c = row + g; c < end; c += 4) {
        int s = csr_src[c];
        float w = dis[s];
        float4 hv = hg[(size_t)s * 16 + sl];
        acc.x = fmaf(hv.x, w, acc.x);
        acc.y = fmaf(hv.y, w, acc.y);
        acc.z = fmaf(hv.z, w, acc.z);
        acc.w = fmaf(hv.w, w, acc.w);
    }
#pragma unroll
    for (int off = 16; off <= 32; off <<= 1) {
        acc.x += __shfl_xor(acc.x, off);
        acc.y += __shfl_xor(acc.y, off);
        acc.z += __shfl_xor(acc.z, off);
        acc.w += __shfl_xor(acc.w, off);
    }
    if (g == 0) {
        float4 bb = bg[sl];
        float4 o;
        o.x = lrelu01(acc.x * dn + bb.x);
        o.y = lrelu01(acc.y * dn + bb.y);
        o.z = lrelu01(acc.z * dn + bb.z);
        o.w = lrelu01(acc.w * dn + bb.w);
        x3[(size_t)n * 16 + sl] = o;
    }
}

// ---------------- graph boundaries: batch is sorted; binary search per graph ----------------
__global__ __launch_bounds__(1024) void bounds_k(const int* __restrict__ batch, int* __restrict__ gstart) {
    int t = threadIdx.x;
    if (t > NB) return;
    int lo = 0, hi = NN;
    while (lo < hi) { int mid = (lo + hi) >> 1; if (batch[mid] < t) lo = mid + 1; else hi = mid; }
    gstart[t] = lo;
}

// ---------------- segmented mean-pool: block per graph, no atomics ----------------
__global__ __launch_bounds__(256) void pool_k(const float* __restrict__ x3,
                                              const int* __restrict__ gstart,
                                              float* __restrict__ pooled) {
    __shared__ float red[4][64];
    int g = blockIdx.x, t = threadIdx.x;
    int c = t & 63, r = t >> 6;
    int s = gstart[g], e = gstart[g + 1];
    float sum = 0.f;
    for (int n = s + r; n < e; n += 4) sum += x3[(size_t)n * 64 + c];
    red[r][c] = sum;
    __syncthreads();
    if (t < 64) {
        float v = red[0][t] + red[1][t] + red[2][t] + red[3][t];
        int cnt = e - s; if (cnt < 1) cnt = 1;
        pooled[g * 64 + t] = v / (float)cnt;
    }
}

// ---------------- per-graph MLP head; output dtype per flag ----------------
__global__ __launch_bounds__(128) void mlp_k(const float* __restrict__ pooled,
                                             const float* __restrict__ l1W,
                                             const float* __restrict__ l1b,
                                             const float* __restrict__ g3,
                                             const float* __restrict__ b3,
                                             const float* __restrict__ l2W,
                                             const float* __restrict__ l2b,
                                             void* __restrict__ outp,
                                             const int* __restrict__ flag) {
    __shared__ float pl[64];
    __shared__ float y1s[128];
    int g = blockIdx.x, t = threadIdx.x;
    if (t < 64) pl[t] = pooled[g * 64 + t];
    __syncthreads();
    float acc = l1b[t];
#pragma unroll 8
    for (int j = 0; j < 64; ++j) acc = fmaf(pl[j], l1W[j * 128 + t], acc);
    acc = acc * (g3[t] * BN_RS) + b3[t];
    y1s[t] = lrelu01(acc);
    __syncthreads();
    if (t < 10) {
        float o = l2b[t];
#pragma unroll 8
        for (int j = 0; j < 128; ++j) o = fmaf(y1s[j], l2W[j * 10 + t], o);
        if (*flag) ((__hip_bfloat16*)outp)[g * 10 + t] = __float2bfloat16(o);
        else       ((float*)outp)[g * 10 + t] = o;
    }
}

// weight segment sizes (W1,as1,ad1,b1,W2,as2,ad2,b2,Wg,bg,bn1g,bn1b,bn2g,bn2b,bn3g,bn3b,l1W,l1b,l2W,l2b)
static const int kSegN[NSEG]  = {32768, 256, 256, 256, 32768, 128, 128, 128, 8192, 64,
                                 256, 256, 128, 128, 128, 128, 8192, 128, 1280, 10};
static const int kSegIn[NSEG] = {3, 4, 5, 6, 7, 8, 9, 10, 11, 12, 13, 14, 15, 16, 17, 18, 19, 20, 21, 22};

extern "C" void kernel_launch(void* const* d_in, const int* in_sizes, int n_in,
                              void* d_out, int out_size, void* d_ws, size_t ws_size,
                              hipStream_t stream) {
    const void* x_raw = d_in[0];
    const int*  ei    = (const int*)d_in[1];
    const int*  batch = (const int*)d_in[2];

    // ---- workspace layout (units: floats unless noted) ----
    int*   flag = (int*)d_ws;
    float* ws   = (float*)d_ws;
    unsigned short* xb = (unsigned short*)(ws + 16);          // N*128 bf16
    float* wf   = ws + 16 + (size_t)NN * 64;                  // 85584 fp32 canonical
    unsigned short* W1t = (unsigned short*)(wf + 85584);      // 32768 bf16 [256][128]
    unsigned short* W2t = W1t + 32768;                        // 32768 bf16 [128][256]
    unsigned short* Wgt = W2t + 32768;                        // 8192  bf16 [64][128]
    float* h1   = (float*)(Wgt + 8192);                       // N*256 (reused as h2 [N,128])
    unsigned short* x1b = (unsigned short*)(h1 + (size_t)NN * 256);  // N*256 bf16
    unsigned short* x2b = x1b + (size_t)NN * 256;             // N*128 bf16
    float* hg   = (float*)(x2b + (size_t)NN * 128);           // N*64
    float* x3   = hg + (size_t)NN * 64;                       // N*64
    float* sc_s1 = x3 + (size_t)NN * 64;                      // N*4
    float* sc_d1 = sc_s1 + (size_t)NN * 4;                    // N*4
    float* sc_s2 = sc_d1 + (size_t)NN * 4;                    // N
    float* sc_d2 = sc_s2 + NN;                                // N
    float* disb  = sc_d2 + NN;                                // N
    float* pooled = disb + NN;                                // B*64
    int*   gstart = (int*)(pooled + NB * 64);                 // B+1
    int*   degi   = gstart + NB + 4;                          // N
    int*   row_ptr = degi + NN;                               // N+1
    int*   cursor  = row_ptr + NN + 1;                        // N
    int*   csr_src = cursor + NN;                             // NE2

    int off[NSEG]; int o = 0;
    for (int s = 0; s < NSEG; ++s) { off[s] = o; o += kSegN[s]; }
    float* W1f  = wf + off[0];  float* as1f = wf + off[1];  float* ad1f = wf + off[2];
    float* b1f  = wf + off[3];  float* W2f  = wf + off[4];  float* as2f = wf + off[5];
    float* ad2f = wf + off[6];  float* b2f  = wf + off[7];  float* Wgf  = wf + off[8];
    float* bgf  = wf + off[9];  float* bn1g = wf + off[10]; float* bn1b = wf + off[11];
    float* bn2g = wf + off[12]; float* bn2b = wf + off[13]; float* bn3g = wf + off[14];
    float* bn3b = wf + off[15]; float* l1Wf = wf + off[16]; float* l1bf = wf + off[17];
    float* l2Wf = wf + off[18]; float* l2bf = wf + off[19];

    float* h2 = h1;   // h1 dead after agg1_k

    // ---- dtype detect + canonicalize ----
    det_k<<<1, 256, 0, stream>>>((const unsigned*)x_raw, flag);
    conv_x_k<<<(NN * 128 + 255) / 256, 256, 0, stream>>>(x_raw, xb, flag);
    SegArgs sa;
    for (int s = 0; s < NSEG; ++s) { sa.src[s] = d_in[kSegIn[s]]; sa.off[s] = off[s]; }
    conv_w_k<<<(WTOT + 255) / 256, 256, 0, stream>>>(sa, wf, flag);
    tr_k<128, 256><<<128, 256, 0, stream>>>(W1f, W1t);
    tr_k<256, 128><<<128, 256, 0, stream>>>(W2f, W2t);
    tr_k<128, 64><<<32, 256, 0, stream>>>(Wgf, Wgt);

    // ---- CSR build (by destination) + graph bounds ----
    hipMemsetAsync(degi, 0, NN * sizeof(int), stream);
    deg_k<<<(NE2 + 255) / 256, 256, 0, stream>>>(ei, degi);
    scan_k<<<1, 1024, 0, stream>>>(degi, row_ptr, cursor);
    scatter_k<<<(NE2 + 255) / 256, 256, 0, stream>>>(ei, cursor, csr_src);
    dis_k<<<(NN + 255) / 256, 256, 0, stream>>>(row_ptr, disb);
    bounds_k<<<1, 1024, 0, stream>>>(batch, gstart);

    // ---- GAT layer 1 ----
    mgemm_k<128, 256><<<NRT, 256, 0, stream>>>((const short*)xb, (const short*)W1t, h1);
    scores1_k<<<12500, 256, 0, stream>>>(h1, as1f, ad1f, sc_s1, sc_d1);
    agg1_k<<<12500, 256, 0, stream>>>(row_ptr, csr_src, (const float4*)h1,
                                      (const float4*)sc_s1, (const float4*)sc_d1,
                                      (const float4*)b1f, (const float4*)bn1g,
                                      (const float4*)bn1b, (ushort4*)x1b);

    // ---- GAT layer 2 ----
    mgemm_k<256, 128><<<(NRT * 2 + 3) / 4, 256, 0, stream>>>((const short*)x1b, (const short*)W2t, h2);
    scores2_k<<<12500, 256, 0, stream>>>(h2, as2f, ad2f, sc_s2, sc_d2);
    agg2_k<<<12500, 256, 0, stream>>>(row_ptr, csr_src, (const float4*)h2,
                                      sc_s2, sc_d2,
                                      (const float4*)b2f, (const float4*)bn2g,
                                      (const float4*)bn2b, (ushort4*)x2b);

    // ---- GCN + pool ----
    mgemm_k<128, 64><<<(NRT + 3) / 4, 256, 0, stream>>>((const short*)x2b, (const short*)Wgt, hg);
    gcn_k<<<12500, 256, 0, stream>>>(row_ptr, csr_src, (const float4*)hg, disb,
                                     (const float4*)bgf, (float4*)x3);
    pool_k<<<NB, 256, 0, stream>>>(x3, gstart, pooled);

    // ---- MLP head ----
    mlp_k<<<NB, 128, 0, stream>>>(pooled, l1Wf, l1bf, bn3g, bn3b, l2Wf, l2bf, d_out, flag);
}

// Round 6
// 627.173 us; speedup vs baseline: 3.1469x; 1.1096x over previous
//
#include <hip/hip_runtime.h>
#include <hip/hip_bf16.h>

// Problem constants (fixed by the harness)
#define NN  50000      // nodes
#define EE  800000     // edges before self-loops
#define NE2 850000     // edges + self-loops
#define NB  512        // graphs
#define NRT 3125       // row tiles of 16 (NN = 3125*16 exactly)
// GAT1: F=128 -> 4 heads x 64 (256). GAT2: 256 -> 1 head x 128. GCN: 128 -> 64.

#define BN_RS 0.9999950000374997f   // 1/sqrt(1+1e-5)

typedef __attribute__((ext_vector_type(8))) short short8;
typedef __attribute__((ext_vector_type(4))) float f32x4;

__device__ __forceinline__ float bf2f(__hip_bfloat16 v) { return __bfloat162float(v); }
__device__ __forceinline__ unsigned short f2b(float v) {
    __hip_bfloat16 b = __float2bfloat16(v);
    return *reinterpret_cast<unsigned short*>(&b);
}
__device__ __forceinline__ float u2f(unsigned short u) {
    union { unsigned u; float f; } c; c.u = ((unsigned)u) << 16; return c.f;
}
__device__ __forceinline__ float4 u42f4(ushort4 v) {
    float4 r; r.x = u2f(v.x); r.y = u2f(v.y); r.z = u2f(v.z); r.w = u2f(v.w); return r;
}
__device__ __forceinline__ float lrelu01(float v) { return v > 0.f ? v : 0.01f * v; }
__device__ __forceinline__ float lrelu02(float v) { return v > 0.f ? v : 0.2f * v; }

__device__ __forceinline__ void edge_sd(const int* __restrict__ ei, int e, int& s, int& d) {
    if (e < EE) { s = ei[e]; d = ei[EE + e]; }
    else        { s = e - EE; d = e - EE; }      // self-loop
}

// ---------------- dtype detector (bf16 vs fp32 inputs) ----------------
__global__ __launch_bounds__(256) void det_k(const unsigned* __restrict__ xw, int* __restrict__ flag) {
    __shared__ int cnt;
    if (threadIdx.x == 0) cnt = 0;
    __syncthreads();
    int c = 0;
#pragma unroll
    for (int k = 0; k < 4; ++k) {
        unsigned w = xw[threadIdx.x * 4 + k];
        unsigned ef = (w >> 7) & 0xFFu;
        if (ef >= 100u && ef <= 140u) c++;
    }
    atomicAdd(&cnt, c);
    __syncthreads();
    if (threadIdx.x == 0) *flag = (cnt > 512) ? 1 : 0;   // 1 = bf16 inputs
}

// canonicalize x to bf16 (straight copy if already bf16)
__global__ __launch_bounds__(256) void conv_x_k(const void* __restrict__ x,
                                                unsigned short* __restrict__ xb,
                                                const int* __restrict__ flag) {
    bool bf = (*flag != 0);
    size_t i = (size_t)blockIdx.x * 256 + threadIdx.x;
    if (i >= (size_t)NN * 128) return;
    xb[i] = bf ? ((const unsigned short*)x)[i] : f2b(((const float*)x)[i]);
}

#define NSEG 20
#define WTOT 85578
struct SegArgs { const void* src[NSEG]; int off[NSEG]; };

// grid-parallel weight conversion to canonical fp32
__global__ __launch_bounds__(256) void conv_w_k(SegArgs a, float* __restrict__ wf,
                                                const int* __restrict__ flag) {
    bool bf = (*flag != 0);
    int i = blockIdx.x * 256 + threadIdx.x;
    if (i >= WTOT) return;
    int s = 0;
#pragma unroll
    for (int k = 1; k < NSEG; ++k) if (i >= a.off[k]) s = k;
    int local = i - a.off[s];
    wf[i] = bf ? bf2f(((const __hip_bfloat16*)a.src[s])[local]) : ((const float*)a.src[s])[local];
}

// transpose W[K][N] fp32 -> Wt[N][K] bf16 (B^T layout for MFMA b-frags)
template <int K, int N>
__global__ __launch_bounds__(256) void tr_k(const float* __restrict__ W, unsigned short* __restrict__ Wt) {
    int i = blockIdx.x * 256 + threadIdx.x;
    if (i >= K * N) return;
    int k = i / N, n = i - k * N;
    Wt[n * K + k] = f2b(W[i]);
}

// ---------------- CSR build: deg -> scan -> scatter ----------------
__global__ __launch_bounds__(256) void deg_k(const int* __restrict__ ei, int* __restrict__ degi) {
    int e = blockIdx.x * 256 + threadIdx.x;
    if (e >= NE2) return;
    int s, d; edge_sd(ei, e, s, d);
    atomicAdd(&degi[d], 1);
}

__global__ __launch_bounds__(1024) void scan_k(const int* __restrict__ degi,
                                               int* __restrict__ row_ptr,
                                               int* __restrict__ cursor) {
    __shared__ int ps[1024];
    int t = threadIdx.x;
    int start = t * 49;
    int stop = start + 49 < NN ? start + 49 : NN;
    if (start > NN) start = NN;
    int s = 0;
    for (int i = start; i < stop; ++i) s += degi[i];
    ps[t] = s;
    __syncthreads();
    for (int off = 1; off < 1024; off <<= 1) {
        int v = (t >= off) ? ps[t - off] : 0;
        __syncthreads();
        ps[t] += v;
        __syncthreads();
    }
    int base = (t == 0) ? 0 : ps[t - 1];
    for (int i = start; i < stop; ++i) {
        row_ptr[i] = base; cursor[i] = base;
        base += degi[i];
    }
    if (t == 1023) row_ptr[NN] = ps[1023];
}

__global__ __launch_bounds__(256) void scatter_k(const int* __restrict__ ei,
                                                 int* __restrict__ cursor,
                                                 int* __restrict__ csr_src) {
    int e = blockIdx.x * 256 + threadIdx.x;
    if (e >= NE2) return;
    int s, d; edge_sd(ei, e, s, d);
    int pos = atomicAdd(&cursor[d], 1);
    csr_src[pos] = s;
}

__global__ __launch_bounds__(256) void dis_k(const int* __restrict__ row_ptr, float* __restrict__ dis) {
    int n = blockIdx.x * 256 + threadIdx.x;
    if (n >= NN) return;
    int dg = row_ptr[n + 1] - row_ptr[n];
    dis[n] = dg > 0 ? rsqrtf((float)dg) : 0.f;
}

// ---------------- MFMA bf16 GEMM: C[M x NCOLS] bf16 = A[M x K] bf16 @ Bt[NCOLS x K] bf16 ----
// One wave computes a 16x64 tile; fp32 accumulate, bf16 store.
// C/D: col=lane&15, row=(lane>>4)*4+reg
template <int K, int NCOLS>
__global__ __launch_bounds__(256) void mgemm_k(const short* __restrict__ A,
                                               const short* __restrict__ Bt,
                                               unsigned short* __restrict__ C) {
    constexpr int CG = NCOLS / 64;
    int wave = threadIdx.x >> 6, lane = threadIdx.x & 63;
    int gidx = blockIdx.x * 4 + wave;
    if (gidx >= NRT * CG) return;
    int rt = gidx / CG, cg = gidx - rt * CG;
    int l15 = lane & 15, quad = lane >> 4;
    const short* ap = A + (size_t)(rt * 16 + l15) * K + quad * 8;
    const short* bp = Bt + (size_t)(cg * 64 + l15) * K + quad * 8;
    f32x4 acc[4] = {};
    for (int k0 = 0; k0 < K; k0 += 32) {
        short8 a = *(const short8*)(ap + k0);
#pragma unroll
        for (int j = 0; j < 4; ++j) {
            short8 b = *(const short8*)(bp + (size_t)j * 16 * K + k0);
            acc[j] = __builtin_amdgcn_mfma_f32_16x16x32_bf16(a, b, acc[j], 0, 0, 0);
        }
    }
#pragma unroll
    for (int j = 0; j < 4; ++j) {
        int n = cg * 64 + j * 16 + l15;
#pragma unroll
        for (int r = 0; r < 4; ++r) {
            int row = rt * 16 + quad * 4 + r;
            C[(size_t)row * NCOLS + n] = f2b(acc[j][r]);
        }
    }
}

// ---------------- attention scores (bf16 h, vectorized, head-group reduce) ----------------
__global__ __launch_bounds__(256) void scores1_k(const ushort4* __restrict__ h1b, // [N*64]
                                                 const float4* __restrict__ a_s4, // [64]
                                                 const float4* __restrict__ a_d4,
                                                 float* __restrict__ sc_s, float* __restrict__ sc_d) {
    int n = (blockIdx.x * 256 + threadIdx.x) >> 6;
    int lane = threadIdx.x & 63;
    if (n >= NN) return;
    float4 hv = u42f4(h1b[(size_t)n * 64 + lane]);
    float4 as = a_s4[lane], ad = a_d4[lane];
    float ps = hv.x * as.x + hv.y * as.y + hv.z * as.z + hv.w * as.w;
    float pd = hv.x * ad.x + hv.y * ad.y + hv.z * ad.z + hv.w * ad.w;
#pragma unroll
    for (int off = 1; off < 16; off <<= 1) { ps += __shfl_xor(ps, off); pd += __shfl_xor(pd, off); }
    if ((lane & 15) == 0) {
        int h = lane >> 4;
        sc_s[n * 4 + h] = ps; sc_d[n * 4 + h] = pd;
    }
}

__global__ __launch_bounds__(256) void scores2_k(const ushort2* __restrict__ h2b, // [N*64]
                                                 const float2* __restrict__ a_s2, // [64]
                                                 const float2* __restrict__ a_d2,
                                                 float* __restrict__ sc_s, float* __restrict__ sc_d) {
    int n = (blockIdx.x * 256 + threadIdx.x) >> 6;
    int lane = threadIdx.x & 63;
    if (n >= NN) return;
    ushort2 hu = h2b[(size_t)n * 64 + lane];
    float2 as = a_s2[lane], ad = a_d2[lane];
    float h0 = u2f(hu.x), h1 = u2f(hu.y);
    float ps = h0 * as.x + h1 * as.y;
    float pd = h0 * ad.x + h1 * ad.y;
#pragma unroll
    for (int off = 32; off; off >>= 1) { ps += __shfl_down(ps, off); pd += __shfl_down(pd, off); }
    if (lane == 0) { sc_s[n] = ps; sc_d[n] = pd; }
}

__device__ __forceinline__ float sel4(float4 v, int head) {
    float ab = (head & 1) ? v.y : v.x;
    float cd = (head & 1) ? v.w : v.z;
    return (head & 2) ? cd : ab;
}

// ---------------- GAT1 aggregate: wave per dst node, bf16 gathers; writes x1 bf16 ----------
__global__ __launch_bounds__(256) void agg1_k(const int* __restrict__ row_ptr,
                                              const int* __restrict__ csr_src,
                                              const ushort4* __restrict__ h1b,  // [N*64]
                                              const float4* __restrict__ sc_s4, // [N]
                                              const float4* __restrict__ sc_d4, // [N]
                                              const float4* __restrict__ b1,    // [64]
                                              const float4* __restrict__ g1,
                                              const float4* __restrict__ bb1,
                                              ushort4* __restrict__ x1b) {
    int n = (blockIdx.x * 256 + threadIdx.x) >> 6;
    int lane = threadIdx.x & 63;
    if (n >= NN) return;
    int row = row_ptr[n], end = row_ptr[n + 1];
    int head = lane >> 4;
    float scd_h = sel4(sc_d4[n], head);
    float4 acc = {0.f, 0.f, 0.f, 0.f};
    float den = 0.f;
    int c = row;
    for (; c + 1 < end; c += 2) {
        int s0 = csr_src[c], s1 = csr_src[c + 1];
        float4 scs0 = sc_s4[s0], scs1 = sc_s4[s1];
        float4 hv0 = u42f4(h1b[(size_t)s0 * 64 + lane]);
        float4 hv1 = u42f4(h1b[(size_t)s1 * 64 + lane]);
        float e0 = __expf(lrelu02(sel4(scs0, head) + scd_h));
        float e1 = __expf(lrelu02(sel4(scs1, head) + scd_h));
        den += e0 + e1;
        acc.x = fmaf(hv0.x, e0, fmaf(hv1.x, e1, acc.x));
        acc.y = fmaf(hv0.y, e0, fmaf(hv1.y, e1, acc.y));
        acc.z = fmaf(hv0.z, e0, fmaf(hv1.z, e1, acc.z));
        acc.w = fmaf(hv0.w, e0, fmaf(hv1.w, e1, acc.w));
    }
    if (c < end) {
        int s0 = csr_src[c];
        float4 scs0 = sc_s4[s0];
        float4 hv0 = u42f4(h1b[(size_t)s0 * 64 + lane]);
        float e0 = __expf(lrelu02(sel4(scs0, head) + scd_h));
        den += e0;
        acc.x = fmaf(hv0.x, e0, acc.x);
        acc.y = fmaf(hv0.y, e0, acc.y);
        acc.z = fmaf(hv0.z, e0, acc.z);
        acc.w = fmaf(hv0.w, e0, acc.w);
    }
    float inv = 1.f / (den + 1e-16f);
    float4 bb = b1[lane], gg = g1[lane], be = bb1[lane];
    ushort4 o;
    o.x = f2b(lrelu01(acc.x * inv + bb.x) * (gg.x * BN_RS) + be.x);
    o.y = f2b(lrelu01(acc.y * inv + bb.y) * (gg.y * BN_RS) + be.y);
    o.z = f2b(lrelu01(acc.z * inv + bb.z) * (gg.z * BN_RS) + be.z);
    o.w = f2b(lrelu01(acc.w * inv + bb.w) * (gg.w * BN_RS) + be.w);
    x1b[(size_t)n * 64 + lane] = o;
}

// ---------------- GAT2 aggregate: 2 half-wave groups, bf16 gathers; writes x2 bf16 --------
__global__ __launch_bounds__(256) void agg2_k(const int* __restrict__ row_ptr,
                                              const int* __restrict__ csr_src,
                                              const ushort4* __restrict__ h2b,  // [N*32]
                                              const float* __restrict__ sc_s,   // [N]
                                              const float* __restrict__ sc_d,
                                              const float4* __restrict__ b2,    // [32]
                                              const float4* __restrict__ g2,
                                              const float4* __restrict__ bb2,
                                              ushort4* __restrict__ x2b) {
    int n = (blockIdx.x * 256 + threadIdx.x) >> 6;
    int lane = threadIdx.x & 63;
    if (n >= NN) return;
    int g = lane >> 5, sl = lane & 31;
    int row = row_ptr[n], end = row_ptr[n + 1];
    float scd = sc_d[n];
    float4 acc = {0.f, 0.f, 0.f, 0.f};
    float den = 0.f;
    for (int c = row + g; c < end; c += 2) {
        int s = csr_src[c];
        float e = __expf(lrelu02(sc_s[s] + scd));
        den += e;
        float4 hv = u42f4(h2b[(size_t)s * 32 + sl]);
        acc.x = fmaf(hv.x, e, acc.x);
        acc.y = fmaf(hv.y, e, acc.y);
        acc.z = fmaf(hv.z, e, acc.z);
        acc.w = fmaf(hv.w, e, acc.w);
    }
    den += __shfl_xor(den, 32);
    acc.x += __shfl_xor(acc.x, 32);
    acc.y += __shfl_xor(acc.y, 32);
    acc.z += __shfl_xor(acc.z, 32);
    acc.w += __shfl_xor(acc.w, 32);
    if (g == 0) {
        float inv = 1.f / (den + 1e-16f);
        float4 bb = b2[sl], gg = g2[sl], be = bb2[sl];
        ushort4 o;
        o.x = f2b(lrelu01(acc.x * inv + bb.x) * (gg.x * BN_RS) + be.x);
        o.y = f2b(lrelu01(acc.y * inv + bb.y) * (gg.y * BN_RS) + be.y);
        o.z = f2b(lrelu01(acc.z * inv + bb.z) * (gg.z * BN_RS) + be.z);
        o.w = f2b(lrelu01(acc.w * inv + bb.w) * (gg.w * BN_RS) + be.w);
        x2b[(size_t)n * 32 + sl] = o;
    }
}

// ---------------- GCN aggregate + lrelu -> x3 (bf16 gathers, coalesced f32 store) ----------
__global__ __launch_bounds__(256) void gcn_k(const int* __restrict__ row_ptr,
                                             const int* __restrict__ csr_src,
                                             const ushort4* __restrict__ hgb,  // [N*16]
                                             const float* __restrict__ dis,
                                             const float4* __restrict__ bg,    // [16]
                                             float4* __restrict__ x3) {        // [N*16]
    int n = (blockIdx.x * 256 + threadIdx.x) >> 6;
    int lane = threadIdx.x & 63;
    if (n >= NN) return;
    int g = lane >> 4, sl = lane & 15;
    int row = row_ptr[n], end = row_ptr[n + 1];
    float dn = dis[n];
    float4 acc = {0.f, 0.f, 0.f, 0.f};
    for (int c = row + g; c < end; c += 4) {
        int s = csr_src[c];
        float w = dis[s];
        float4 hv = u42f4(hgb[(size_t)s * 16 + sl]);
        acc.x = fmaf(hv.x, w, acc.x);
        acc.y = fmaf(hv.y, w, acc.y);
        acc.z = fmaf(hv.z, w, acc.z);
        acc.w = fmaf(hv.w, w, acc.w);
    }
#pragma unroll
    for (int off = 16; off <= 32; off <<= 1) {
        acc.x += __shfl_xor(acc.x, off);
        acc.y += __shfl_xor(acc.y, off);
        acc.z += __shfl_xor(acc.z, off);
        acc.w += __shfl_xor(acc.w, off);
    }
    if (g == 0) {
        float4 bb = bg[sl];
        float4 o;
        o.x = lrelu01(acc.x * dn + bb.x);
        o.y = lrelu01(acc.y * dn + bb.y);
        o.z = lrelu01(acc.z * dn + bb.z);
        o.w = lrelu01(acc.w * dn + bb.w);
        x3[(size_t)n * 16 + sl] = o;
    }
}

// ---------------- graph boundaries: batch is sorted; binary search per graph ----------------
__global__ __launch_bounds__(1024) void bounds_k(const int* __restrict__ batch, int* __restrict__ gstart) {
    int t = threadIdx.x;
    if (t > NB) return;
    int lo = 0, hi = NN;
    while (lo < hi) { int mid = (lo + hi) >> 1; if (batch[mid] < t) lo = mid + 1; else hi = mid; }
    gstart[t] = lo;
}

// ---------------- segmented mean-pool: block per graph, no atomics ----------------
__global__ __launch_bounds__(256) void pool_k(const float* __restrict__ x3,
                                              const int* __restrict__ gstart,
                                              float* __restrict__ pooled) {
    __shared__ float red[4][64];
    int g = blockIdx.x, t = threadIdx.x;
    int c = t & 63, r = t >> 6;
    int s = gstart[g], e = gstart[g + 1];
    float sum = 0.f;
    for (int n = s + r; n < e; n += 4) sum += x3[(size_t)n * 64 + c];
    red[r][c] = sum;
    __syncthreads();
    if (t < 64) {
        float v = red[0][t] + red[1][t] + red[2][t] + red[3][t];
        int cnt = e - s; if (cnt < 1) cnt = 1;
        pooled[g * 64 + t] = v / (float)cnt;
    }
}

// ---------------- per-graph MLP head; output dtype per flag ----------------
__global__ __launch_bounds__(128) void mlp_k(const float* __restrict__ pooled,
                                             const float* __restrict__ l1W,
                                             const float* __restrict__ l1b,
                                             const float* __restrict__ g3,
                                             const float* __restrict__ b3,
                                             const float* __restrict__ l2W,
                                             const float* __restrict__ l2b,
                                             void* __restrict__ outp,
                                             const int* __restrict__ flag) {
    __shared__ float pl[64];
    __shared__ float y1s[128];
    int g = blockIdx.x, t = threadIdx.x;
    if (t < 64) pl[t] = pooled[g * 64 + t];
    __syncthreads();
    float acc = l1b[t];
#pragma unroll 8
    for (int j = 0; j < 64; ++j) acc = fmaf(pl[j], l1W[j * 128 + t], acc);
    acc = acc * (g3[t] * BN_RS) + b3[t];
    y1s[t] = lrelu01(acc);
    __syncthreads();
    if (t < 10) {
        float o = l2b[t];
#pragma unroll 8
        for (int j = 0; j < 128; ++j) o = fmaf(y1s[j], l2W[j * 10 + t], o);
        if (*flag) ((__hip_bfloat16*)outp)[g * 10 + t] = __float2bfloat16(o);
        else       ((float*)outp)[g * 10 + t] = o;
    }
}

// weight segment sizes (W1,as1,ad1,b1,W2,as2,ad2,b2,Wg,bg,bn1g,bn1b,bn2g,bn2b,bn3g,bn3b,l1W,l1b,l2W,l2b)
static const int kSegN[NSEG]  = {32768, 256, 256, 256, 32768, 128, 128, 128, 8192, 64,
                                 256, 256, 128, 128, 128, 128, 8192, 128, 1280, 10};
static const int kSegIn[NSEG] = {3, 4, 5, 6, 7, 8, 9, 10, 11, 12, 13, 14, 15, 16, 17, 18, 19, 20, 21, 22};

extern "C" void kernel_launch(void* const* d_in, const int* in_sizes, int n_in,
                              void* d_out, int out_size, void* d_ws, size_t ws_size,
                              hipStream_t stream) {
    const void* x_raw = d_in[0];
    const int*  ei    = (const int*)d_in[1];
    const int*  batch = (const int*)d_in[2];

    // ---- workspace layout ----
    int*   flag = (int*)d_ws;
    float* ws   = (float*)d_ws;
    unsigned short* xb = (unsigned short*)(ws + 16);          // N*128 bf16
    float* wf   = ws + 16 + (size_t)NN * 64;                  // 85584 fp32 canonical
    unsigned short* W1t = (unsigned short*)(wf + 85584);      // 32768 bf16 [256][128]
    unsigned short* W2t = W1t + 32768;                        // 32768 bf16 [128][256]
    unsigned short* Wgt = W2t + 32768;                        // 8192  bf16 [64][128]
    unsigned short* h1b = Wgt + 8192;                         // N*256 bf16 (reused as h2b [N,128])
    unsigned short* x1b = h1b + (size_t)NN * 256;             // N*256 bf16
    unsigned short* x2b = x1b + (size_t)NN * 256;             // N*128 bf16
    unsigned short* hgb = x2b + (size_t)NN * 128;             // N*64 bf16
    float* x3   = (float*)(hgb + (size_t)NN * 64);            // N*64 fp32
    float* sc_s1 = x3 + (size_t)NN * 64;                      // N*4
    float* sc_d1 = sc_s1 + (size_t)NN * 4;                    // N*4
    float* sc_s2 = sc_d1 + (size_t)NN * 4;                    // N
    float* sc_d2 = sc_s2 + NN;                                // N
    float* disb  = sc_d2 + NN;                                // N
    float* pooled = disb + NN;                                // B*64
    int*   gstart = (int*)(pooled + NB * 64);                 // B+1
    int*   degi   = gstart + NB + 4;                          // N
    int*   row_ptr = degi + NN;                               // N+1
    int*   cursor  = row_ptr + NN + 1;                        // N
    int*   csr_src = cursor + NN;                             // NE2

    int off[NSEG]; int o = 0;
    for (int s = 0; s < NSEG; ++s) { off[s] = o; o += kSegN[s]; }
    float* W1f  = wf + off[0];  float* as1f = wf + off[1];  float* ad1f = wf + off[2];
    float* b1f  = wf + off[3];  float* W2f  = wf + off[4];  float* as2f = wf + off[5];
    float* ad2f = wf + off[6];  float* b2f  = wf + off[7];  float* Wgf  = wf + off[8];
    float* bgf  = wf + off[9];  float* bn1g = wf + off[10]; float* bn1b = wf + off[11];
    float* bn2g = wf + off[12]; float* bn2b = wf + off[13]; float* bn3g = wf + off[14];
    float* bn3b = wf + off[15]; float* l1Wf = wf + off[16]; float* l1bf = wf + off[17];
    float* l2Wf = wf + off[18]; float* l2bf = wf + off[19];

    unsigned short* h2b = h1b;   // h1b dead after agg1_k

    // ---- dtype detect + canonicalize ----
    det_k<<<1, 256, 0, stream>>>((const unsigned*)x_raw, flag);
    conv_x_k<<<(NN * 128 + 255) / 256, 256, 0, stream>>>(x_raw, xb, flag);
    SegArgs sa;
    for (int s = 0; s < NSEG; ++s) { sa.src[s] = d_in[kSegIn[s]]; sa.off[s] = off[s]; }
    conv_w_k<<<(WTOT + 255) / 256, 256, 0, stream>>>(sa, wf, flag);
    tr_k<128, 256><<<128, 256, 0, stream>>>(W1f, W1t);
    tr_k<256, 128><<<128, 256, 0, stream>>>(W2f, W2t);
    tr_k<128, 64><<<32, 256, 0, stream>>>(Wgf, Wgt);

    // ---- CSR build (by destination) + graph bounds ----
    hipMemsetAsync(degi, 0, NN * sizeof(int), stream);
    deg_k<<<(NE2 + 255) / 256, 256, 0, stream>>>(ei, degi);
    scan_k<<<1, 1024, 0, stream>>>(degi, row_ptr, cursor);
    scatter_k<<<(NE2 + 255) / 256, 256, 0, stream>>>(ei, cursor, csr_src);
    dis_k<<<(NN + 255) / 256, 256, 0, stream>>>(row_ptr, disb);
    bounds_k<<<1, 1024, 0, stream>>>(batch, gstart);

    // ---- GAT layer 1 ----
    mgemm_k<128, 256><<<NRT, 256, 0, stream>>>((const short*)xb, (const short*)W1t, h1b);
    scores1_k<<<12500, 256, 0, stream>>>((const ushort4*)h1b, (const float4*)as1f,
                                         (const float4*)ad1f, sc_s1, sc_d1);
    agg1_k<<<12500, 256, 0, stream>>>(row_ptr, csr_src, (const ushort4*)h1b,
                                      (const float4*)sc_s1, (const float4*)sc_d1,
                                      (const float4*)b1f, (const float4*)bn1g,
                                      (const float4*)bn1b, (ushort4*)x1b);

    // ---- GAT layer 2 ----
    mgemm_k<256, 128><<<(NRT * 2 + 3) / 4, 256, 0, stream>>>((const short*)x1b, (const short*)W2t, h2b);
    scores2_k<<<12500, 256, 0, stream>>>((const ushort2*)h2b, (const float2*)as2f,
                                         (const float2*)ad2f, sc_s2, sc_d2);
    agg2_k<<<12500, 256, 0, stream>>>(row_ptr, csr_src, (const ushort4*)h2b,
                                      sc_s2, sc_d2,
                                      (const float4*)b2f, (const float4*)bn2g,
                                      (const float4*)bn2b, (ushort4*)x2b);

    // ---- GCN + pool ----
    mgemm_k<128, 64><<<(NRT + 3) / 4, 256, 0, stream>>>((const short*)x2b, (const short*)Wgt, hgb);
    gcn_k<<<12500, 256, 0, stream>>>(row_ptr, csr_src, (const ushort4*)hgb, disb,
                                     (const float4*)bgf, (float4*)x3);
    pool_k<<<NB, 256, 0, stream>>>(x3, gstart, pooled);

    // ---- MLP head ----
    mlp_k<<<NB, 128, 0, stream>>>(pooled, l1Wf, l1bf, bn3g, bn3b, l2Wf, l2bf, d_out, flag);
}

// Round 7
// 523.226 us; speedup vs baseline: 3.7721x; 1.1987x over previous
//
#include <hip/hip_runtime.h>
#include <hip/hip_bf16.h>

// Problem constants (fixed by the harness)
#define NN  50000      // nodes
#define EE  800000     // edges before self-loops
#define NE2 850000     // edges + self-loops
#define NB  512        // graphs
#define NRT 3125       // row tiles of 16 (NN = 3125*16 exactly)
#define NSB 196        // scan blocks = ceil(NN/256)
// GAT1: F=128 -> 4 heads x 64 (256). GAT2: 256 -> 1 head x 128. GCN: 128 -> 64.

#define BN_RS 0.9999950000374997f   // 1/sqrt(1+1e-5)

typedef __attribute__((ext_vector_type(8))) short short8;
typedef __attribute__((ext_vector_type(4))) float f32x4;

__device__ __forceinline__ float bf2f(__hip_bfloat16 v) { return __bfloat162float(v); }
__device__ __forceinline__ unsigned short f2b(float v) {
    __hip_bfloat16 b = __float2bfloat16(v);
    return *reinterpret_cast<unsigned short*>(&b);
}
__device__ __forceinline__ float u2f(unsigned short u) {
    union { unsigned u; float f; } c; c.u = ((unsigned)u) << 16; return c.f;
}
__device__ __forceinline__ float4 u42f4(ushort4 v) {
    float4 r; r.x = u2f(v.x); r.y = u2f(v.y); r.z = u2f(v.z); r.w = u2f(v.w); return r;
}
__device__ __forceinline__ float lrelu01(float v) { return v > 0.f ? v : 0.01f * v; }
__device__ __forceinline__ float lrelu02(float v) { return v > 0.f ? v : 0.2f * v; }

__device__ __forceinline__ void edge_sd(const int* __restrict__ ei, int e, int& s, int& d) {
    if (e < EE) { s = ei[e]; d = ei[EE + e]; }
    else        { s = e - EE; d = e - EE; }      // self-loop
}

// ---------------- dtype detector (bf16 vs fp32 inputs) ----------------
__global__ __launch_bounds__(256) void det_k(const unsigned* __restrict__ xw, int* __restrict__ flag) {
    __shared__ int cnt;
    if (threadIdx.x == 0) cnt = 0;
    __syncthreads();
    int c = 0;
#pragma unroll
    for (int k = 0; k < 4; ++k) {
        unsigned w = xw[threadIdx.x * 4 + k];
        unsigned ef = (w >> 7) & 0xFFu;
        if (ef >= 100u && ef <= 140u) c++;
    }
    atomicAdd(&cnt, c);
    __syncthreads();
    if (threadIdx.x == 0) *flag = (cnt > 512) ? 1 : 0;   // 1 = bf16 inputs
}

// canonicalize x to bf16 (straight copy if already bf16)
__global__ __launch_bounds__(256) void conv_x_k(const void* __restrict__ x,
                                                unsigned short* __restrict__ xb,
                                                const int* __restrict__ flag) {
    bool bf = (*flag != 0);
    size_t i = (size_t)blockIdx.x * 256 + threadIdx.x;
    if (i >= (size_t)NN * 128) return;
    xb[i] = bf ? ((const unsigned short*)x)[i] : f2b(((const float*)x)[i]);
}

#define NSEG 20
#define WTOT 85578
struct SegArgs { const void* src[NSEG]; int off[NSEG]; };

// grid-parallel weight conversion to canonical fp32
__global__ __launch_bounds__(256) void conv_w_k(SegArgs a, float* __restrict__ wf,
                                                const int* __restrict__ flag) {
    bool bf = (*flag != 0);
    int i = blockIdx.x * 256 + threadIdx.x;
    if (i >= WTOT) return;
    int s = 0;
#pragma unroll
    for (int k = 1; k < NSEG; ++k) if (i >= a.off[k]) s = k;
    int local = i - a.off[s];
    wf[i] = bf ? bf2f(((const __hip_bfloat16*)a.src[s])[local]) : ((const float*)a.src[s])[local];
}

// transpose W[K][N] fp32 -> Wt[N][K] bf16 (B^T layout for MFMA b-frags)
template <int K, int N>
__global__ __launch_bounds__(256) void tr_k(const float* __restrict__ W, unsigned short* __restrict__ Wt) {
    int i = blockIdx.x * 256 + threadIdx.x;
    if (i >= K * N) return;
    int k = i / N, n = i - k * N;
    Wt[n * K + k] = f2b(W[i]);
}

// ---------------- CSR build: deg -> 3-phase parallel scan -> scatter ----------------
__global__ __launch_bounds__(256) void deg_k(const int* __restrict__ ei, int* __restrict__ degi) {
    int e = blockIdx.x * 256 + threadIdx.x;
    if (e >= NE2) return;
    int s, d; edge_sd(ei, e, s, d);
    atomicAdd(&degi[d], 1);
}

// phase 1: block-local inclusive scan (Hillis-Steele in LDS), emit block sums
__global__ __launch_bounds__(256) void pscan_k(const int* __restrict__ degi,
                                               int* __restrict__ incl, int* __restrict__ bsum) {
    __shared__ int tmp[256];
    int t = threadIdx.x;
    int i = blockIdx.x * 256 + t;
    int v = (i < NN) ? degi[i] : 0;
    tmp[t] = v;
    __syncthreads();
#pragma unroll
    for (int off = 1; off < 256; off <<= 1) {
        int u = (t >= off) ? tmp[t - off] : 0;
        __syncthreads();
        tmp[t] += u;
        __syncthreads();
    }
    if (i < NN) incl[i] = tmp[t];
    if (t == 255) bsum[blockIdx.x] = tmp[255];
}

// phase 2: single-block inclusive scan of the NSB block sums
__global__ __launch_bounds__(256) void bscan_k(int* __restrict__ bsum) {
    __shared__ int tmp[256];
    int t = threadIdx.x;
    tmp[t] = (t < NSB) ? bsum[t] : 0;
    __syncthreads();
#pragma unroll
    for (int off = 1; off < 256; off <<= 1) {
        int u = (t >= off) ? tmp[t - off] : 0;
        __syncthreads();
        tmp[t] += u;
        __syncthreads();
    }
    if (t < NSB) bsum[t] = tmp[t];
}

// phase 3: exclusive row_ptr + cursor
__global__ __launch_bounds__(256) void fscan_k(const int* __restrict__ degi,
                                               const int* __restrict__ incl,
                                               const int* __restrict__ bsum,
                                               int* __restrict__ row_ptr, int* __restrict__ cursor) {
    int i = blockIdx.x * 256 + threadIdx.x;
    if (i >= NN) return;
    int base = (blockIdx.x > 0) ? bsum[blockIdx.x - 1] : 0;
    int ex = base + incl[i] - degi[i];
    row_ptr[i] = ex; cursor[i] = ex;
    if (i == NN - 1) row_ptr[NN] = bsum[NSB - 1];
}

__global__ __launch_bounds__(256) void scatter_k(const int* __restrict__ ei,
                                                 int* __restrict__ cursor,
                                                 int* __restrict__ csr_src) {
    int e = blockIdx.x * 256 + threadIdx.x;
    if (e >= NE2) return;
    int s, d; edge_sd(ei, e, s, d);
    int pos = atomicAdd(&cursor[d], 1);
    csr_src[pos] = s;
}

__global__ __launch_bounds__(256) void dis_k(const int* __restrict__ row_ptr, float* __restrict__ dis) {
    int n = blockIdx.x * 256 + threadIdx.x;
    if (n >= NN) return;
    int dg = row_ptr[n + 1] - row_ptr[n];
    dis[n] = dg > 0 ? rsqrtf((float)dg) : 0.f;
}

// ---------------- MFMA bf16 GEMM: C[M x NCOLS] bf16 = A[M x K] bf16 @ Bt[NCOLS x K] bf16 ----
template <int K, int NCOLS>
__global__ __launch_bounds__(256) void mgemm_k(const short* __restrict__ A,
                                               const short* __restrict__ Bt,
                                               unsigned short* __restrict__ C) {
    constexpr int CG = NCOLS / 64;
    int wave = threadIdx.x >> 6, lane = threadIdx.x & 63;
    int gidx = blockIdx.x * 4 + wave;
    if (gidx >= NRT * CG) return;
    int rt = gidx / CG, cg = gidx - rt * CG;
    int l15 = lane & 15, quad = lane >> 4;
    const short* ap = A + (size_t)(rt * 16 + l15) * K + quad * 8;
    const short* bp = Bt + (size_t)(cg * 64 + l15) * K + quad * 8;
    f32x4 acc[4] = {};
    for (int k0 = 0; k0 < K; k0 += 32) {
        short8 a = *(const short8*)(ap + k0);
#pragma unroll
        for (int j = 0; j < 4; ++j) {
            short8 b = *(const short8*)(bp + (size_t)j * 16 * K + k0);
            acc[j] = __builtin_amdgcn_mfma_f32_16x16x32_bf16(a, b, acc[j], 0, 0, 0);
        }
    }
#pragma unroll
    for (int j = 0; j < 4; ++j) {
        int n = cg * 64 + j * 16 + l15;
#pragma unroll
        for (int r = 0; r < 4; ++r) {
            int row = rt * 16 + quad * 4 + r;
            C[(size_t)row * NCOLS + n] = f2b(acc[j][r]);
        }
    }
}

// ---------------- attention scores (bf16 h, vectorized, head-group reduce) ----------------
__global__ __launch_bounds__(256) void scores1_k(const ushort4* __restrict__ h1b, // [N*64]
                                                 const float4* __restrict__ a_s4, // [64]
                                                 const float4* __restrict__ a_d4,
                                                 float* __restrict__ sc_s, float* __restrict__ sc_d) {
    int n = (blockIdx.x * 256 + threadIdx.x) >> 6;
    int lane = threadIdx.x & 63;
    if (n >= NN) return;
    float4 hv = u42f4(h1b[(size_t)n * 64 + lane]);
    float4 as = a_s4[lane], ad = a_d4[lane];
    float ps = hv.x * as.x + hv.y * as.y + hv.z * as.z + hv.w * as.w;
    float pd = hv.x * ad.x + hv.y * ad.y + hv.z * ad.z + hv.w * ad.w;
#pragma unroll
    for (int off = 1; off < 16; off <<= 1) { ps += __shfl_xor(ps, off); pd += __shfl_xor(pd, off); }
    if ((lane & 15) == 0) {
        int h = lane >> 4;
        sc_s[n * 4 + h] = ps; sc_d[n * 4 + h] = pd;
    }
}

__global__ __launch_bounds__(256) void scores2_k(const ushort2* __restrict__ h2b, // [N*64]
                                                 const float2* __restrict__ a_s2, // [64]
                                                 const float2* __restrict__ a_d2,
                                                 float* __restrict__ sc_s, float* __restrict__ sc_d) {
    int n = (blockIdx.x * 256 + threadIdx.x) >> 6;
    int lane = threadIdx.x & 63;
    if (n >= NN) return;
    ushort2 hu = h2b[(size_t)n * 64 + lane];
    float2 as = a_s2[lane], ad = a_d2[lane];
    float h0 = u2f(hu.x), h1 = u2f(hu.y);
    float ps = h0 * as.x + h1 * as.y;
    float pd = h0 * ad.x + h1 * ad.y;
#pragma unroll
    for (int off = 32; off; off >>= 1) { ps += __shfl_down(ps, off); pd += __shfl_down(pd, off); }
    if (lane == 0) { sc_s[n] = ps; sc_d[n] = pd; }
}

__device__ __forceinline__ float sel4(float4 v, int head) {
    float ab = (head & 1) ? v.y : v.x;
    float cd = (head & 1) ? v.w : v.z;
    return (head & 2) ? cd : ab;
}

// ---------------- GAT1 aggregate: wave per dst node, bf16 gathers; writes x1 bf16 ----------
__global__ __launch_bounds__(256) void agg1_k(const int* __restrict__ row_ptr,
                                              const int* __restrict__ csr_src,
                                              const ushort4* __restrict__ h1b,  // [N*64]
                                              const float4* __restrict__ sc_s4, // [N]
                                              const float4* __restrict__ sc_d4, // [N]
                                              const float4* __restrict__ b1,    // [64]
                                              const float4* __restrict__ g1,
                                              const float4* __restrict__ bb1,
                                              ushort4* __restrict__ x1b) {
    int n = (blockIdx.x * 256 + threadIdx.x) >> 6;
    int lane = threadIdx.x & 63;
    if (n >= NN) return;
    int row = row_ptr[n], end = row_ptr[n + 1];
    int head = lane >> 4;
    float scd_h = sel4(sc_d4[n], head);
    float4 acc = {0.f, 0.f, 0.f, 0.f};
    float den = 0.f;
    int c = row;
    for (; c + 1 < end; c += 2) {
        int s0 = csr_src[c], s1 = csr_src[c + 1];
        float4 scs0 = sc_s4[s0], scs1 = sc_s4[s1];
        float4 hv0 = u42f4(h1b[(size_t)s0 * 64 + lane]);
        float4 hv1 = u42f4(h1b[(size_t)s1 * 64 + lane]);
        float e0 = __expf(lrelu02(sel4(scs0, head) + scd_h));
        float e1 = __expf(lrelu02(sel4(scs1, head) + scd_h));
        den += e0 + e1;
        acc.x = fmaf(hv0.x, e0, fmaf(hv1.x, e1, acc.x));
        acc.y = fmaf(hv0.y, e0, fmaf(hv1.y, e1, acc.y));
        acc.z = fmaf(hv0.z, e0, fmaf(hv1.z, e1, acc.z));
        acc.w = fmaf(hv0.w, e0, fmaf(hv1.w, e1, acc.w));
    }
    if (c < end) {
        int s0 = csr_src[c];
        float4 scs0 = sc_s4[s0];
        float4 hv0 = u42f4(h1b[(size_t)s0 * 64 + lane]);
        float e0 = __expf(lrelu02(sel4(scs0, head) + scd_h));
        den += e0;
        acc.x = fmaf(hv0.x, e0, acc.x);
        acc.y = fmaf(hv0.y, e0, acc.y);
        acc.z = fmaf(hv0.z, e0, acc.z);
        acc.w = fmaf(hv0.w, e0, acc.w);
    }
    float inv = 1.f / (den + 1e-16f);
    float4 bb = b1[lane], gg = g1[lane], be = bb1[lane];
    ushort4 o;
    o.x = f2b(lrelu01(acc.x * inv + bb.x) * (gg.x * BN_RS) + be.x);
    o.y = f2b(lrelu01(acc.y * inv + bb.y) * (gg.y * BN_RS) + be.y);
    o.z = f2b(lrelu01(acc.z * inv + bb.z) * (gg.z * BN_RS) + be.z);
    o.w = f2b(lrelu01(acc.w * inv + bb.w) * (gg.w * BN_RS) + be.w);
    x1b[(size_t)n * 64 + lane] = o;
}

// ---------------- GAT2 aggregate: 2 half-wave groups, bf16 gathers; writes x2 bf16 --------
__global__ __launch_bounds__(256) void agg2_k(const int* __restrict__ row_ptr,
                                              const int* __restrict__ csr_src,
                                              const ushort4* __restrict__ h2b,  // [N*32]
                                              const float* __restrict__ sc_s,   // [N]
                                              const float* __restrict__ sc_d,
                                              const float4* __restrict__ b2,    // [32]
                                              const float4* __restrict__ g2,
                                              const float4* __restrict__ bb2,
                                              ushort4* __restrict__ x2b) {
    int n = (blockIdx.x * 256 + threadIdx.x) >> 6;
    int lane = threadIdx.x & 63;
    if (n >= NN) return;
    int g = lane >> 5, sl = lane & 31;
    int row = row_ptr[n], end = row_ptr[n + 1];
    float scd = sc_d[n];
    float4 acc = {0.f, 0.f, 0.f, 0.f};
    float den = 0.f;
    for (int c = row + g; c < end; c += 2) {
        int s = csr_src[c];
        float e = __expf(lrelu02(sc_s[s] + scd));
        den += e;
        float4 hv = u42f4(h2b[(size_t)s * 32 + sl]);
        acc.x = fmaf(hv.x, e, acc.x);
        acc.y = fmaf(hv.y, e, acc.y);
        acc.z = fmaf(hv.z, e, acc.z);
        acc.w = fmaf(hv.w, e, acc.w);
    }
    den += __shfl_xor(den, 32);
    acc.x += __shfl_xor(acc.x, 32);
    acc.y += __shfl_xor(acc.y, 32);
    acc.z += __shfl_xor(acc.z, 32);
    acc.w += __shfl_xor(acc.w, 32);
    if (g == 0) {
        float inv = 1.f / (den + 1e-16f);
        float4 bb = b2[sl], gg = g2[sl], be = bb2[sl];
        ushort4 o;
        o.x = f2b(lrelu01(acc.x * inv + bb.x) * (gg.x * BN_RS) + be.x);
        o.y = f2b(lrelu01(acc.y * inv + bb.y) * (gg.y * BN_RS) + be.y);
        o.z = f2b(lrelu01(acc.z * inv + bb.z) * (gg.z * BN_RS) + be.z);
        o.w = f2b(lrelu01(acc.w * inv + bb.w) * (gg.w * BN_RS) + be.w);
        x2b[(size_t)n * 32 + sl] = o;
    }
}

// ---------------- GCN aggregate + lrelu -> x3 (bf16 gathers, coalesced f32 store) ----------
__global__ __launch_bounds__(256) void gcn_k(const int* __restrict__ row_ptr,
                                             const int* __restrict__ csr_src,
                                             const ushort4* __restrict__ hgb,  // [N*16]
                                             const float* __restrict__ dis,
                                             const float4* __restrict__ bg,    // [16]
                                             float4* __restrict__ x3) {        // [N*16]
    int n = (blockIdx.x * 256 + threadIdx.x) >> 6;
    int lane = threadIdx.x & 63;
    if (n >= NN) return;
    int g = lane >> 4, sl = lane & 15;
    int row = row_ptr[n], end = row_ptr[n + 1];
    float dn = dis[n];
    float4 acc = {0.f, 0.f, 0.f, 0.f};
    for (int c = row + g; c < end; c += 4) {
        int s = csr_src[c];
        float w = dis[s];
        float4 hv = u42f4(hgb[(size_t)s * 16 + sl]);
        acc.x = fmaf(hv.x, w, acc.x);
        acc.y = fmaf(hv.y, w, acc.y);
        acc.z = fmaf(hv.z, w, acc.z);
        acc.w = fmaf(hv.w, w, acc.w);
    }
#pragma unroll
    for (int off = 16; off <= 32; off <<= 1) {
        acc.x += __shfl_xor(acc.x, off);
        acc.y += __shfl_xor(acc.y, off);
        acc.z += __shfl_xor(acc.z, off);
        acc.w += __shfl_xor(acc.w, off);
    }
    if (g == 0) {
        float4 bb = bg[sl];
        float4 o;
        o.x = lrelu01(acc.x * dn + bb.x);
        o.y = lrelu01(acc.y * dn + bb.y);
        o.z = lrelu01(acc.z * dn + bb.z);
        o.w = lrelu01(acc.w * dn + bb.w);
        x3[(size_t)n * 16 + sl] = o;
    }
}

// ---------------- graph boundaries: batch is sorted; binary search per graph ----------------
__global__ __launch_bounds__(1024) void bounds_k(const int* __restrict__ batch, int* __restrict__ gstart) {
    int t = threadIdx.x;
    if (t > NB) return;
    int lo = 0, hi = NN;
    while (lo < hi) { int mid = (lo + hi) >> 1; if (batch[mid] < t) lo = mid + 1; else hi = mid; }
    gstart[t] = lo;
}

// ---------------- segmented mean-pool: block per graph, no atomics ----------------
__global__ __launch_bounds__(256) void pool_k(const float* __restrict__ x3,
                                              const int* __restrict__ gstart,
                                              float* __restrict__ pooled) {
    __shared__ float red[4][64];
    int g = blockIdx.x, t = threadIdx.x;
    int c = t & 63, r = t >> 6;
    int s = gstart[g], e = gstart[g + 1];
    float sum = 0.f;
    for (int n = s + r; n < e; n += 4) sum += x3[(size_t)n * 64 + c];
    red[r][c] = sum;
    __syncthreads();
    if (t < 64) {
        float v = red[0][t] + red[1][t] + red[2][t] + red[3][t];
        int cnt = e - s; if (cnt < 1) cnt = 1;
        pooled[g * 64 + t] = v / (float)cnt;
    }
}

// ---------------- per-graph MLP head; output dtype per flag ----------------
__global__ __launch_bounds__(128) void mlp_k(const float* __restrict__ pooled,
                                             const float* __restrict__ l1W,
                                             const float* __restrict__ l1b,
                                             const float* __restrict__ g3,
                                             const float* __restrict__ b3,
                                             const float* __restrict__ l2W,
                                             const float* __restrict__ l2b,
                                             void* __restrict__ outp,
                                             const int* __restrict__ flag) {
    __shared__ float pl[64];
    __shared__ float y1s[128];
    int g = blockIdx.x, t = threadIdx.x;
    if (t < 64) pl[t] = pooled[g * 64 + t];
    __syncthreads();
    float acc = l1b[t];
#pragma unroll 8
    for (int j = 0; j < 64; ++j) acc = fmaf(pl[j], l1W[j * 128 + t], acc);
    acc = acc * (g3[t] * BN_RS) + b3[t];
    y1s[t] = lrelu01(acc);
    __syncthreads();
    if (t < 10) {
        float o = l2b[t];
#pragma unroll 8
        for (int j = 0; j < 128; ++j) o = fmaf(y1s[j], l2W[j * 10 + t], o);
        if (*flag) ((__hip_bfloat16*)outp)[g * 10 + t] = __float2bfloat16(o);
        else       ((float*)outp)[g * 10 + t] = o;
    }
}

// weight segment sizes (W1,as1,ad1,b1,W2,as2,ad2,b2,Wg,bg,bn1g,bn1b,bn2g,bn2b,bn3g,bn3b,l1W,l1b,l2W,l2b)
static const int kSegN[NSEG]  = {32768, 256, 256, 256, 32768, 128, 128, 128, 8192, 64,
                                 256, 256, 128, 128, 128, 128, 8192, 128, 1280, 10};
static const int kSegIn[NSEG] = {3, 4, 5, 6, 7, 8, 9, 10, 11, 12, 13, 14, 15, 16, 17, 18, 19, 20, 21, 22};

extern "C" void kernel_launch(void* const* d_in, const int* in_sizes, int n_in,
                              void* d_out, int out_size, void* d_ws, size_t ws_size,
                              hipStream_t stream) {
    const void* x_raw = d_in[0];
    const int*  ei    = (const int*)d_in[1];
    const int*  batch = (const int*)d_in[2];

    // ---- workspace layout ----
    int*   flag = (int*)d_ws;
    float* ws   = (float*)d_ws;
    unsigned short* xb = (unsigned short*)(ws + 16);          // N*128 bf16
    float* wf   = ws + 16 + (size_t)NN * 64;                  // 85584 fp32 canonical
    unsigned short* W1t = (unsigned short*)(wf + 85584);      // 32768 bf16 [256][128]
    unsigned short* W2t = W1t + 32768;                        // 32768 bf16 [128][256]
    unsigned short* Wgt = W2t + 32768;                        // 8192  bf16 [64][128]
    unsigned short* h1b = Wgt + 8192;                         // N*256 bf16 (reused as h2b [N,128])
    unsigned short* x1b = h1b + (size_t)NN * 256;             // N*256 bf16
    unsigned short* x2b = x1b + (size_t)NN * 256;             // N*128 bf16
    unsigned short* hgb = x2b + (size_t)NN * 128;             // N*64 bf16
    float* x3   = (float*)(hgb + (size_t)NN * 64);            // N*64 fp32
    float* sc_s1 = x3 + (size_t)NN * 64;                      // N*4
    float* sc_d1 = sc_s1 + (size_t)NN * 4;                    // N*4
    float* sc_s2 = sc_d1 + (size_t)NN * 4;                    // N
    float* sc_d2 = sc_s2 + NN;                                // N
    float* disb  = sc_d2 + NN;                                // N
    float* pooled = disb + NN;                                // B*64
    int*   gstart = (int*)(pooled + NB * 64);                 // B+1
    int*   degi   = gstart + NB + 4;                          // N
    int*   incl   = degi + NN;                                // N
    int*   bsum   = incl + NN;                                // 256
    int*   row_ptr = bsum + 256;                              // N+1
    int*   cursor  = row_ptr + NN + 1;                        // N
    int*   csr_src = cursor + NN;                             // NE2

    int off[NSEG]; int o = 0;
    for (int s = 0; s < NSEG; ++s) { off[s] = o; o += kSegN[s]; }
    float* W1f  = wf + off[0];  float* as1f = wf + off[1];  float* ad1f = wf + off[2];
    float* b1f  = wf + off[3];  float* W2f  = wf + off[4];  float* as2f = wf + off[5];
    float* ad2f = wf + off[6];  float* b2f  = wf + off[7];  float* Wgf  = wf + off[8];
    float* bgf  = wf + off[9];  float* bn1g = wf + off[10]; float* bn1b = wf + off[11];
    float* bn2g = wf + off[12]; float* bn2b = wf + off[13]; float* bn3g = wf + off[14];
    float* bn3b = wf + off[15]; float* l1Wf = wf + off[16]; float* l1bf = wf + off[17];
    float* l2Wf = wf + off[18]; float* l2bf = wf + off[19];

    unsigned short* h2b = h1b;   // h1b dead after agg1_k

    // ---- dtype detect + canonicalize ----
    det_k<<<1, 256, 0, stream>>>((const unsigned*)x_raw, flag);
    conv_x_k<<<(NN * 128 + 255) / 256, 256, 0, stream>>>(x_raw, xb, flag);
    SegArgs sa;
    for (int s = 0; s < NSEG; ++s) { sa.src[s] = d_in[kSegIn[s]]; sa.off[s] = off[s]; }
    conv_w_k<<<(WTOT + 255) / 256, 256, 0, stream>>>(sa, wf, flag);
    tr_k<128, 256><<<128, 256, 0, stream>>>(W1f, W1t);
    tr_k<256, 128><<<128, 256, 0, stream>>>(W2f, W2t);
    tr_k<128, 64><<<32, 256, 0, stream>>>(Wgf, Wgt);

    // ---- CSR build (by destination) + graph bounds ----
    hipMemsetAsync(degi, 0, NN * sizeof(int), stream);
    deg_k<<<(NE2 + 255) / 256, 256, 0, stream>>>(ei, degi);
    pscan_k<<<NSB, 256, 0, stream>>>(degi, incl, bsum);
    bscan_k<<<1, 256, 0, stream>>>(bsum);
    fscan_k<<<NSB, 256, 0, stream>>>(degi, incl, bsum, row_ptr, cursor);
    scatter_k<<<(NE2 + 255) / 256, 256, 0, stream>>>(ei, cursor, csr_src);
    dis_k<<<(NN + 255) / 256, 256, 0, stream>>>(row_ptr, disb);
    bounds_k<<<1, 1024, 0, stream>>>(batch, gstart);

    // ---- GAT layer 1 ----
    mgemm_k<128, 256><<<NRT, 256, 0, stream>>>((const short*)xb, (const short*)W1t, h1b);
    scores1_k<<<12500, 256, 0, stream>>>((const ushort4*)h1b, (const float4*)as1f,
                                         (const float4*)ad1f, sc_s1, sc_d1);
    agg1_k<<<12500, 256, 0, stream>>>(row_ptr, csr_src, (const ushort4*)h1b,
                                      (const float4*)sc_s1, (const float4*)sc_d1,
                                      (const float4*)b1f, (const float4*)bn1g,
                                      (const float4*)bn1b, (ushort4*)x1b);

    // ---- GAT layer 2 ----
    mgemm_k<256, 128><<<(NRT * 2 + 3) / 4, 256, 0, stream>>>((const short*)x1b, (const short*)W2t, h2b);
    scores2_k<<<12500, 256, 0, stream>>>((const ushort2*)h2b, (const float2*)as2f,
                                         (const float2*)ad2f, sc_s2, sc_d2);
    agg2_k<<<12500, 256, 0, stream>>>(row_ptr, csr_src, (const ushort4*)h2b,
                                      sc_s2, sc_d2,
                                      (const float4*)b2f, (const float4*)bn2g,
                                      (const float4*)bn2b, (ushort4*)x2b);

    // ---- GCN + pool ----
    mgemm_k<128, 64><<<(NRT + 3) / 4, 256, 0, stream>>>((const short*)x2b, (const short*)Wgt, hgb);
    gcn_k<<<12500, 256, 0, stream>>>(row_ptr, csr_src, (const ushort4*)hgb, disb,
                                     (const float4*)bgf, (float4*)x3);
    pool_k<<<NB, 256, 0, stream>>>(x3, gstart, pooled);

    // ---- MLP head ----
    mlp_k<<<NB, 128, 0, stream>>>(pooled, l1Wf, l1bf, bn3g, bn3b, l2Wf, l2bf, d_out, flag);
}

// Round 8
// 476.296 us; speedup vs baseline: 4.1438x; 1.0985x over previous
//
#include <hip/hip_runtime.h>
#include <hip/hip_bf16.h>

// Problem constants (fixed by the harness)
#define NN  50000      // nodes
#define EE  800000     // edges before self-loops
#define NE2 850000     // edges + self-loops
#define NB  512        // graphs
#define NRT 3125       // row tiles of 16 (NN = 3125*16 exactly)
#define NSB 196        // scan blocks = ceil(NN/256)
// GAT1: F=128 -> 4 heads x 64 (256). GAT2: 256 -> 1 head x 128. GCN: 128 -> 64.

#define BN_RS 0.9999950000374997f   // 1/sqrt(1+1e-5)

typedef __attribute__((ext_vector_type(8))) short short8;
typedef __attribute__((ext_vector_type(4))) float f32x4;

__device__ __forceinline__ float bf2f(__hip_bfloat16 v) { return __bfloat162float(v); }
__device__ __forceinline__ unsigned short f2b(float v) {
    __hip_bfloat16 b = __float2bfloat16(v);
    return *reinterpret_cast<unsigned short*>(&b);
}
__device__ __forceinline__ float u2f(unsigned short u) {
    union { unsigned u; float f; } c; c.u = ((unsigned)u) << 16; return c.f;
}
__device__ __forceinline__ float4 u42f4(ushort4 v) {
    float4 r; r.x = u2f(v.x); r.y = u2f(v.y); r.z = u2f(v.z); r.w = u2f(v.w); return r;
}
__device__ __forceinline__ float lrelu01(float v) { return v > 0.f ? v : 0.01f * v; }
__device__ __forceinline__ float lrelu02(float v) { return v > 0.f ? v : 0.2f * v; }

__device__ __forceinline__ void edge_sd(const int* __restrict__ ei, int e, int& s, int& d) {
    if (e < EE) { s = ei[e]; d = ei[EE + e]; }
    else        { s = e - EE; d = e - EE; }      // self-loop
}

// load fp32 value from raw input that is either bf16 or fp32
__device__ __forceinline__ float ldf(const void* p, int i, bool bf) {
    return bf ? bf2f(((const __hip_bfloat16*)p)[i]) : ((const float*)p)[i];
}

// ---------------- dtype detector (bf16 vs fp32 inputs) ----------------
__global__ __launch_bounds__(256) void det_k(const unsigned* __restrict__ xw, int* __restrict__ flag) {
    __shared__ int cnt;
    if (threadIdx.x == 0) cnt = 0;
    __syncthreads();
    int c = 0;
#pragma unroll
    for (int k = 0; k < 4; ++k) {
        unsigned w = xw[threadIdx.x * 4 + k];
        unsigned ef = (w >> 7) & 0xFFu;
        if (ef >= 100u && ef <= 140u) c++;
    }
    atomicAdd(&cnt, c);
    __syncthreads();
    if (threadIdx.x == 0) *flag = (cnt > 512) ? 1 : 0;   // 1 = bf16 inputs
}

// canonicalize x to bf16, 4 elements/thread
__global__ __launch_bounds__(256) void conv_x_k(const void* __restrict__ x,
                                                ushort4* __restrict__ xb4,
                                                const int* __restrict__ flag) {
    bool bf = (*flag != 0);
    size_t i = (size_t)blockIdx.x * 256 + threadIdx.x;     // quad index
    if (i >= (size_t)NN * 32) return;
    ushort4 o;
    if (bf) {
        o = ((const ushort4*)x)[i];
    } else {
        float4 v = ((const float4*)x)[i];
        o.x = f2b(v.x); o.y = f2b(v.y); o.z = f2b(v.z); o.w = f2b(v.w);
    }
    xb4[i] = o;
}

#define NSEG 20
#define WTOT 85578
#define PREP_TOT (WTOT + 32768 + 32768 + 8192)
struct SegArgs { const void* src[NSEG]; int off[NSEG]; };

// fused: canonical fp32 weights + three bf16 B^T transposes (read raw inputs)
__global__ __launch_bounds__(256) void prep_w_k(SegArgs a,
                                                const void* __restrict__ W1r,
                                                const void* __restrict__ W2r,
                                                const void* __restrict__ Wgr,
                                                float* __restrict__ wf,
                                                unsigned short* __restrict__ W1t,
                                                unsigned short* __restrict__ W2t,
                                                unsigned short* __restrict__ Wgt,
                                                const int* __restrict__ flag) {
    bool bf = (*flag != 0);
    int i = blockIdx.x * 256 + threadIdx.x;
    if (i >= PREP_TOT) return;
    if (i < WTOT) {
        int s = 0;
#pragma unroll
        for (int k = 1; k < NSEG; ++k) if (i >= a.off[k]) s = k;
        wf[i] = ldf(a.src[s], i - a.off[s], bf);
        return;
    }
    i -= WTOT;
    if (i < 32768) {           // W1 [128][256] -> W1t[n*128+k]
        int n = i >> 7, k = i & 127;
        W1t[i] = f2b(ldf(W1r, k * 256 + n, bf));
        return;
    }
    i -= 32768;
    if (i < 32768) {           // W2 [256][128] -> W2t[n*256+k]
        int n = i >> 8, k = i & 255;
        W2t[i] = f2b(ldf(W2r, k * 128 + n, bf));
        return;
    }
    i -= 32768;
    {                          // Wg [128][64] -> Wgt[n*128+k]
        int n = i >> 7, k = i & 127;
        Wgt[i] = f2b(ldf(Wgr, k * 64 + n, bf));
    }
}

// ---------------- CSR build: deg -> 3-phase parallel scan -> scatter ----------------
__global__ __launch_bounds__(256) void deg_k(const int* __restrict__ ei, int* __restrict__ degi) {
    int e = blockIdx.x * 256 + threadIdx.x;
    if (e >= NE2) return;
    int s, d; edge_sd(ei, e, s, d);
    atomicAdd(&degi[d], 1);
}

__global__ __launch_bounds__(256) void pscan_k(const int* __restrict__ degi,
                                               int* __restrict__ incl, int* __restrict__ bsum) {
    __shared__ int tmp[256];
    int t = threadIdx.x;
    int i = blockIdx.x * 256 + t;
    int v = (i < NN) ? degi[i] : 0;
    tmp[t] = v;
    __syncthreads();
#pragma unroll
    for (int off = 1; off < 256; off <<= 1) {
        int u = (t >= off) ? tmp[t - off] : 0;
        __syncthreads();
        tmp[t] += u;
        __syncthreads();
    }
    if (i < NN) incl[i] = tmp[t];
    if (t == 255) bsum[blockIdx.x] = tmp[255];
}

__global__ __launch_bounds__(256) void bscan_k(int* __restrict__ bsum) {
    __shared__ int tmp[256];
    int t = threadIdx.x;
    tmp[t] = (t < NSB) ? bsum[t] : 0;
    __syncthreads();
#pragma unroll
    for (int off = 1; off < 256; off <<= 1) {
        int u = (t >= off) ? tmp[t - off] : 0;
        __syncthreads();
        tmp[t] += u;
        __syncthreads();
    }
    if (t < NSB) bsum[t] = tmp[t];
}

// phase 3: exclusive row_ptr + cursor + dis (fused)
__global__ __launch_bounds__(256) void fscan_k(const int* __restrict__ degi,
                                               const int* __restrict__ incl,
                                               const int* __restrict__ bsum,
                                               int* __restrict__ row_ptr, int* __restrict__ cursor,
                                               float* __restrict__ dis) {
    int i = blockIdx.x * 256 + threadIdx.x;
    if (i >= NN) return;
    int dg = degi[i];
    int base = (blockIdx.x > 0) ? bsum[blockIdx.x - 1] : 0;
    int ex = base + incl[i] - dg;
    row_ptr[i] = ex; cursor[i] = ex;
    dis[i] = dg > 0 ? rsqrtf((float)dg) : 0.f;
    if (i == NN - 1) row_ptr[NN] = bsum[NSB - 1];
}

__global__ __launch_bounds__(256) void scatter_k(const int* __restrict__ ei,
                                                 int* __restrict__ cursor,
                                                 int* __restrict__ csr_src) {
    int e = blockIdx.x * 256 + threadIdx.x;
    if (e >= NE2) return;
    int s, d; edge_sd(ei, e, s, d);
    int pos = atomicAdd(&cursor[d], 1);
    csr_src[pos] = s;
}

// ---------------- MFMA bf16 GEMM: C[M x NCOLS] bf16 = A[M x K] bf16 @ Bt[NCOLS x K] bf16 ----
template <int K, int NCOLS>
__global__ __launch_bounds__(256) void mgemm_k(const short* __restrict__ A,
                                               const short* __restrict__ Bt,
                                               unsigned short* __restrict__ C) {
    constexpr int CG = NCOLS / 64;
    int wave = threadIdx.x >> 6, lane = threadIdx.x & 63;
    int gidx = blockIdx.x * 4 + wave;
    if (gidx >= NRT * CG) return;
    int rt = gidx / CG, cg = gidx - rt * CG;
    int l15 = lane & 15, quad = lane >> 4;
    const short* ap = A + (size_t)(rt * 16 + l15) * K + quad * 8;
    const short* bp = Bt + (size_t)(cg * 64 + l15) * K + quad * 8;
    f32x4 acc[4] = {};
    for (int k0 = 0; k0 < K; k0 += 32) {
        short8 a = *(const short8*)(ap + k0);
#pragma unroll
        for (int j = 0; j < 4; ++j) {
            short8 b = *(const short8*)(bp + (size_t)j * 16 * K + k0);
            acc[j] = __builtin_amdgcn_mfma_f32_16x16x32_bf16(a, b, acc[j], 0, 0, 0);
        }
    }
#pragma unroll
    for (int j = 0; j < 4; ++j) {
        int n = cg * 64 + j * 16 + l15;
#pragma unroll
        for (int r = 0; r < 4; ++r) {
            int row = rt * 16 + quad * 4 + r;
            C[(size_t)row * NCOLS + n] = f2b(acc[j][r]);
        }
    }
}

// ---------------- attention scores (bf16 h, vectorized, head-group reduce) ----------------
__global__ __launch_bounds__(256) void scores1_k(const ushort4* __restrict__ h1b, // [N*64]
                                                 const float4* __restrict__ a_s4, // [64]
                                                 const float4* __restrict__ a_d4,
                                                 float* __restrict__ sc_s, float* __restrict__ sc_d) {
    int n = (blockIdx.x * 256 + threadIdx.x) >> 6;
    int lane = threadIdx.x & 63;
    if (n >= NN) return;
    float4 hv = u42f4(h1b[(size_t)n * 64 + lane]);
    float4 as = a_s4[lane], ad = a_d4[lane];
    float ps = hv.x * as.x + hv.y * as.y + hv.z * as.z + hv.w * as.w;
    float pd = hv.x * ad.x + hv.y * ad.y + hv.z * ad.z + hv.w * ad.w;
#pragma unroll
    for (int off = 1; off < 16; off <<= 1) { ps += __shfl_xor(ps, off); pd += __shfl_xor(pd, off); }
    if ((lane & 15) == 0) {
        int h = lane >> 4;
        sc_s[n * 4 + h] = ps; sc_d[n * 4 + h] = pd;
    }
}

__global__ __launch_bounds__(256) void scores2_k(const ushort2* __restrict__ h2b, // [N*64]
                                                 const float2* __restrict__ a_s2, // [64]
                                                 const float2* __restrict__ a_d2,
                                                 float* __restrict__ sc_s, float* __restrict__ sc_d) {
    int n = (blockIdx.x * 256 + threadIdx.x) >> 6;
    int lane = threadIdx.x & 63;
    if (n >= NN) return;
    ushort2 hu = h2b[(size_t)n * 64 + lane];
    float2 as = a_s2[lane], ad = a_d2[lane];
    float h0 = u2f(hu.x), h1 = u2f(hu.y);
    float ps = h0 * as.x + h1 * as.y;
    float pd = h0 * ad.x + h1 * ad.y;
#pragma unroll
    for (int off = 32; off; off >>= 1) { ps += __shfl_down(ps, off); pd += __shfl_down(pd, off); }
    if (lane == 0) { sc_s[n] = ps; sc_d[n] = pd; }
}

__device__ __forceinline__ float sel4(float4 v, int head) {
    float ab = (head & 1) ? v.y : v.x;
    float cd = (head & 1) ? v.w : v.z;
    return (head & 2) ? cd : ab;
}

// ---------------- GAT1 aggregate: wave per dst node, 4 edges in flight ----------------
__global__ __launch_bounds__(256) void agg1_k(const int* __restrict__ row_ptr,
                                              const int* __restrict__ csr_src,
                                              const ushort4* __restrict__ h1b,  // [N*64]
                                              const float4* __restrict__ sc_s4, // [N]
                                              const float4* __restrict__ sc_d4, // [N]
                                              const float4* __restrict__ b1,    // [64]
                                              const float4* __restrict__ g1,
                                              const float4* __restrict__ bb1,
                                              ushort4* __restrict__ x1b) {
    int n = (blockIdx.x * 256 + threadIdx.x) >> 6;
    int lane = threadIdx.x & 63;
    if (n >= NN) return;
    int row = row_ptr[n], end = row_ptr[n + 1];
    int head = lane >> 4;
    float scd_h = sel4(sc_d4[n], head);
    float4 acc = {0.f, 0.f, 0.f, 0.f};
    float den = 0.f;
    int c = row;
    for (; c + 3 < end; c += 4) {
        int s0 = csr_src[c], s1 = csr_src[c + 1], s2 = csr_src[c + 2], s3 = csr_src[c + 3];
        float4 scs0 = sc_s4[s0], scs1 = sc_s4[s1], scs2 = sc_s4[s2], scs3 = sc_s4[s3];
        float4 hv0 = u42f4(h1b[(size_t)s0 * 64 + lane]);
        float4 hv1 = u42f4(h1b[(size_t)s1 * 64 + lane]);
        float4 hv2 = u42f4(h1b[(size_t)s2 * 64 + lane]);
        float4 hv3 = u42f4(h1b[(size_t)s3 * 64 + lane]);
        float e0 = __expf(lrelu02(sel4(scs0, head) + scd_h));
        float e1 = __expf(lrelu02(sel4(scs1, head) + scd_h));
        float e2 = __expf(lrelu02(sel4(scs2, head) + scd_h));
        float e3 = __expf(lrelu02(sel4(scs3, head) + scd_h));
        den += (e0 + e1) + (e2 + e3);
        acc.x = fmaf(hv0.x, e0, fmaf(hv1.x, e1, fmaf(hv2.x, e2, fmaf(hv3.x, e3, acc.x))));
        acc.y = fmaf(hv0.y, e0, fmaf(hv1.y, e1, fmaf(hv2.y, e2, fmaf(hv3.y, e3, acc.y))));
        acc.z = fmaf(hv0.z, e0, fmaf(hv1.z, e1, fmaf(hv2.z, e2, fmaf(hv3.z, e3, acc.z))));
        acc.w = fmaf(hv0.w, e0, fmaf(hv1.w, e1, fmaf(hv2.w, e2, fmaf(hv3.w, e3, acc.w))));
    }
    for (; c < end; ++c) {
        int s0 = csr_src[c];
        float4 scs0 = sc_s4[s0];
        float4 hv0 = u42f4(h1b[(size_t)s0 * 64 + lane]);
        float e0 = __expf(lrelu02(sel4(scs0, head) + scd_h));
        den += e0;
        acc.x = fmaf(hv0.x, e0, acc.x);
        acc.y = fmaf(hv0.y, e0, acc.y);
        acc.z = fmaf(hv0.z, e0, acc.z);
        acc.w = fmaf(hv0.w, e0, acc.w);
    }
    float inv = 1.f / (den + 1e-16f);
    float4 bb = b1[lane], gg = g1[lane], be = bb1[lane];
    ushort4 o;
    o.x = f2b(lrelu01(acc.x * inv + bb.x) * (gg.x * BN_RS) + be.x);
    o.y = f2b(lrelu01(acc.y * inv + bb.y) * (gg.y * BN_RS) + be.y);
    o.z = f2b(lrelu01(acc.z * inv + bb.z) * (gg.z * BN_RS) + be.z);
    o.w = f2b(lrelu01(acc.w * inv + bb.w) * (gg.w * BN_RS) + be.w);
    x1b[(size_t)n * 64 + lane] = o;
}

// ---------------- GAT2 aggregate: 2 half-wave groups x 2-unroll (4 edges in flight) -------
__global__ __launch_bounds__(256) void agg2_k(const int* __restrict__ row_ptr,
                                              const int* __restrict__ csr_src,
                                              const ushort4* __restrict__ h2b,  // [N*32]
                                              const float* __restrict__ sc_s,   // [N]
                                              const float* __restrict__ sc_d,
                                              const float4* __restrict__ b2,    // [32]
                                              const float4* __restrict__ g2,
                                              const float4* __restrict__ bb2,
                                              ushort4* __restrict__ x2b) {
    int n = (blockIdx.x * 256 + threadIdx.x) >> 6;
    int lane = threadIdx.x & 63;
    if (n >= NN) return;
    int g = lane >> 5, sl = lane & 31;
    int row = row_ptr[n], end = row_ptr[n + 1];
    float scd = sc_d[n];
    float4 acc = {0.f, 0.f, 0.f, 0.f};
    float den = 0.f;
    int c = row + g;
    for (; c + 2 < end; c += 4) {
        int s0 = csr_src[c], s1 = csr_src[c + 2];
        float sc0 = sc_s[s0], sc1 = sc_s[s1];
        float4 hv0 = u42f4(h2b[(size_t)s0 * 32 + sl]);
        float4 hv1 = u42f4(h2b[(size_t)s1 * 32 + sl]);
        float e0 = __expf(lrelu02(sc0 + scd));
        float e1 = __expf(lrelu02(sc1 + scd));
        den += e0 + e1;
        acc.x = fmaf(hv0.x, e0, fmaf(hv1.x, e1, acc.x));
        acc.y = fmaf(hv0.y, e0, fmaf(hv1.y, e1, acc.y));
        acc.z = fmaf(hv0.z, e0, fmaf(hv1.z, e1, acc.z));
        acc.w = fmaf(hv0.w, e0, fmaf(hv1.w, e1, acc.w));
    }
    if (c < end) {
        int s0 = csr_src[c];
        float e0 = __expf(lrelu02(sc_s[s0] + scd));
        float4 hv0 = u42f4(h2b[(size_t)s0 * 32 + sl]);
        den += e0;
        acc.x = fmaf(hv0.x, e0, acc.x);
        acc.y = fmaf(hv0.y, e0, acc.y);
        acc.z = fmaf(hv0.z, e0, acc.z);
        acc.w = fmaf(hv0.w, e0, acc.w);
    }
    den += __shfl_xor(den, 32);
    acc.x += __shfl_xor(acc.x, 32);
    acc.y += __shfl_xor(acc.y, 32);
    acc.z += __shfl_xor(acc.z, 32);
    acc.w += __shfl_xor(acc.w, 32);
    if (g == 0) {
        float inv = 1.f / (den + 1e-16f);
        float4 bb = b2[sl], gg = g2[sl], be = bb2[sl];
        ushort4 o;
        o.x = f2b(lrelu01(acc.x * inv + bb.x) * (gg.x * BN_RS) + be.x);
        o.y = f2b(lrelu01(acc.y * inv + bb.y) * (gg.y * BN_RS) + be.y);
        o.z = f2b(lrelu01(acc.z * inv + bb.z) * (gg.z * BN_RS) + be.z);
        o.w = f2b(lrelu01(acc.w * inv + bb.w) * (gg.w * BN_RS) + be.w);
        x2b[(size_t)n * 32 + sl] = o;
    }
}

// ---------------- GCN aggregate: 4 groups x 16 lanes x 2-unroll (8 edges in flight) -------
__global__ __launch_bounds__(256) void gcn_k(const int* __restrict__ row_ptr,
                                             const int* __restrict__ csr_src,
                                             const ushort4* __restrict__ hgb,  // [N*16]
                                             const float* __restrict__ dis,
                                             const float4* __restrict__ bg,    // [16]
                                             float4* __restrict__ x3) {        // [N*16]
    int n = (blockIdx.x * 256 + threadIdx.x) >> 6;
    int lane = threadIdx.x & 63;
    if (n >= NN) return;
    int g = lane >> 4, sl = lane & 15;
    int row = row_ptr[n], end = row_ptr[n + 1];
    float dn = dis[n];
    float4 acc = {0.f, 0.f, 0.f, 0.f};
    int c = row + g;
    for (; c + 4 < end; c += 8) {
        int s0 = csr_src[c], s1 = csr_src[c + 4];
        float w0 = dis[s0], w1 = dis[s1];
        float4 hv0 = u42f4(hgb[(size_t)s0 * 16 + sl]);
        float4 hv1 = u42f4(hgb[(size_t)s1 * 16 + sl]);
        acc.x = fmaf(hv0.x, w0, fmaf(hv1.x, w1, acc.x));
        acc.y = fmaf(hv0.y, w0, fmaf(hv1.y, w1, acc.y));
        acc.z = fmaf(hv0.z, w0, fmaf(hv1.z, w1, acc.z));
        acc.w = fmaf(hv0.w, w0, fmaf(hv1.w, w1, acc.w));
    }
    if (c < end) {
        int s0 = csr_src[c];
        float w0 = dis[s0];
        float4 hv0 = u42f4(hgb[(size_t)s0 * 16 + sl]);
        acc.x = fmaf(hv0.x, w0, acc.x);
        acc.y = fmaf(hv0.y, w0, acc.y);
        acc.z = fmaf(hv0.z, w0, acc.z);
        acc.w = fmaf(hv0.w, w0, acc.w);
    }
#pragma unroll
    for (int off = 16; off <= 32; off <<= 1) {
        acc.x += __shfl_xor(acc.x, off);
        acc.y += __shfl_xor(acc.y, off);
        acc.z += __shfl_xor(acc.z, off);
        acc.w += __shfl_xor(acc.w, off);
    }
    if (g == 0) {
        float4 bb = bg[sl];
        float4 o;
        o.x = lrelu01(acc.x * dn + bb.x);
        o.y = lrelu01(acc.y * dn + bb.y);
        o.z = lrelu01(acc.z * dn + bb.z);
        o.w = lrelu01(acc.w * dn + bb.w);
        x3[(size_t)n * 16 + sl] = o;
    }
}

// ---------------- graph boundaries: batch is sorted; binary search per graph ----------------
__global__ __launch_bounds__(1024) void bounds_k(const int* __restrict__ batch, int* __restrict__ gstart) {
    int t = threadIdx.x;
    if (t > NB) return;
    int lo = 0, hi = NN;
    while (lo < hi) { int mid = (lo + hi) >> 1; if (batch[mid] < t) lo = mid + 1; else hi = mid; }
    gstart[t] = lo;
}

// ---------------- segmented mean-pool: block per graph, no atomics ----------------
__global__ __launch_bounds__(256) void pool_k(const float* __restrict__ x3,
                                              const int* __restrict__ gstart,
                                              float* __restrict__ pooled) {
    __shared__ float red[4][64];
    int g = blockIdx.x, t = threadIdx.x;
    int c = t & 63, r = t >> 6;
    int s = gstart[g], e = gstart[g + 1];
    float sum = 0.f;
    for (int n = s + r; n < e; n += 4) sum += x3[(size_t)n * 64 + c];
    red[r][c] = sum;
    __syncthreads();
    if (t < 64) {
        float v = red[0][t] + red[1][t] + red[2][t] + red[3][t];
        int cnt = e - s; if (cnt < 1) cnt = 1;
        pooled[g * 64 + t] = v / (float)cnt;
    }
}

// ---------------- per-graph MLP head; output dtype per flag ----------------
__global__ __launch_bounds__(128) void mlp_k(const float* __restrict__ pooled,
                                             const float* __restrict__ l1W,
                                             const float* __restrict__ l1b,
                                             const float* __restrict__ g3,
                                             const float* __restrict__ b3,
                                             const float* __restrict__ l2W,
                                             const float* __restrict__ l2b,
                                             void* __restrict__ outp,
                                             const int* __restrict__ flag) {
    __shared__ float pl[64];
    __shared__ float y1s[128];
    int g = blockIdx.x, t = threadIdx.x;
    if (t < 64) pl[t] = pooled[g * 64 + t];
    __syncthreads();
    float acc = l1b[t];
#pragma unroll 8
    for (int j = 0; j < 64; ++j) acc = fmaf(pl[j], l1W[j * 128 + t], acc);
    acc = acc * (g3[t] * BN_RS) + b3[t];
    y1s[t] = lrelu01(acc);
    __syncthreads();
    if (t < 10) {
        float o = l2b[t];
#pragma unroll 8
        for (int j = 0; j < 128; ++j) o = fmaf(y1s[j], l2W[j * 10 + t], o);
        if (*flag) ((__hip_bfloat16*)outp)[g * 10 + t] = __float2bfloat16(o);
        else       ((float*)outp)[g * 10 + t] = o;
    }
}

// weight segment sizes (W1,as1,ad1,b1,W2,as2,ad2,b2,Wg,bg,bn1g,bn1b,bn2g,bn2b,bn3g,bn3b,l1W,l1b,l2W,l2b)
static const int kSegN[NSEG]  = {32768, 256, 256, 256, 32768, 128, 128, 128, 8192, 64,
                                 256, 256, 128, 128, 128, 128, 8192, 128, 1280, 10};
static const int kSegIn[NSEG] = {3, 4, 5, 6, 7, 8, 9, 10, 11, 12, 13, 14, 15, 16, 17, 18, 19, 20, 21, 22};

extern "C" void kernel_launch(void* const* d_in, const int* in_sizes, int n_in,
                              void* d_out, int out_size, void* d_ws, size_t ws_size,
                              hipStream_t stream) {
    const void* x_raw = d_in[0];
    const int*  ei    = (const int*)d_in[1];
    const int*  batch = (const int*)d_in[2];

    // ---- workspace layout ----
    int*   flag = (int*)d_ws;
    float* ws   = (float*)d_ws;
    unsigned short* xb = (unsigned short*)(ws + 16);          // N*128 bf16
    float* wf   = ws + 16 + (size_t)NN * 64;                  // 85584 fp32 canonical
    unsigned short* W1t = (unsigned short*)(wf + 85584);      // 32768 bf16 [256][128]
    unsigned short* W2t = W1t + 32768;                        // 32768 bf16 [128][256]
    unsigned short* Wgt = W2t + 32768;                        // 8192  bf16 [64][128]
    unsigned short* h1b = Wgt + 8192;                         // N*256 bf16 (reused as h2b [N,128])
    unsigned short* x1b = h1b + (size_t)NN * 256;             // N*256 bf16
    unsigned short* x2b = x1b + (size_t)NN * 256;             // N*128 bf16
    unsigned short* hgb = x2b + (size_t)NN * 128;             // N*64 bf16
    float* x3   = (float*)(hgb + (size_t)NN * 64);            // N*64 fp32
    float* sc_s1 = x3 + (size_t)NN * 64;                      // N*4
    float* sc_d1 = sc_s1 + (size_t)NN * 4;                    // N*4
    float* sc_s2 = sc_d1 + (size_t)NN * 4;                    // N
    float* sc_d2 = sc_s2 + NN;                                // N
    float* disb  = sc_d2 + NN;                                // N
    float* pooled = disb + NN;                                // B*64
    int*   gstart = (int*)(pooled + NB * 64);                 // B+1
    int*   degi   = gstart + NB + 4;                          // N
    int*   incl   = degi + NN;                                // N
    int*   bsum   = incl + NN;                                // 256
    int*   row_ptr = bsum + 256;                              // N+1
    int*   cursor  = row_ptr + NN + 1;                        // N
    int*   csr_src = cursor + NN;                             // NE2

    int off[NSEG]; int o = 0;
    for (int s = 0; s < NSEG; ++s) { off[s] = o; o += kSegN[s]; }
    float* W1f  = wf + off[0];  float* as1f = wf + off[1];  float* ad1f = wf + off[2];
    float* b1f  = wf + off[3];  float* W2f  = wf + off[4];  float* as2f = wf + off[5];
    float* ad2f = wf + off[6];  float* b2f  = wf + off[7];  float* Wgf  = wf + off[8];
    float* bgf  = wf + off[9];  float* bn1g = wf + off[10]; float* bn1b = wf + off[11];
    float* bn2g = wf + off[12]; float* bn2b = wf + off[13]; float* bn3g = wf + off[14];
    float* bn3b = wf + off[15]; float* l1Wf = wf + off[16]; float* l1bf = wf + off[17];
    float* l2Wf = wf + off[18]; float* l2bf = wf + off[19];
    (void)W1f; (void)W2f; (void)Wgf;

    unsigned short* h2b = h1b;   // h1b dead after agg1_k

    // ---- dtype detect + canonicalize (x + weights + transposes fused) ----
    det_k<<<1, 256, 0, stream>>>((const unsigned*)x_raw, flag);
    conv_x_k<<<(NN * 32 + 255) / 256, 256, 0, stream>>>(x_raw, (ushort4*)xb, flag);
    SegArgs sa;
    for (int s = 0; s < NSEG; ++s) { sa.src[s] = d_in[kSegIn[s]]; sa.off[s] = off[s]; }
    prep_w_k<<<(PREP_TOT + 255) / 256, 256, 0, stream>>>(sa, d_in[3], d_in[7], d_in[11],
                                                         wf, W1t, W2t, Wgt, flag);

    // ---- CSR build (by destination) + graph bounds ----
    hipMemsetAsync(degi, 0, NN * sizeof(int), stream);
    deg_k<<<(NE2 + 255) / 256, 256, 0, stream>>>(ei, degi);
    pscan_k<<<NSB, 256, 0, stream>>>(degi, incl, bsum);
    bscan_k<<<1, 256, 0, stream>>>(bsum);
    fscan_k<<<NSB, 256, 0, stream>>>(degi, incl, bsum, row_ptr, cursor, disb);
    scatter_k<<<(NE2 + 255) / 256, 256, 0, stream>>>(ei, cursor, csr_src);
    bounds_k<<<1, 1024, 0, stream>>>(batch, gstart);

    // ---- GAT layer 1 ----
    mgemm_k<128, 256><<<NRT, 256, 0, stream>>>((const short*)xb, (const short*)W1t, h1b);
    scores1_k<<<12500, 256, 0, stream>>>((const ushort4*)h1b, (const float4*)as1f,
                                         (const float4*)ad1f, sc_s1, sc_d1);
    agg1_k<<<12500, 256, 0, stream>>>(row_ptr, csr_src, (const ushort4*)h1b,
                                      (const float4*)sc_s1, (const float4*)sc_d1,
                                      (const float4*)b1f, (const float4*)bn1g,
                                      (const float4*)bn1b, (ushort4*)x1b);

    // ---- GAT layer 2 ----
    mgemm_k<256, 128><<<(NRT * 2 + 3) / 4, 256, 0, stream>>>((const short*)x1b, (const short*)W2t, h2b);
    scores2_k<<<12500, 256, 0, stream>>>((const ushort2*)h2b, (const float2*)as2f,
                                         (const float2*)ad2f, sc_s2, sc_d2);
    agg2_k<<<12500, 256, 0, stream>>>(row_ptr, csr_src, (const ushort4*)h2b,
                                      sc_s2, sc_d2,
                                      (const float4*)b2f, (const float4*)bn2g,
                                      (const float4*)bn2b, (ushort4*)x2b);

    // ---- GCN + pool ----
    mgemm_k<128, 64><<<(NRT + 3) / 4, 256, 0, stream>>>((const short*)x2b, (const short*)Wgt, hgb);
    gcn_k<<<12500, 256, 0, stream>>>(row_ptr, csr_src, (const ushort4*)hgb, disb,
                                     (const float4*)bgf, (float4*)x3);
    pool_k<<<NB, 256, 0, stream>>>(x3, gstart, pooled);

    // ---- MLP head ----
    mlp_k<<<NB, 128, 0, stream>>>(pooled, l1Wf, l1bf, bn3g, bn3b, l2Wf, l2bf, d_out, flag);
}

// Round 9
// 458.878 us; speedup vs baseline: 4.3011x; 1.0380x over previous
//
#include <hip/hip_runtime.h>
#include <hip/hip_bf16.h>

// Problem constants (fixed by the harness)
#define NN  50000      // nodes
#define EE  800000     // edges before self-loops
#define NE2 850000     // edges + self-loops
#define NB  512        // graphs
#define NRT 3125       // row tiles of 16 (NN = 3125*16 exactly)
#define NSB 196        // scan blocks = ceil(NN/256)
// GAT1: F=128 -> 4 heads x 64 (256). GAT2: 256 -> 1 head x 128. GCN: 128 -> 64.

#define BN_RS 0.9999950000374997f   // 1/sqrt(1+1e-5)

typedef __attribute__((ext_vector_type(8))) short short8;
typedef __attribute__((ext_vector_type(4))) float f32x4;

__device__ __forceinline__ float bf2f(__hip_bfloat16 v) { return __bfloat162float(v); }
__device__ __forceinline__ unsigned short f2b(float v) {
    __hip_bfloat16 b = __float2bfloat16(v);
    return *reinterpret_cast<unsigned short*>(&b);
}
__device__ __forceinline__ float u2f(unsigned short u) {
    union { unsigned u; float f; } c; c.u = ((unsigned)u) << 16; return c.f;
}
__device__ __forceinline__ float4 u42f4(ushort4 v) {
    float4 r; r.x = u2f(v.x); r.y = u2f(v.y); r.z = u2f(v.z); r.w = u2f(v.w); return r;
}
__device__ __forceinline__ float lrelu01(float v) { return v > 0.f ? v : 0.01f * v; }
__device__ __forceinline__ float lrelu02(float v) { return v > 0.f ? v : 0.2f * v; }

__device__ __forceinline__ void edge_sd(const int* __restrict__ ei, int e, int& s, int& d) {
    if (e < EE) { s = ei[e]; d = ei[EE + e]; }
    else        { s = e - EE; d = e - EE; }      // self-loop
}

__device__ __forceinline__ float ldf(const void* p, int i, bool bf) {
    return bf ? bf2f(((const __hip_bfloat16*)p)[i]) : ((const float*)p)[i];
}

// ---------------- dtype detector (bf16 vs fp32 inputs) ----------------
__global__ __launch_bounds__(256) void det_k(const unsigned* __restrict__ xw, int* __restrict__ flag) {
    __shared__ int cnt;
    if (threadIdx.x == 0) cnt = 0;
    __syncthreads();
    int c = 0;
#pragma unroll
    for (int k = 0; k < 4; ++k) {
        unsigned w = xw[threadIdx.x * 4 + k];
        unsigned ef = (w >> 7) & 0xFFu;
        if (ef >= 100u && ef <= 140u) c++;
    }
    atomicAdd(&cnt, c);
    __syncthreads();
    if (threadIdx.x == 0) *flag = (cnt > 512) ? 1 : 0;   // 1 = bf16 inputs
}

#define NSEG 20
#define WTOT 85578
#define XQUADS (NN * 32)
#define PREP_TOT (XQUADS + WTOT + 32768 + 32768 + 8192)
struct SegArgs { const void* src[NSEG]; int off[NSEG]; };

// fused: x->bf16 copy + canonical fp32 weights + three bf16 B^T transposes
__global__ __launch_bounds__(256) void prep_k(SegArgs a,
                                              const void* __restrict__ x_raw,
                                              ushort4* __restrict__ xb4,
                                              const void* __restrict__ W1r,
                                              const void* __restrict__ W2r,
                                              const void* __restrict__ Wgr,
                                              float* __restrict__ wf,
                                              unsigned short* __restrict__ W1t,
                                              unsigned short* __restrict__ W2t,
                                              unsigned short* __restrict__ Wgt,
                                              const int* __restrict__ flag) {
    bool bf = (*flag != 0);
    int i = blockIdx.x * 256 + threadIdx.x;
    if (i >= PREP_TOT) return;
    if (i < XQUADS) {
        ushort4 o;
        if (bf) o = ((const ushort4*)x_raw)[i];
        else {
            float4 v = ((const float4*)x_raw)[i];
            o.x = f2b(v.x); o.y = f2b(v.y); o.z = f2b(v.z); o.w = f2b(v.w);
        }
        xb4[i] = o;
        return;
    }
    i -= XQUADS;
    if (i < WTOT) {
        int s = 0;
#pragma unroll
        for (int k = 1; k < NSEG; ++k) if (i >= a.off[k]) s = k;
        wf[i] = ldf(a.src[s], i - a.off[s], bf);
        return;
    }
    i -= WTOT;
    if (i < 32768) {           // W1 [128][256] -> W1t[n*128+k]
        int n = i >> 7, k = i & 127;
        W1t[i] = f2b(ldf(W1r, k * 256 + n, bf));
        return;
    }
    i -= 32768;
    if (i < 32768) {           // W2 [256][128] -> W2t[n*256+k]
        int n = i >> 8, k = i & 255;
        W2t[i] = f2b(ldf(W2r, k * 128 + n, bf));
        return;
    }
    i -= 32768;
    {                          // Wg [128][64] -> Wgt[n*128+k]
        int n = i >> 7, k = i & 127;
        Wgt[i] = f2b(ldf(Wgr, k * 64 + n, bf));
    }
}

// ---------------- CSR build: deg -> 3-phase parallel scan -> scatter ----------------
__global__ __launch_bounds__(256) void deg_k(const int* __restrict__ ei, int* __restrict__ degi) {
    int e = blockIdx.x * 256 + threadIdx.x;
    if (e >= NE2) return;
    int s, d; edge_sd(ei, e, s, d);
    atomicAdd(&degi[d], 1);
}

__global__ __launch_bounds__(256) void pscan_k(const int* __restrict__ degi,
                                               int* __restrict__ incl, int* __restrict__ bsum) {
    __shared__ int tmp[256];
    int t = threadIdx.x;
    int i = blockIdx.x * 256 + t;
    int v = (i < NN) ? degi[i] : 0;
    tmp[t] = v;
    __syncthreads();
#pragma unroll
    for (int off = 1; off < 256; off <<= 1) {
        int u = (t >= off) ? tmp[t - off] : 0;
        __syncthreads();
        tmp[t] += u;
        __syncthreads();
    }
    if (i < NN) incl[i] = tmp[t];
    if (t == 255) bsum[blockIdx.x] = tmp[255];
}

__global__ __launch_bounds__(256) void bscan_k(int* __restrict__ bsum) {
    __shared__ int tmp[256];
    int t = threadIdx.x;
    tmp[t] = (t < NSB) ? bsum[t] : 0;
    __syncthreads();
#pragma unroll
    for (int off = 1; off < 256; off <<= 1) {
        int u = (t >= off) ? tmp[t - off] : 0;
        __syncthreads();
        tmp[t] += u;
        __syncthreads();
    }
    if (t < NSB) bsum[t] = tmp[t];
}

__global__ __launch_bounds__(256) void fscan_k(const int* __restrict__ degi,
                                               const int* __restrict__ incl,
                                               const int* __restrict__ bsum,
                                               int* __restrict__ row_ptr, int* __restrict__ cursor,
                                               float* __restrict__ dis) {
    int i = blockIdx.x * 256 + threadIdx.x;
    if (i >= NN) return;
    int dg = degi[i];
    int base = (blockIdx.x > 0) ? bsum[blockIdx.x - 1] : 0;
    int ex = base + incl[i] - dg;
    row_ptr[i] = ex; cursor[i] = ex;
    dis[i] = dg > 0 ? rsqrtf((float)dg) : 0.f;
    if (i == NN - 1) row_ptr[NN] = bsum[NSB - 1];
}

__global__ __launch_bounds__(256) void scatter_k(const int* __restrict__ ei,
                                                 int* __restrict__ cursor,
                                                 int* __restrict__ csr_src) {
    int e = blockIdx.x * 256 + threadIdx.x;
    if (e >= NE2) return;
    int s, d; edge_sd(ei, e, s, d);
    int pos = atomicAdd(&cursor[d], 1);
    csr_src[pos] = s;
}

// ---------------- GEMM1 + fused GAT1 scores: head == column-group, no LDS needed ----------
// Block = 4 waves = 4 column groups of one 16-row tile.
__global__ __launch_bounds__(256) void mgemm1_k(const short* __restrict__ A,    // xb [N][128]
                                                const short* __restrict__ Bt,   // W1t [256][128]
                                                unsigned short* __restrict__ C, // h1b [N][256]
                                                const float* __restrict__ a_s,  // [256]
                                                const float* __restrict__ a_d,
                                                float* __restrict__ sc_s,       // [N*4]
                                                float* __restrict__ sc_d) {
    int wave = threadIdx.x >> 6, lane = threadIdx.x & 63;
    int rt = blockIdx.x, cg = wave;
    int l15 = lane & 15, quad = lane >> 4;
    const short* ap = A + (size_t)(rt * 16 + l15) * 128 + quad * 8;
    const short* bp = Bt + (size_t)(cg * 64 + l15) * 128 + quad * 8;
    f32x4 acc[4] = {};
    for (int k0 = 0; k0 < 128; k0 += 32) {
        short8 a = *(const short8*)(ap + k0);
#pragma unroll
        for (int j = 0; j < 4; ++j) {
            short8 b = *(const short8*)(bp + (size_t)j * 16 * 128 + k0);
            acc[j] = __builtin_amdgcn_mfma_f32_16x16x32_bf16(a, b, acc[j], 0, 0, 0);
        }
    }
    float asv[4], adv[4];
#pragma unroll
    for (int j = 0; j < 4; ++j) {
        asv[j] = a_s[cg * 64 + j * 16 + l15];
        adv[j] = a_d[cg * 64 + j * 16 + l15];
    }
    float ss[4] = {0.f, 0.f, 0.f, 0.f}, sd[4] = {0.f, 0.f, 0.f, 0.f};
#pragma unroll
    for (int j = 0; j < 4; ++j) {
        int n = cg * 64 + j * 16 + l15;
#pragma unroll
        for (int r = 0; r < 4; ++r) {
            float v = acc[j][r];
            C[(size_t)(rt * 16 + quad * 4 + r) * 256 + n] = f2b(v);
            ss[r] = fmaf(v, asv[j], ss[r]);
            sd[r] = fmaf(v, adv[j], sd[r]);
        }
    }
#pragma unroll
    for (int off = 1; off < 16; off <<= 1) {
#pragma unroll
        for (int r = 0; r < 4; ++r) {
            ss[r] += __shfl_xor(ss[r], off);
            sd[r] += __shfl_xor(sd[r], off);
        }
    }
    if (l15 == 0) {
#pragma unroll
        for (int r = 0; r < 4; ++r) {
            int node = rt * 16 + quad * 4 + r;
            sc_s[node * 4 + cg] = ss[r];
            sc_d[node * 4 + cg] = sd[r];
        }
    }
}

// ---------------- GEMM2 + fused GAT2 scores (1 head over 128 cols, LDS pair-reduce) --------
__global__ __launch_bounds__(256) void mgemm2_k(const short* __restrict__ A,    // x1b [N][256]
                                                const short* __restrict__ Bt,   // W2t [128][256]
                                                unsigned short* __restrict__ C, // h2b [N][128]
                                                const float* __restrict__ a_s,  // [128]
                                                const float* __restrict__ a_d,
                                                float* __restrict__ sc_s,       // [N]
                                                float* __restrict__ sc_d) {
    __shared__ float sred[4][16][2];
    int wave = threadIdx.x >> 6, lane = threadIdx.x & 63;
    int gidx = blockIdx.x * 4 + wave;
    bool act = gidx < NRT * 2;
    int gcl = act ? gidx : NRT * 2 - 1;
    int rt = gcl >> 1, cg = gcl & 1;
    int l15 = lane & 15, quad = lane >> 4;
    const short* ap = A + (size_t)(rt * 16 + l15) * 256 + quad * 8;
    const short* bp = Bt + (size_t)(cg * 64 + l15) * 256 + quad * 8;
    f32x4 acc[4] = {};
    for (int k0 = 0; k0 < 256; k0 += 32) {
        short8 a = *(const short8*)(ap + k0);
#pragma unroll
        for (int j = 0; j < 4; ++j) {
            short8 b = *(const short8*)(bp + (size_t)j * 16 * 256 + k0);
            acc[j] = __builtin_amdgcn_mfma_f32_16x16x32_bf16(a, b, acc[j], 0, 0, 0);
        }
    }
    float asv[4], adv[4];
#pragma unroll
    for (int j = 0; j < 4; ++j) {
        asv[j] = a_s[cg * 64 + j * 16 + l15];
        adv[j] = a_d[cg * 64 + j * 16 + l15];
    }
    float ss[4] = {0.f, 0.f, 0.f, 0.f}, sd[4] = {0.f, 0.f, 0.f, 0.f};
#pragma unroll
    for (int j = 0; j < 4; ++j) {
        int n = cg * 64 + j * 16 + l15;
#pragma unroll
        for (int r = 0; r < 4; ++r) {
            float v = acc[j][r];
            if (act) C[(size_t)(rt * 16 + quad * 4 + r) * 128 + n] = f2b(v);
            ss[r] = fmaf(v, asv[j], ss[r]);
            sd[r] = fmaf(v, adv[j], sd[r]);
        }
    }
#pragma unroll
    for (int off = 1; off < 16; off <<= 1) {
#pragma unroll
        for (int r = 0; r < 4; ++r) {
            ss[r] += __shfl_xor(ss[r], off);
            sd[r] += __shfl_xor(sd[r], off);
        }
    }
    if (l15 == 0) {
#pragma unroll
        for (int r = 0; r < 4; ++r) {
            sred[wave][quad * 4 + r][0] = ss[r];
            sred[wave][quad * 4 + r][1] = sd[r];
        }
    }
    __syncthreads();
    if (threadIdx.x < 32) {
        int rl = threadIdx.x >> 4, row = threadIdx.x & 15;
        int g2 = blockIdx.x * 4 + rl * 2;
        if (g2 < NRT * 2) {
            int node = (g2 >> 1) * 16 + row;
            sc_s[node] = sred[rl * 2][row][0] + sred[rl * 2 + 1][row][0];
            sc_d[node] = sred[rl * 2][row][1] + sred[rl * 2 + 1][row][1];
        }
    }
}

// ---------------- GEMM3 (plain): hg = x2 @ Wg ----------------
__global__ __launch_bounds__(256) void mgemm3_k(const short* __restrict__ A,    // x2b [N][128]
                                                const short* __restrict__ Bt,   // Wgt [64][128]
                                                unsigned short* __restrict__ C) {
    int wave = threadIdx.x >> 6, lane = threadIdx.x & 63;
    int gidx = blockIdx.x * 4 + wave;
    if (gidx >= NRT) return;
    int rt = gidx;
    int l15 = lane & 15, quad = lane >> 4;
    const short* ap = A + (size_t)(rt * 16 + l15) * 128 + quad * 8;
    const short* bp = Bt + (size_t)l15 * 128 + quad * 8;
    f32x4 acc[4] = {};
    for (int k0 = 0; k0 < 128; k0 += 32) {
        short8 a = *(const short8*)(ap + k0);
#pragma unroll
        for (int j = 0; j < 4; ++j) {
            short8 b = *(const short8*)(bp + (size_t)j * 16 * 128 + k0);
            acc[j] = __builtin_amdgcn_mfma_f32_16x16x32_bf16(a, b, acc[j], 0, 0, 0);
        }
    }
#pragma unroll
    for (int j = 0; j < 4; ++j) {
        int n = j * 16 + l15;
#pragma unroll
        for (int r = 0; r < 4; ++r)
            C[(size_t)(rt * 16 + quad * 4 + r) * 64 + n] = f2b(acc[j][r]);
    }
}

__device__ __forceinline__ float sel4(float4 v, int head) {
    float ab = (head & 1) ? v.y : v.x;
    float cd = (head & 1) ? v.w : v.z;
    return (head & 2) ? cd : ab;
}

// ---------------- GAT1 aggregate: wave/node, SGPR-uniform CSR+score loads, 4-deep pipe -----
__global__ __launch_bounds__(256) void agg1_k(const int* __restrict__ row_ptr,
                                              const int* __restrict__ csr_src,
                                              const ushort4* __restrict__ h1b,  // [N*64]
                                              const float4* __restrict__ sc_s4, // [N]
                                              const float4* __restrict__ sc_d4, // [N]
                                              const float4* __restrict__ b1,    // [64]
                                              const float4* __restrict__ g1,
                                              const float4* __restrict__ bb1,
                                              ushort4* __restrict__ x1b) {
    int n = __builtin_amdgcn_readfirstlane((blockIdx.x * 256 + threadIdx.x) >> 6);
    int lane = threadIdx.x & 63;
    if (n >= NN) return;
    int row = row_ptr[n], end = row_ptr[n + 1];
    int head = lane >> 4;
    float scd_h = sel4(sc_d4[n], head);
    float4 acc = {0.f, 0.f, 0.f, 0.f};
    float den = 0.f;
    int c = row;
    for (; c + 3 < end; c += 4) {
        int s0 = csr_src[c], s1 = csr_src[c + 1], s2 = csr_src[c + 2], s3 = csr_src[c + 3];
        float4 scs0 = sc_s4[s0], scs1 = sc_s4[s1], scs2 = sc_s4[s2], scs3 = sc_s4[s3];
        float4 hv0 = u42f4(h1b[(size_t)s0 * 64 + lane]);
        float4 hv1 = u42f4(h1b[(size_t)s1 * 64 + lane]);
        float4 hv2 = u42f4(h1b[(size_t)s2 * 64 + lane]);
        float4 hv3 = u42f4(h1b[(size_t)s3 * 64 + lane]);
        float e0 = __expf(lrelu02(sel4(scs0, head) + scd_h));
        float e1 = __expf(lrelu02(sel4(scs1, head) + scd_h));
        float e2 = __expf(lrelu02(sel4(scs2, head) + scd_h));
        float e3 = __expf(lrelu02(sel4(scs3, head) + scd_h));
        den += (e0 + e1) + (e2 + e3);
        acc.x = fmaf(hv0.x, e0, fmaf(hv1.x, e1, fmaf(hv2.x, e2, fmaf(hv3.x, e3, acc.x))));
        acc.y = fmaf(hv0.y, e0, fmaf(hv1.y, e1, fmaf(hv2.y, e2, fmaf(hv3.y, e3, acc.y))));
        acc.z = fmaf(hv0.z, e0, fmaf(hv1.z, e1, fmaf(hv2.z, e2, fmaf(hv3.z, e3, acc.z))));
        acc.w = fmaf(hv0.w, e0, fmaf(hv1.w, e1, fmaf(hv2.w, e2, fmaf(hv3.w, e3, acc.w))));
    }
    for (; c < end; ++c) {
        int s0 = csr_src[c];
        float4 scs0 = sc_s4[s0];
        float4 hv0 = u42f4(h1b[(size_t)s0 * 64 + lane]);
        float e0 = __expf(lrelu02(sel4(scs0, head) + scd_h));
        den += e0;
        acc.x = fmaf(hv0.x, e0, acc.x);
        acc.y = fmaf(hv0.y, e0, acc.y);
        acc.z = fmaf(hv0.z, e0, acc.z);
        acc.w = fmaf(hv0.w, e0, acc.w);
    }
    float inv = 1.f / (den + 1e-16f);
    float4 bb = b1[lane], gg = g1[lane], be = bb1[lane];
    ushort4 o;
    o.x = f2b(lrelu01(acc.x * inv + bb.x) * (gg.x * BN_RS) + be.x);
    o.y = f2b(lrelu01(acc.y * inv + bb.y) * (gg.y * BN_RS) + be.y);
    o.z = f2b(lrelu01(acc.z * inv + bb.z) * (gg.z * BN_RS) + be.z);
    o.w = f2b(lrelu01(acc.w * inv + bb.w) * (gg.w * BN_RS) + be.w);
    x1b[(size_t)n * 64 + lane] = o;
}

// ---------------- GAT2 aggregate: 2 half-wave groups x 2-unroll ----------------
__global__ __launch_bounds__(256) void agg2_k(const int* __restrict__ row_ptr,
                                              const int* __restrict__ csr_src,
                                              const ushort4* __restrict__ h2b,  // [N*32]
                                              const float* __restrict__ sc_s,   // [N]
                                              const float* __restrict__ sc_d,
                                              const float4* __restrict__ b2,    // [32]
                                              const float4* __restrict__ g2,
                                              const float4* __restrict__ bb2,
                                              ushort4* __restrict__ x2b) {
    int n = __builtin_amdgcn_readfirstlane((blockIdx.x * 256 + threadIdx.x) >> 6);
    int lane = threadIdx.x & 63;
    if (n >= NN) return;
    int g = lane >> 5, sl = lane & 31;
    int row = row_ptr[n], end = row_ptr[n + 1];
    float scd = sc_d[n];
    float4 acc = {0.f, 0.f, 0.f, 0.f};
    float den = 0.f;
    int c = row + g;
    for (; c + 2 < end; c += 4) {
        int s0 = csr_src[c], s1 = csr_src[c + 2];
        float sc0 = sc_s[s0], sc1 = sc_s[s1];
        float4 hv0 = u42f4(h2b[(size_t)s0 * 32 + sl]);
        float4 hv1 = u42f4(h2b[(size_t)s1 * 32 + sl]);
        float e0 = __expf(lrelu02(sc0 + scd));
        float e1 = __expf(lrelu02(sc1 + scd));
        den += e0 + e1;
        acc.x = fmaf(hv0.x, e0, fmaf(hv1.x, e1, acc.x));
        acc.y = fmaf(hv0.y, e0, fmaf(hv1.y, e1, acc.y));
        acc.z = fmaf(hv0.z, e0, fmaf(hv1.z, e1, acc.z));
        acc.w = fmaf(hv0.w, e0, fmaf(hv1.w, e1, acc.w));
    }
    if (c < end) {
        int s0 = csr_src[c];
        float e0 = __expf(lrelu02(sc_s[s0] + scd));
        float4 hv0 = u42f4(h2b[(size_t)s0 * 32 + sl]);
        den += e0;
        acc.x = fmaf(hv0.x, e0, acc.x);
        acc.y = fmaf(hv0.y, e0, acc.y);
        acc.z = fmaf(hv0.z, e0, acc.z);
        acc.w = fmaf(hv0.w, e0, acc.w);
    }
    den += __shfl_xor(den, 32);
    acc.x += __shfl_xor(acc.x, 32);
    acc.y += __shfl_xor(acc.y, 32);
    acc.z += __shfl_xor(acc.z, 32);
    acc.w += __shfl_xor(acc.w, 32);
    if (g == 0) {
        float inv = 1.f / (den + 1e-16f);
        float4 bb = b2[sl], gg = g2[sl], be = bb2[sl];
        ushort4 o;
        o.x = f2b(lrelu01(acc.x * inv + bb.x) * (gg.x * BN_RS) + be.x);
        o.y = f2b(lrelu01(acc.y * inv + bb.y) * (gg.y * BN_RS) + be.y);
        o.z = f2b(lrelu01(acc.z * inv + bb.z) * (gg.z * BN_RS) + be.z);
        o.w = f2b(lrelu01(acc.w * inv + bb.w) * (gg.w * BN_RS) + be.w);
        x2b[(size_t)n * 32 + sl] = o;
    }
}

// ---------------- GCN aggregate: 4 groups x 16 lanes x 2-unroll ----------------
__global__ __launch_bounds__(256) void gcn_k(const int* __restrict__ row_ptr,
                                             const int* __restrict__ csr_src,
                                             const ushort4* __restrict__ hgb,  // [N*16]
                                             const float* __restrict__ dis,
                                             const float4* __restrict__ bg,    // [16]
                                             float4* __restrict__ x3) {        // [N*16]
    int n = __builtin_amdgcn_readfirstlane((blockIdx.x * 256 + threadIdx.x) >> 6);
    int lane = threadIdx.x & 63;
    if (n >= NN) return;
    int g = lane >> 4, sl = lane & 15;
    int row = row_ptr[n], end = row_ptr[n + 1];
    float dn = dis[n];
    float4 acc = {0.f, 0.f, 0.f, 0.f};
    int c = row + g;
    for (; c + 4 < end; c += 8) {
        int s0 = csr_src[c], s1 = csr_src[c + 4];
        float w0 = dis[s0], w1 = dis[s1];
        float4 hv0 = u42f4(hgb[(size_t)s0 * 16 + sl]);
        float4 hv1 = u42f4(hgb[(size_t)s1 * 16 + sl]);
        acc.x = fmaf(hv0.x, w0, fmaf(hv1.x, w1, acc.x));
        acc.y = fmaf(hv0.y, w0, fmaf(hv1.y, w1, acc.y));
        acc.z = fmaf(hv0.z, w0, fmaf(hv1.z, w1, acc.z));
        acc.w = fmaf(hv0.w, w0, fmaf(hv1.w, w1, acc.w));
    }
    if (c < end) {
        int s0 = csr_src[c];
        float w0 = dis[s0];
        float4 hv0 = u42f4(hgb[(size_t)s0 * 16 + sl]);
        acc.x = fmaf(hv0.x, w0, acc.x);
        acc.y = fmaf(hv0.y, w0, acc.y);
        acc.z = fmaf(hv0.z, w0, acc.z);
        acc.w = fmaf(hv0.w, w0, acc.w);
    }
#pragma unroll
    for (int off = 16; off <= 32; off <<= 1) {
        acc.x += __shfl_xor(acc.x, off);
        acc.y += __shfl_xor(acc.y, off);
        acc.z += __shfl_xor(acc.z, off);
        acc.w += __shfl_xor(acc.w, off);
    }
    if (g == 0) {
        float4 bb = bg[sl];
        float4 o;
        o.x = lrelu01(acc.x * dn + bb.x);
        o.y = lrelu01(acc.y * dn + bb.y);
        o.z = lrelu01(acc.z * dn + bb.z);
        o.w = lrelu01(acc.w * dn + bb.w);
        x3[(size_t)n * 16 + sl] = o;
    }
}

// ---------------- graph boundaries ----------------
__global__ __launch_bounds__(1024) void bounds_k(const int* __restrict__ batch, int* __restrict__ gstart) {
    int t = threadIdx.x;
    if (t > NB) return;
    int lo = 0, hi = NN;
    while (lo < hi) { int mid = (lo + hi) >> 1; if (batch[mid] < t) lo = mid + 1; else hi = mid; }
    gstart[t] = lo;
}

// ---------------- segmented mean-pool ----------------
__global__ __launch_bounds__(256) void pool_k(const float* __restrict__ x3,
                                              const int* __restrict__ gstart,
                                              float* __restrict__ pooled) {
    __shared__ float red[4][64];
    int g = blockIdx.x, t = threadIdx.x;
    int c = t & 63, r = t >> 6;
    int s = gstart[g], e = gstart[g + 1];
    float sum = 0.f;
    for (int n = s + r; n < e; n += 4) sum += x3[(size_t)n * 64 + c];
    red[r][c] = sum;
    __syncthreads();
    if (t < 64) {
        float v = red[0][t] + red[1][t] + red[2][t] + red[3][t];
        int cnt = e - s; if (cnt < 1) cnt = 1;
        pooled[g * 64 + t] = v / (float)cnt;
    }
}

// ---------------- per-graph MLP head ----------------
__global__ __launch_bounds__(128) void mlp_k(const float* __restrict__ pooled,
                                             const float* __restrict__ l1W,
                                             const float* __restrict__ l1b,
                                             const float* __restrict__ g3,
                                             const float* __restrict__ b3,
                                             const float* __restrict__ l2W,
                                             const float* __restrict__ l2b,
                                             void* __restrict__ outp,
                                             const int* __restrict__ flag) {
    __shared__ float pl[64];
    __shared__ float y1s[128];
    int g = blockIdx.x, t = threadIdx.x;
    if (t < 64) pl[t] = pooled[g * 64 + t];
    __syncthreads();
    float acc = l1b[t];
#pragma unroll 8
    for (int j = 0; j < 64; ++j) acc = fmaf(pl[j], l1W[j * 128 + t], acc);
    acc = acc * (g3[t] * BN_RS) + b3[t];
    y1s[t] = lrelu01(acc);
    __syncthreads();
    if (t < 10) {
        float o = l2b[t];
#pragma unroll 8
        for (int j = 0; j < 128; ++j) o = fmaf(y1s[j], l2W[j * 10 + t], o);
        if (*flag) ((__hip_bfloat16*)outp)[g * 10 + t] = __float2bfloat16(o);
        else       ((float*)outp)[g * 10 + t] = o;
    }
}

// weight segment sizes (W1,as1,ad1,b1,W2,as2,ad2,b2,Wg,bg,bn1g,bn1b,bn2g,bn2b,bn3g,bn3b,l1W,l1b,l2W,l2b)
static const int kSegN[NSEG]  = {32768, 256, 256, 256, 32768, 128, 128, 128, 8192, 64,
                                 256, 256, 128, 128, 128, 128, 8192, 128, 1280, 10};
static const int kSegIn[NSEG] = {3, 4, 5, 6, 7, 8, 9, 10, 11, 12, 13, 14, 15, 16, 17, 18, 19, 20, 21, 22};

extern "C" void kernel_launch(void* const* d_in, const int* in_sizes, int n_in,
                              void* d_out, int out_size, void* d_ws, size_t ws_size,
                              hipStream_t stream) {
    const void* x_raw = d_in[0];
    const int*  ei    = (const int*)d_in[1];
    const int*  batch = (const int*)d_in[2];

    // ---- workspace layout ----
    int*   flag = (int*)d_ws;
    float* ws   = (float*)d_ws;
    unsigned short* xb = (unsigned short*)(ws + 16);          // N*128 bf16
    float* wf   = ws + 16 + (size_t)NN * 64;                  // 85584 fp32 canonical
    unsigned short* W1t = (unsigned short*)(wf + 85584);      // 32768 bf16 [256][128]
    unsigned short* W2t = W1t + 32768;                        // 32768 bf16 [128][256]
    unsigned short* Wgt = W2t + 32768;                        // 8192  bf16 [64][128]
    unsigned short* h1b = Wgt + 8192;                         // N*256 bf16 (reused as h2b)
    unsigned short* x1b = h1b + (size_t)NN * 256;             // N*256 bf16
    unsigned short* x2b = x1b + (size_t)NN * 256;             // N*128 bf16
    unsigned short* hgb = x2b + (size_t)NN * 128;             // N*64 bf16
    float* x3   = (float*)(hgb + (size_t)NN * 64);            // N*64 fp32
    float* sc_s1 = x3 + (size_t)NN * 64;                      // N*4
    float* sc_d1 = sc_s1 + (size_t)NN * 4;                    // N*4
    float* sc_s2 = sc_d1 + (size_t)NN * 4;                    // N
    float* sc_d2 = sc_s2 + NN;                                // N
    float* disb  = sc_d2 + NN;                                // N
    float* pooled = disb + NN;                                // B*64
    int*   gstart = (int*)(pooled + NB * 64);                 // B+1
    int*   degi   = gstart + NB + 4;                          // N
    int*   incl   = degi + NN;                                // N
    int*   bsum   = incl + NN;                                // 256
    int*   row_ptr = bsum + 256;                              // N+1
    int*   cursor  = row_ptr + NN + 1;                        // N
    int*   csr_src = cursor + NN;                             // NE2

    int off[NSEG]; int o = 0;
    for (int s = 0; s < NSEG; ++s) { off[s] = o; o += kSegN[s]; }
    float* as1f = wf + off[1];  float* ad1f = wf + off[2];
    float* b1f  = wf + off[3];  float* as2f = wf + off[5];
    float* ad2f = wf + off[6];  float* b2f  = wf + off[7];
    float* bgf  = wf + off[9];  float* bn1g = wf + off[10]; float* bn1b = wf + off[11];
    float* bn2g = wf + off[12]; float* bn2b = wf + off[13]; float* bn3g = wf + off[14];
    float* bn3b = wf + off[15]; float* l1Wf = wf + off[16]; float* l1bf = wf + off[17];
    float* l2Wf = wf + off[18]; float* l2bf = wf + off[19];

    unsigned short* h2b = h1b;   // h1b dead after agg1_k

    // ---- dtype detect + canonicalize (x + weights + transposes in one kernel) ----
    det_k<<<1, 256, 0, stream>>>((const unsigned*)x_raw, flag);
    SegArgs sa;
    for (int s = 0; s < NSEG; ++s) { sa.src[s] = d_in[kSegIn[s]]; sa.off[s] = off[s]; }
    prep_k<<<(PREP_TOT + 255) / 256, 256, 0, stream>>>(sa, x_raw, (ushort4*)xb,
                                                       d_in[3], d_in[7], d_in[11],
                                                       wf, W1t, W2t, Wgt, flag);

    // ---- CSR build (by destination) + graph bounds ----
    hipMemsetAsync(degi, 0, NN * sizeof(int), stream);
    deg_k<<<(NE2 + 255) / 256, 256, 0, stream>>>(ei, degi);
    pscan_k<<<NSB, 256, 0, stream>>>(degi, incl, bsum);
    bscan_k<<<1, 256, 0, stream>>>(bsum);
    fscan_k<<<NSB, 256, 0, stream>>>(degi, incl, bsum, row_ptr, cursor, disb);
    scatter_k<<<(NE2 + 255) / 256, 256, 0, stream>>>(ei, cursor, csr_src);
    bounds_k<<<1, 1024, 0, stream>>>(batch, gstart);

    // ---- GAT layer 1 (scores fused into GEMM) ----
    mgemm1_k<<<NRT, 256, 0, stream>>>((const short*)xb, (const short*)W1t, h1b,
                                      as1f, ad1f, sc_s1, sc_d1);
    agg1_k<<<12500, 256, 0, stream>>>(row_ptr, csr_src, (const ushort4*)h1b,
                                      (const float4*)sc_s1, (const float4*)sc_d1,
                                      (const float4*)b1f, (const float4*)bn1g,
                                      (const float4*)bn1b, (ushort4*)x1b);

    // ---- GAT layer 2 (scores fused into GEMM) ----
    mgemm2_k<<<(NRT * 2 + 3) / 4, 256, 0, stream>>>((const short*)x1b, (const short*)W2t, h2b,
                                                    as2f, ad2f, sc_s2, sc_d2);
    agg2_k<<<12500, 256, 0, stream>>>(row_ptr, csr_src, (const ushort4*)h2b,
                                      sc_s2, sc_d2,
                                      (const float4*)b2f, (const float4*)bn2g,
                                      (const float4*)bn2b, (ushort4*)x2b);

    // ---- GCN + pool ----
    mgemm3_k<<<(NRT + 3) / 4, 256, 0, stream>>>((const short*)x2b, (const short*)Wgt, hgb);
    gcn_k<<<12500, 256, 0, stream>>>(row_ptr, csr_src, (const ushort4*)hgb, disb,
                                     (const float4*)bgf, (float4*)x3);
    pool_k<<<NB, 256, 0, stream>>>(x3, gstart, pooled);

    // ---- MLP head ----
    mlp_k<<<NB, 128, 0, stream>>>(pooled, l1Wf, l1bf, bn3g, bn3b, l2Wf, l2bf, d_out, flag);
}

// Round 10
// 455.921 us; speedup vs baseline: 4.3290x; 1.0065x over previous
//
#include <hip/hip_runtime.h>
#include <hip/hip_bf16.h>

// Problem constants (fixed by the harness)
#define NN  50000      // nodes
#define EE  800000     // edges before self-loops
#define NE2 850000     // edges + self-loops
#define NB  512        // graphs
#define NRT 3125       // row tiles of 16 (NN = 3125*16 exactly)
#define NSB 196        // scan blocks = ceil(NN/256)
// GAT1: F=128 -> 4 heads x 64 (256). GAT2: 256 -> 1 head x 128. GCN: 128 -> 64.

#define BN_RS 0.9999950000374997f   // 1/sqrt(1+1e-5)

typedef __attribute__((ext_vector_type(8))) short short8;
typedef __attribute__((ext_vector_type(4))) float f32x4;

__device__ __forceinline__ float bf2f(__hip_bfloat16 v) { return __bfloat162float(v); }
__device__ __forceinline__ unsigned short f2b(float v) {
    __hip_bfloat16 b = __float2bfloat16(v);
    return *reinterpret_cast<unsigned short*>(&b);
}
__device__ __forceinline__ float u2f(unsigned short u) {
    union { unsigned u; float f; } c; c.u = ((unsigned)u) << 16; return c.f;
}
__device__ __forceinline__ float4 u42f4(ushort4 v) {
    float4 r; r.x = u2f(v.x); r.y = u2f(v.y); r.z = u2f(v.z); r.w = u2f(v.w); return r;
}
__device__ __forceinline__ float lrelu01(float v) { return v > 0.f ? v : 0.01f * v; }
__device__ __forceinline__ float lrelu02(float v) { return v > 0.f ? v : 0.2f * v; }

__device__ __forceinline__ void edge_sd(const int* __restrict__ ei, int e, int& s, int& d) {
    if (e < EE) { s = ei[e]; d = ei[EE + e]; }
    else        { s = e - EE; d = e - EE; }      // self-loop
}

__device__ __forceinline__ float ldf(const void* p, int i, bool bf) {
    return bf ? bf2f(((const __hip_bfloat16*)p)[i]) : ((const float*)p)[i];
}

#define NSEG 20
#define WTOT 85578
#define XQUADS (NN * 32)
// prep index space: [0,NN) zero degi | x quads | weights | W1t | W2t | Wgt
#define PREP_TOT (NN + XQUADS + WTOT + 32768 + 32768 + 8192)
struct SegArgs { const void* src[NSEG]; int off[NSEG]; };

// fused: per-block dtype detect + degi zero + x->bf16 + fp32 weights + three bf16 B^T transposes
__global__ __launch_bounds__(256) void prep_k(SegArgs a,
                                              const void* __restrict__ x_raw,
                                              ushort4* __restrict__ xb4,
                                              const void* __restrict__ W1r,
                                              const void* __restrict__ W2r,
                                              const void* __restrict__ Wgr,
                                              float* __restrict__ wf,
                                              unsigned short* __restrict__ W1t,
                                              unsigned short* __restrict__ W2t,
                                              unsigned short* __restrict__ Wgt,
                                              int* __restrict__ degi,
                                              int* __restrict__ flag) {
    __shared__ int cnt;
    int t = threadIdx.x;
    if (t == 0) cnt = 0;
    __syncthreads();
    {
        int c = 0;
        const unsigned* xw = (const unsigned*)x_raw;
#pragma unroll
        for (int k = 0; k < 4; ++k) {
            unsigned w = xw[t * 4 + k];
            unsigned ef = (w >> 7) & 0xFFu;
            if (ef >= 100u && ef <= 140u) c++;
        }
        atomicAdd(&cnt, c);
    }
    __syncthreads();
    bool bf = (cnt > 512);
    if (blockIdx.x == 0 && t == 0) *flag = bf ? 1 : 0;

    int i = blockIdx.x * 256 + t;
    if (i >= PREP_TOT) return;
    if (i < NN) { degi[i] = 0; return; }
    i -= NN;
    if (i < XQUADS) {
        ushort4 o;
        if (bf) o = ((const ushort4*)x_raw)[i];
        else {
            float4 v = ((const float4*)x_raw)[i];
            o.x = f2b(v.x); o.y = f2b(v.y); o.z = f2b(v.z); o.w = f2b(v.w);
        }
        xb4[i] = o;
        return;
    }
    i -= XQUADS;
    if (i < WTOT) {
        int s = 0;
#pragma unroll
        for (int k = 1; k < NSEG; ++k) if (i >= a.off[k]) s = k;
        wf[i] = ldf(a.src[s], i - a.off[s], bf);
        return;
    }
    i -= WTOT;
    if (i < 32768) {           // W1 [128][256] -> W1t[n*128+k]
        int n = i >> 7, k = i & 127;
        W1t[i] = f2b(ldf(W1r, k * 256 + n, bf));
        return;
    }
    i -= 32768;
    if (i < 32768) {           // W2 [256][128] -> W2t[n*256+k]
        int n = i >> 8, k = i & 255;
        W2t[i] = f2b(ldf(W2r, k * 128 + n, bf));
        return;
    }
    i -= 32768;
    {                          // Wg [128][64] -> Wgt[n*128+k]
        int n = i >> 7, k = i & 127;
        Wgt[i] = f2b(ldf(Wgr, k * 64 + n, bf));
    }
}

// ---------------- CSR build: deg -> 3-phase parallel scan -> scatter ----------------
__global__ __launch_bounds__(256) void deg_k(const int* __restrict__ ei, int* __restrict__ degi) {
    int e = blockIdx.x * 256 + threadIdx.x;
    if (e >= NE2) return;
    int s, d; edge_sd(ei, e, s, d);
    atomicAdd(&degi[d], 1);
}

__global__ __launch_bounds__(256) void pscan_k(const int* __restrict__ degi,
                                               int* __restrict__ incl, int* __restrict__ bsum) {
    __shared__ int tmp[256];
    int t = threadIdx.x;
    int i = blockIdx.x * 256 + t;
    int v = (i < NN) ? degi[i] : 0;
    tmp[t] = v;
    __syncthreads();
#pragma unroll
    for (int off = 1; off < 256; off <<= 1) {
        int u = (t >= off) ? tmp[t - off] : 0;
        __syncthreads();
        tmp[t] += u;
        __syncthreads();
    }
    if (i < NN) incl[i] = tmp[t];
    if (t == 255) bsum[blockIdx.x] = tmp[255];
}

__global__ __launch_bounds__(256) void bscan_k(int* __restrict__ bsum) {
    __shared__ int tmp[256];
    int t = threadIdx.x;
    tmp[t] = (t < NSB) ? bsum[t] : 0;
    __syncthreads();
#pragma unroll
    for (int off = 1; off < 256; off <<= 1) {
        int u = (t >= off) ? tmp[t - off] : 0;
        __syncthreads();
        tmp[t] += u;
        __syncthreads();
    }
    if (t < NSB) bsum[t] = tmp[t];
}

// phase 3: exclusive row_ptr + cursor + dis; blocks 0..2 also compute graph bounds
__global__ __launch_bounds__(256) void fscan_k(const int* __restrict__ degi,
                                               const int* __restrict__ incl,
                                               const int* __restrict__ bsum,
                                               const int* __restrict__ batch,
                                               int* __restrict__ row_ptr, int* __restrict__ cursor,
                                               float* __restrict__ dis, int* __restrict__ gstart) {
    int i = blockIdx.x * 256 + threadIdx.x;
    if (i <= NB) {
        int lo = 0, hi = NN;
        while (lo < hi) { int mid = (lo + hi) >> 1; if (batch[mid] < i) lo = mid + 1; else hi = mid; }
        gstart[i] = lo;
    }
    if (i >= NN) return;
    int dg = degi[i];
    int base = (blockIdx.x > 0) ? bsum[blockIdx.x - 1] : 0;
    int ex = base + incl[i] - dg;
    row_ptr[i] = ex; cursor[i] = ex;
    dis[i] = dg > 0 ? rsqrtf((float)dg) : 0.f;
    if (i == NN - 1) row_ptr[NN] = bsum[NSB - 1];
}

__global__ __launch_bounds__(256) void scatter_k(const int* __restrict__ ei,
                                                 int* __restrict__ cursor,
                                                 int* __restrict__ csr_src) {
    int e = blockIdx.x * 256 + threadIdx.x;
    if (e >= NE2) return;
    int s, d; edge_sd(ei, e, s, d);
    int pos = atomicAdd(&cursor[d], 1);
    csr_src[pos] = s;
}

// ---------------- GEMM1 + fused GAT1 scores ----------------
__global__ __launch_bounds__(256) void mgemm1_k(const short* __restrict__ A,    // xb [N][128]
                                                const short* __restrict__ Bt,   // W1t [256][128]
                                                unsigned short* __restrict__ C, // h1b [N][256]
                                                const float* __restrict__ a_s,  // [256]
                                                const float* __restrict__ a_d,
                                                float* __restrict__ sc_s,       // [N*4]
                                                float* __restrict__ sc_d) {
    int wave = threadIdx.x >> 6, lane = threadIdx.x & 63;
    int rt = blockIdx.x, cg = wave;
    int l15 = lane & 15, quad = lane >> 4;
    const short* ap = A + (size_t)(rt * 16 + l15) * 128 + quad * 8;
    const short* bp = Bt + (size_t)(cg * 64 + l15) * 128 + quad * 8;
    f32x4 acc[4] = {};
    for (int k0 = 0; k0 < 128; k0 += 32) {
        short8 a = *(const short8*)(ap + k0);
#pragma unroll
        for (int j = 0; j < 4; ++j) {
            short8 b = *(const short8*)(bp + (size_t)j * 16 * 128 + k0);
            acc[j] = __builtin_amdgcn_mfma_f32_16x16x32_bf16(a, b, acc[j], 0, 0, 0);
        }
    }
    float asv[4], adv[4];
#pragma unroll
    for (int j = 0; j < 4; ++j) {
        asv[j] = a_s[cg * 64 + j * 16 + l15];
        adv[j] = a_d[cg * 64 + j * 16 + l15];
    }
    float ss[4] = {0.f, 0.f, 0.f, 0.f}, sd[4] = {0.f, 0.f, 0.f, 0.f};
#pragma unroll
    for (int j = 0; j < 4; ++j) {
        int n = cg * 64 + j * 16 + l15;
#pragma unroll
        for (int r = 0; r < 4; ++r) {
            float v = acc[j][r];
            C[(size_t)(rt * 16 + quad * 4 + r) * 256 + n] = f2b(v);
            ss[r] = fmaf(v, asv[j], ss[r]);
            sd[r] = fmaf(v, adv[j], sd[r]);
        }
    }
#pragma unroll
    for (int off = 1; off < 16; off <<= 1) {
#pragma unroll
        for (int r = 0; r < 4; ++r) {
            ss[r] += __shfl_xor(ss[r], off);
            sd[r] += __shfl_xor(sd[r], off);
        }
    }
    if (l15 == 0) {
#pragma unroll
        for (int r = 0; r < 4; ++r) {
            int node = rt * 16 + quad * 4 + r;
            sc_s[node * 4 + cg] = ss[r];
            sc_d[node * 4 + cg] = sd[r];
        }
    }
}

// ---------------- GEMM2 + fused GAT2 scores ----------------
__global__ __launch_bounds__(256) void mgemm2_k(const short* __restrict__ A,    // x1b [N][256]
                                                const short* __restrict__ Bt,   // W2t [128][256]
                                                unsigned short* __restrict__ C, // h2b [N][128]
                                                const float* __restrict__ a_s,  // [128]
                                                const float* __restrict__ a_d,
                                                float* __restrict__ sc_s,       // [N]
                                                float* __restrict__ sc_d) {
    __shared__ float sred[4][16][2];
    int wave = threadIdx.x >> 6, lane = threadIdx.x & 63;
    int gidx = blockIdx.x * 4 + wave;
    bool act = gidx < NRT * 2;
    int gcl = act ? gidx : NRT * 2 - 1;
    int rt = gcl >> 1, cg = gcl & 1;
    int l15 = lane & 15, quad = lane >> 4;
    const short* ap = A + (size_t)(rt * 16 + l15) * 256 + quad * 8;
    const short* bp = Bt + (size_t)(cg * 64 + l15) * 256 + quad * 8;
    f32x4 acc[4] = {};
    for (int k0 = 0; k0 < 256; k0 += 32) {
        short8 a = *(const short8*)(ap + k0);
#pragma unroll
        for (int j = 0; j < 4; ++j) {
            short8 b = *(const short8*)(bp + (size_t)j * 16 * 256 + k0);
            acc[j] = __builtin_amdgcn_mfma_f32_16x16x32_bf16(a, b, acc[j], 0, 0, 0);
        }
    }
    float asv[4], adv[4];
#pragma unroll
    for (int j = 0; j < 4; ++j) {
        asv[j] = a_s[cg * 64 + j * 16 + l15];
        adv[j] = a_d[cg * 64 + j * 16 + l15];
    }
    float ss[4] = {0.f, 0.f, 0.f, 0.f}, sd[4] = {0.f, 0.f, 0.f, 0.f};
#pragma unroll
    for (int j = 0; j < 4; ++j) {
        int n = cg * 64 + j * 16 + l15;
#pragma unroll
        for (int r = 0; r < 4; ++r) {
            float v = acc[j][r];
            if (act) C[(size_t)(rt * 16 + quad * 4 + r) * 128 + n] = f2b(v);
            ss[r] = fmaf(v, asv[j], ss[r]);
            sd[r] = fmaf(v, adv[j], sd[r]);
        }
    }
#pragma unroll
    for (int off = 1; off < 16; off <<= 1) {
#pragma unroll
        for (int r = 0; r < 4; ++r) {
            ss[r] += __shfl_xor(ss[r], off);
            sd[r] += __shfl_xor(sd[r], off);
        }
    }
    if (l15 == 0) {
#pragma unroll
        for (int r = 0; r < 4; ++r) {
            sred[wave][quad * 4 + r][0] = ss[r];
            sred[wave][quad * 4 + r][1] = sd[r];
        }
    }
    __syncthreads();
    if (threadIdx.x < 32) {
        int rl = threadIdx.x >> 4, row = threadIdx.x & 15;
        int g2 = blockIdx.x * 4 + rl * 2;
        if (g2 < NRT * 2) {
            int node = (g2 >> 1) * 16 + row;
            sc_s[node] = sred[rl * 2][row][0] + sred[rl * 2 + 1][row][0];
            sc_d[node] = sred[rl * 2][row][1] + sred[rl * 2 + 1][row][1];
        }
    }
}

// ---------------- GEMM3 (plain): hg = x2 @ Wg ----------------
__global__ __launch_bounds__(256) void mgemm3_k(const short* __restrict__ A,    // x2b [N][128]
                                                const short* __restrict__ Bt,   // Wgt [64][128]
                                                unsigned short* __restrict__ C) {
    int wave = threadIdx.x >> 6, lane = threadIdx.x & 63;
    int gidx = blockIdx.x * 4 + wave;
    if (gidx >= NRT) return;
    int rt = gidx;
    int l15 = lane & 15, quad = lane >> 4;
    const short* ap = A + (size_t)(rt * 16 + l15) * 128 + quad * 8;
    const short* bp = Bt + (size_t)l15 * 128 + quad * 8;
    f32x4 acc[4] = {};
    for (int k0 = 0; k0 < 128; k0 += 32) {
        short8 a = *(const short8*)(ap + k0);
#pragma unroll
        for (int j = 0; j < 4; ++j) {
            short8 b = *(const short8*)(bp + (size_t)j * 16 * 128 + k0);
            acc[j] = __builtin_amdgcn_mfma_f32_16x16x32_bf16(a, b, acc[j], 0, 0, 0);
        }
    }
#pragma unroll
    for (int j = 0; j < 4; ++j) {
        int n = j * 16 + l15;
#pragma unroll
        for (int r = 0; r < 4; ++r)
            C[(size_t)(rt * 16 + quad * 4 + r) * 64 + n] = f2b(acc[j][r]);
    }
}

__device__ __forceinline__ float sel4(float4 v, int head) {
    float ab = (head & 1) ? v.y : v.x;
    float cd = (head & 1) ? v.w : v.z;
    return (head & 2) ? cd : ab;
}

// ---------------- GAT1 aggregate: wave/node, scalar CSR+score loads, 8-deep pipeline ------
__global__ __launch_bounds__(256) void agg1_k(const int* __restrict__ row_ptr,
                                              const int* __restrict__ csr_src,
                                              const ushort4* __restrict__ h1b,  // [N*64]
                                              const float4* __restrict__ sc_s4, // [N]
                                              const float4* __restrict__ sc_d4, // [N]
                                              const float4* __restrict__ b1,    // [64]
                                              const float4* __restrict__ g1,
                                              const float4* __restrict__ bb1,
                                              ushort4* __restrict__ x1b) {
    int n = __builtin_amdgcn_readfirstlane((blockIdx.x * 256 + threadIdx.x) >> 6);
    int lane = threadIdx.x & 63;
    if (n >= NN) return;
    int row = row_ptr[n], end = row_ptr[n + 1];
    int head = lane >> 4;
    float scd_h = sel4(sc_d4[n], head);
    float4 acc = {0.f, 0.f, 0.f, 0.f};
    float den = 0.f;
    int c = row;
    for (; c + 7 < end; c += 8) {
        int s[8];
#pragma unroll
        for (int j = 0; j < 8; ++j) s[j] = csr_src[c + j];
        float4 scs[8];
#pragma unroll
        for (int j = 0; j < 8; ++j) scs[j] = sc_s4[s[j]];
        ushort4 hu[8];
#pragma unroll
        for (int j = 0; j < 8; ++j) hu[j] = h1b[(size_t)s[j] * 64 + lane];
        float e[8];
#pragma unroll
        for (int j = 0; j < 8; ++j) { e[j] = __expf(lrelu02(sel4(scs[j], head) + scd_h)); den += e[j]; }
#pragma unroll
        for (int j = 0; j < 8; ++j) {
            float4 hv = u42f4(hu[j]);
            acc.x = fmaf(hv.x, e[j], acc.x);
            acc.y = fmaf(hv.y, e[j], acc.y);
            acc.z = fmaf(hv.z, e[j], acc.z);
            acc.w = fmaf(hv.w, e[j], acc.w);
        }
    }
    for (; c + 3 < end; c += 4) {
        int s[4];
#pragma unroll
        for (int j = 0; j < 4; ++j) s[j] = csr_src[c + j];
        float4 scs[4];
#pragma unroll
        for (int j = 0; j < 4; ++j) scs[j] = sc_s4[s[j]];
        ushort4 hu[4];
#pragma unroll
        for (int j = 0; j < 4; ++j) hu[j] = h1b[(size_t)s[j] * 64 + lane];
#pragma unroll
        for (int j = 0; j < 4; ++j) {
            float e0 = __expf(lrelu02(sel4(scs[j], head) + scd_h));
            den += e0;
            float4 hv = u42f4(hu[j]);
            acc.x = fmaf(hv.x, e0, acc.x);
            acc.y = fmaf(hv.y, e0, acc.y);
            acc.z = fmaf(hv.z, e0, acc.z);
            acc.w = fmaf(hv.w, e0, acc.w);
        }
    }
    for (; c < end; ++c) {
        int s0 = csr_src[c];
        float4 scs0 = sc_s4[s0];
        float4 hv0 = u42f4(h1b[(size_t)s0 * 64 + lane]);
        float e0 = __expf(lrelu02(sel4(scs0, head) + scd_h));
        den += e0;
        acc.x = fmaf(hv0.x, e0, acc.x);
        acc.y = fmaf(hv0.y, e0, acc.y);
        acc.z = fmaf(hv0.z, e0, acc.z);
        acc.w = fmaf(hv0.w, e0, acc.w);
    }
    float inv = 1.f / (den + 1e-16f);
    float4 bb = b1[lane], gg = g1[lane], be = bb1[lane];
    ushort4 o;
    o.x = f2b(lrelu01(acc.x * inv + bb.x) * (gg.x * BN_RS) + be.x);
    o.y = f2b(lrelu01(acc.y * inv + bb.y) * (gg.y * BN_RS) + be.y);
    o.z = f2b(lrelu01(acc.z * inv + bb.z) * (gg.z * BN_RS) + be.z);
    o.w = f2b(lrelu01(acc.w * inv + bb.w) * (gg.w * BN_RS) + be.w);
    x1b[(size_t)n * 64 + lane] = o;
}

// ---------------- GAT2 aggregate: 2 half-wave groups x 4-unroll (8 in flight) -------------
__global__ __launch_bounds__(256) void agg2_k(const int* __restrict__ row_ptr,
                                              const int* __restrict__ csr_src,
                                              const ushort4* __restrict__ h2b,  // [N*32]
                                              const float* __restrict__ sc_s,   // [N]
                                              const float* __restrict__ sc_d,
                                              const float4* __restrict__ b2,    // [32]
                                              const float4* __restrict__ g2,
                                              const float4* __restrict__ bb2,
                                              ushort4* __restrict__ x2b) {
    int n = __builtin_amdgcn_readfirstlane((blockIdx.x * 256 + threadIdx.x) >> 6);
    int lane = threadIdx.x & 63;
    if (n >= NN) return;
    int g = lane >> 5, sl = lane & 31;
    int row = row_ptr[n], end = row_ptr[n + 1];
    float scd = sc_d[n];
    float4 acc = {0.f, 0.f, 0.f, 0.f};
    float den = 0.f;
    int c = row + g;
    for (; c + 6 < end; c += 8) {
        int s[4];
#pragma unroll
        for (int j = 0; j < 4; ++j) s[j] = csr_src[c + 2 * j];
        float sc[4];
#pragma unroll
        for (int j = 0; j < 4; ++j) sc[j] = sc_s[s[j]];
        ushort4 hu[4];
#pragma unroll
        for (int j = 0; j < 4; ++j) hu[j] = h2b[(size_t)s[j] * 32 + sl];
#pragma unroll
        for (int j = 0; j < 4; ++j) {
            float e0 = __expf(lrelu02(sc[j] + scd));
            den += e0;
            float4 hv = u42f4(hu[j]);
            acc.x = fmaf(hv.x, e0, acc.x);
            acc.y = fmaf(hv.y, e0, acc.y);
            acc.z = fmaf(hv.z, e0, acc.z);
            acc.w = fmaf(hv.w, e0, acc.w);
        }
    }
    for (; c < end; c += 2) {
        int s0 = csr_src[c];
        float e0 = __expf(lrelu02(sc_s[s0] + scd));
        float4 hv0 = u42f4(h2b[(size_t)s0 * 32 + sl]);
        den += e0;
        acc.x = fmaf(hv0.x, e0, acc.x);
        acc.y = fmaf(hv0.y, e0, acc.y);
        acc.z = fmaf(hv0.z, e0, acc.z);
        acc.w = fmaf(hv0.w, e0, acc.w);
    }
    den += __shfl_xor(den, 32);
    acc.x += __shfl_xor(acc.x, 32);
    acc.y += __shfl_xor(acc.y, 32);
    acc.z += __shfl_xor(acc.z, 32);
    acc.w += __shfl_xor(acc.w, 32);
    if (g == 0) {
        float inv = 1.f / (den + 1e-16f);
        float4 bb = b2[sl], gg = g2[sl], be = bb2[sl];
        ushort4 o;
        o.x = f2b(lrelu01(acc.x * inv + bb.x) * (gg.x * BN_RS) + be.x);
        o.y = f2b(lrelu01(acc.y * inv + bb.y) * (gg.y * BN_RS) + be.y);
        o.z = f2b(lrelu01(acc.z * inv + bb.z) * (gg.z * BN_RS) + be.z);
        o.w = f2b(lrelu01(acc.w * inv + bb.w) * (gg.w * BN_RS) + be.w);
        x2b[(size_t)n * 32 + sl] = o;
    }
}

// ---------------- GCN aggregate: 4 groups x 16 lanes x 4-unroll (16 in flight) ------------
__global__ __launch_bounds__(256) void gcn_k(const int* __restrict__ row_ptr,
                                             const int* __restrict__ csr_src,
                                             const ushort4* __restrict__ hgb,  // [N*16]
                                             const float* __restrict__ dis,
                                             const float4* __restrict__ bg,    // [16]
                                             float4* __restrict__ x3) {        // [N*16]
    int n = __builtin_amdgcn_readfirstlane((blockIdx.x * 256 + threadIdx.x) >> 6);
    int lane = threadIdx.x & 63;
    if (n >= NN) return;
    int g = lane >> 4, sl = lane & 15;
    int row = row_ptr[n], end = row_ptr[n + 1];
    float dn = dis[n];
    float4 acc = {0.f, 0.f, 0.f, 0.f};
    int c = row + g;
    for (; c + 12 < end; c += 16) {
        int s[4];
#pragma unroll
        for (int j = 0; j < 4; ++j) s[j] = csr_src[c + 4 * j];
        float w[4];
#pragma unroll
        for (int j = 0; j < 4; ++j) w[j] = dis[s[j]];
        ushort4 hu[4];
#pragma unroll
        for (int j = 0; j < 4; ++j) hu[j] = hgb[(size_t)s[j] * 16 + sl];
#pragma unroll
        for (int j = 0; j < 4; ++j) {
            float4 hv = u42f4(hu[j]);
            acc.x = fmaf(hv.x, w[j], acc.x);
            acc.y = fmaf(hv.y, w[j], acc.y);
            acc.z = fmaf(hv.z, w[j], acc.z);
            acc.w = fmaf(hv.w, w[j], acc.w);
        }
    }
    for (; c < end; c += 4) {
        int s0 = csr_src[c];
        float w0 = dis[s0];
        float4 hv0 = u42f4(hgb[(size_t)s0 * 16 + sl]);
        acc.x = fmaf(hv0.x, w0, acc.x);
        acc.y = fmaf(hv0.y, w0, acc.y);
        acc.z = fmaf(hv0.z, w0, acc.z);
        acc.w = fmaf(hv0.w, w0, acc.w);
    }
#pragma unroll
    for (int off = 16; off <= 32; off <<= 1) {
        acc.x += __shfl_xor(acc.x, off);
        acc.y += __shfl_xor(acc.y, off);
        acc.z += __shfl_xor(acc.z, off);
        acc.w += __shfl_xor(acc.w, off);
    }
    if (g == 0) {
        float4 bb = bg[sl];
        float4 o;
        o.x = lrelu01(acc.x * dn + bb.x);
        o.y = lrelu01(acc.y * dn + bb.y);
        o.z = lrelu01(acc.z * dn + bb.z);
        o.w = lrelu01(acc.w * dn + bb.w);
        x3[(size_t)n * 16 + sl] = o;
    }
}

// ---------------- segmented mean-pool ----------------
__global__ __launch_bounds__(256) void pool_k(const float* __restrict__ x3,
                                              const int* __restrict__ gstart,
                                              float* __restrict__ pooled) {
    __shared__ float red[4][64];
    int g = blockIdx.x, t = threadIdx.x;
    int c = t & 63, r = t >> 6;
    int s = gstart[g], e = gstart[g + 1];
    float sum = 0.f;
    for (int n = s + r; n < e; n += 4) sum += x3[(size_t)n * 64 + c];
    red[r][c] = sum;
    __syncthreads();
    if (t < 64) {
        float v = red[0][t] + red[1][t] + red[2][t] + red[3][t];
        int cnt = e - s; if (cnt < 1) cnt = 1;
        pooled[g * 64 + t] = v / (float)cnt;
    }
}

// ---------------- per-graph MLP head ----------------
__global__ __launch_bounds__(128) void mlp_k(const float* __restrict__ pooled,
                                             const float* __restrict__ l1W,
                                             const float* __restrict__ l1b,
                                             const float* __restrict__ g3,
                                             const float* __restrict__ b3,
                                             const float* __restrict__ l2W,
                                             const float* __restrict__ l2b,
                                             void* __restrict__ outp,
                                             const int* __restrict__ flag) {
    __shared__ float pl[64];
    __shared__ float y1s[128];
    int g = blockIdx.x, t = threadIdx.x;
    if (t < 64) pl[t] = pooled[g * 64 + t];
    __syncthreads();
    float acc = l1b[t];
#pragma unroll 8
    for (int j = 0; j < 64; ++j) acc = fmaf(pl[j], l1W[j * 128 + t], acc);
    acc = acc * (g3[t] * BN_RS) + b3[t];
    y1s[t] = lrelu01(acc);
    __syncthreads();
    if (t < 10) {
        float o = l2b[t];
#pragma unroll 8
        for (int j = 0; j < 128; ++j) o = fmaf(y1s[j], l2W[j * 10 + t], o);
        if (*flag) ((__hip_bfloat16*)outp)[g * 10 + t] = __float2bfloat16(o);
        else       ((float*)outp)[g * 10 + t] = o;
    }
}

// weight segment sizes (W1,as1,ad1,b1,W2,as2,ad2,b2,Wg,bg,bn1g,bn1b,bn2g,bn2b,bn3g,bn3b,l1W,l1b,l2W,l2b)
static const int kSegN[NSEG]  = {32768, 256, 256, 256, 32768, 128, 128, 128, 8192, 64,
                                 256, 256, 128, 128, 128, 128, 8192, 128, 1280, 10};
static const int kSegIn[NSEG] = {3, 4, 5, 6, 7, 8, 9, 10, 11, 12, 13, 14, 15, 16, 17, 18, 19, 20, 21, 22};

extern "C" void kernel_launch(void* const* d_in, const int* in_sizes, int n_in,
                              void* d_out, int out_size, void* d_ws, size_t ws_size,
                              hipStream_t stream) {
    const void* x_raw = d_in[0];
    const int*  ei    = (const int*)d_in[1];
    const int*  batch = (const int*)d_in[2];

    // ---- workspace layout ----
    int*   flag = (int*)d_ws;
    float* ws   = (float*)d_ws;
    unsigned short* xb = (unsigned short*)(ws + 16);          // N*128 bf16
    float* wf   = ws + 16 + (size_t)NN * 64;                  // 85584 fp32 canonical
    unsigned short* W1t = (unsigned short*)(wf + 85584);      // 32768 bf16 [256][128]
    unsigned short* W2t = W1t + 32768;                        // 32768 bf16 [128][256]
    unsigned short* Wgt = W2t + 32768;                        // 8192  bf16 [64][128]
    unsigned short* h1b = Wgt + 8192;                         // N*256 bf16 (reused as h2b)
    unsigned short* x1b = h1b + (size_t)NN * 256;             // N*256 bf16
    unsigned short* x2b = x1b + (size_t)NN * 256;             // N*128 bf16
    unsigned short* hgb = x2b + (size_t)NN * 128;             // N*64 bf16
    float* x3   = (float*)(hgb + (size_t)NN * 64);            // N*64 fp32
    float* sc_s1 = x3 + (size_t)NN * 64;                      // N*4
    float* sc_d1 = sc_s1 + (size_t)NN * 4;                    // N*4
    float* sc_s2 = sc_d1 + (size_t)NN * 4;                    // N
    float* sc_d2 = sc_s2 + NN;                                // N
    float* disb  = sc_d2 + NN;                                // N
    float* pooled = disb + NN;                                // B*64
    int*   gstart = (int*)(pooled + NB * 64);                 // B+1
    int*   degi   = gstart + NB + 4;                          // N
    int*   incl   = degi + NN;                                // N
    int*   bsum   = incl + NN;                                // 256
    int*   row_ptr = bsum + 256;                              // N+1
    int*   cursor  = row_ptr + NN + 1;                        // N
    int*   csr_src = cursor + NN;                             // NE2

    int off[NSEG]; int o = 0;
    for (int s = 0; s < NSEG; ++s) { off[s] = o; o += kSegN[s]; }
    float* as1f = wf + off[1];  float* ad1f = wf + off[2];
    float* b1f  = wf + off[3];  float* as2f = wf + off[5];
    float* ad2f = wf + off[6];  float* b2f  = wf + off[7];
    float* bgf  = wf + off[9];  float* bn1g = wf + off[10]; float* bn1b = wf + off[11];
    float* bn2g = wf + off[12]; float* bn2b = wf + off[13]; float* bn3g = wf + off[14];
    float* bn3b = wf + off[15]; float* l1Wf = wf + off[16]; float* l1bf = wf + off[17];
    float* l2Wf = wf + off[18]; float* l2bf = wf + off[19];

    unsigned short* h2b = h1b;   // h1b dead after agg1_k

    // ---- prep: dtype detect (per block) + degi zero + x/weights canonicalize ----
    SegArgs sa;
    for (int s = 0; s < NSEG; ++s) { sa.src[s] = d_in[kSegIn[s]]; sa.off[s] = off[s]; }
    prep_k<<<(PREP_TOT + 255) / 256, 256, 0, stream>>>(sa, x_raw, (ushort4*)xb,
                                                       d_in[3], d_in[7], d_in[11],
                                                       wf, W1t, W2t, Wgt, degi, flag);

    // ---- CSR build (by destination) + graph bounds ----
    deg_k<<<(NE2 + 255) / 256, 256, 0, stream>>>(ei, degi);
    pscan_k<<<NSB, 256, 0, stream>>>(degi, incl, bsum);
    bscan_k<<<1, 256, 0, stream>>>(bsum);
    fscan_k<<<NSB, 256, 0, stream>>>(degi, incl, bsum, batch, row_ptr, cursor, disb, gstart);
    scatter_k<<<(NE2 + 255) / 256, 256, 0, stream>>>(ei, cursor, csr_src);

    // ---- GAT layer 1 (scores fused into GEMM) ----
    mgemm1_k<<<NRT, 256, 0, stream>>>((const short*)xb, (const short*)W1t, h1b,
                                      as1f, ad1f, sc_s1, sc_d1);
    agg1_k<<<12500, 256, 0, stream>>>(row_ptr, csr_src, (const ushort4*)h1b,
                                      (const float4*)sc_s1, (const float4*)sc_d1,
                                      (const float4*)b1f, (const float4*)bn1g,
                                      (const float4*)bn1b, (ushort4*)x1b);

    // ---- GAT layer 2 (scores fused into GEMM) ----
    mgemm2_k<<<(NRT * 2 + 3) / 4, 256, 0, stream>>>((const short*)x1b, (const short*)W2t, h2b,
                                                    as2f, ad2f, sc_s2, sc_d2);
    agg2_k<<<12500, 256, 0, stream>>>(row_ptr, csr_src, (const ushort4*)h2b,
                                      sc_s2, sc_d2,
                                      (const float4*)b2f, (const float4*)bn2g,
                                      (const float4*)bn2b, (ushort4*)x2b);

    // ---- GCN + pool ----
    mgemm3_k<<<(NRT + 3) / 4, 256, 0, stream>>>((const short*)x2b, (const short*)Wgt, hgb);
    gcn_k<<<12500, 256, 0, stream>>>(row_ptr, csr_src, (const ushort4*)hgb, disb,
                                     (const float4*)bgf, (float4*)x3);
    pool_k<<<NB, 256, 0, stream>>>(x3, gstart, pooled);

    // ---- MLP head ----
    mlp_k<<<NB, 128, 0, stream>>>(pooled, l1Wf, l1bf, bn3g, bn3b, l2Wf, l2bf, d_out, flag);
}